// Round 8
// baseline (1259.155 us; speedup 1.0000x reference)
//
#include <hip/hip_runtime.h>
#include <hip/hip_bf16.h>

typedef _Float16 f16;
typedef __attribute__((ext_vector_type(8))) _Float16 f16x8;
typedef __attribute__((ext_vector_type(4))) float f32x4;

// ---------------- global_load_lds helper (16B, wave-uniform LDS base + lane*16) ----
__device__ __forceinline__ void gload_lds16(const void* g, void* l) {
  __builtin_amdgcn_global_load_lds((const __attribute__((address_space(1))) void*)g,
                                   (__attribute__((address_space(3))) void*)l, 16, 0, 0);
}

// ---------------- weight transpose+cast: [81*CIN][COUT] f32 -> [COUT][81*CIN] f16 --
template<int CIN, int COUT>
__global__ __launch_bounds__(256) void wtrans_kernel(const float* __restrict__ src,
                                                     f16* __restrict__ dst) {
  constexpr int KT = 81 * CIN;
  __shared__ float tile[64][65];
  int k0 = blockIdx.x * 64;
  int n0 = blockIdx.y * 64;
  int t = threadIdx.x;
#pragma unroll
  for (int i = 0; i < 16; ++i) {
    int id = t + i * 256;
    int r = id >> 6, c = id & 63;
    tile[r][c] = src[(k0 + r) * COUT + n0 + c];
  }
  __syncthreads();
#pragma unroll
  for (int i = 0; i < 16; ++i) {
    int id = t + i * 256;
    int r = id >> 6, c = id & 63;  // r = n_local, c = k_local
    dst[(n0 + r) * KT + k0 + c] = (f16)tile[c][r];
  }
}

// ---------------- generic transpose+cast+pad: [K][N] f32 -> [NP][K] f16, zero rows n>=N
__global__ __launch_bounds__(256) void wtransg_kernel(const float* __restrict__ src,
                                                      f16* __restrict__ dst,
                                                      int K, int N, int NP) {
  __shared__ float tile[64][65];
  int k0 = blockIdx.x * 64;
  int n0 = blockIdx.y * 64;
  int t = threadIdx.x;
#pragma unroll
  for (int i = 0; i < 16; ++i) {
    int id = t + i * 256;
    int r = id >> 6, c = id & 63;  // r = k_local, c = n_local
    tile[r][c] = (n0 + c < N) ? src[(k0 + r) * N + n0 + c] : 0.f;
  }
  __syncthreads();
#pragma unroll
  for (int i = 0; i < 16; ++i) {
    int id = t + i * 256;
    int r = id >> 6, c = id & 63;  // r = n_local, c = k_local
    dst[(size_t)(n0 + r) * K + k0 + c] = (f16)tile[c][r];
  }
}

// ---------------- conv1: 5x5, Cin=1, Cout=64, relu, f16 out (8 couts/thread) -------
__global__ __launch_bounds__(256) void conv1_kernel(const float* __restrict__ x,
                                                    const float* __restrict__ kw,
                                                    const float* __restrict__ bias,
                                                    f16* __restrict__ out) {
  int idx = blockIdx.x * 256 + threadIdx.x;  // 256*36*36*8 threads
  int g = idx & 7;
  int co0 = g * 8;
  int r = idx >> 3;
  int ow = r % 36; int r2 = r / 36; int oh = r2 % 36; int b = r2 / 36;
  float acc[8];
#pragma unroll
  for (int j = 0; j < 8; ++j) acc[j] = bias[co0 + j];
  const float* xp = x + (b * 40 + oh) * 40 + ow;
#pragma unroll
  for (int dy = 0; dy < 5; ++dy)
#pragma unroll
    for (int dx = 0; dx < 5; ++dx) {
      float xv = xp[dy * 40 + dx];
      const float* kp = kw + (dy * 5 + dx) * 64 + co0;
#pragma unroll
      for (int j = 0; j < 8; ++j) acc[j] += xv * kp[j];
    }
  f16x8 o;
#pragma unroll
  for (int j = 0; j < 8; ++j) o[j] = (f16)fmaxf(acc[j], 0.f);
  *(f16x8*)(out + r * 64 + co0) = o;
}

// ---------------- im2col tap offset helper (BK=64 chunks) ----------------
template<int CIN, int WIN>
__device__ __forceinline__ int tapA_off(int kt) {
  int tap, ci0;
  if (CIN == 64)       { tap = kt;      ci0 = 0; }
  else if (CIN == 128) { tap = kt >> 1; ci0 = (kt & 1) << 6; }
  else                 { tap = kt >> 2; ci0 = (kt & 3) << 6; }
  int dy = tap / 9, dx = tap - dy * 9;
  return (dy * WIN + dx) * CIN + ci0;
}

// ============ 8-phase 256x256 implicit-GEMM conv (HK-template port, R3 config) ======
template<int HIN, int WIN, int CIN, int HOUT, int WOUT, int COUT, int STRIDE,
         bool RELU, bool OUTF16>
__global__ __launch_bounds__(512, 2) void conv8p_kernel(const f16* __restrict__ in,
                                                        const f16* __restrict__ wt,
                                                        const float* __restrict__ bias,
                                                        f16* __restrict__ out16,
                                                        float* __restrict__ out32) {
  static_assert(COUT == 256, "BN=256 template requires COUT==256");
  constexpr int KTOT = 81 * CIN;
  constexpr int NT = KTOT / 64;
  __shared__ __align__(16) f16 lds[65536];  // 128 KiB
  const int mb = (int)blockIdx.x;
  const int t = threadIdx.x;
  const int wave = t >> 6, lane = t & 63;
  const int hi = lane >> 4, lo = lane & 15;
  const int wm = wave >> 2, wn = wave & 3;

  int Aoff[4], Boff[4];
  {
    int g = (lane & 7) ^ ((lane >> 3) & 7);  // inverse swizzle granule
#pragma unroll
    for (int rbi = 0; rbi < 4; ++rbi) {
      int r = rbi * 64 + 8 * wave + (lane >> 3);
      int m = mb * 256 + r;
      int b = m / (HOUT * WOUT);
      int rr = m - b * (HOUT * WOUT);
      int oh = rr / WOUT, ow = rr - oh * WOUT;
      Aoff[rbi] = ((b * HIN + oh * STRIDE) * WIN + ow * STRIDE) * CIN + g * 8;
      Boff[rbi] = r * KTOT + g * 8;
    }
  }
  const int gb0 = (hi ^ (lo & 7)) << 4;
  const int gb1 = ((4 + hi) ^ (lo & 7)) << 4;

  const char* ldsc = (const char*)lds;
  char* ldsw = (char*)lds;

#define GA(rbi, tpo, bq) gload_lds16(in + Aoff[rbi] + (tpo),                        \
    (void*)(ldsw + (bq) * 32768 + ((rbi) * 64 + 8 * wave) * 128))
#define GB(rbi, tile) gload_lds16(wt + Boff[rbi] + ((tile) << 6),                   \
    (void*)(ldsw + 65536 + ((tile) & 1) * 32768 + ((rbi) * 64 + 8 * wave) * 128))

  {
    int tp0 = tapA_off<CIN, WIN>(0);
    GA(0, tp0, 0); GA(2, tp0, 0); GA(1, tp0, 0); GA(3, tp0, 0);
    GB(0, 0); GB(1, 0); GB(2, 0); GB(3, 0);
    GB(0, 1); GB(1, 1); GB(2, 1); GB(3, 1);
    asm volatile("s_waitcnt vmcnt(4)" ::: "memory");
    __builtin_amdgcn_s_barrier();
  }

  f32x4 acc[8][4] = {};

#define DO_PHASE(Q, STAGE)                                                          \
  {                                                                                 \
    f16x8 af[2][2];                                                                 \
    _Pragma("unroll")                                                               \
    for (int mf = 0; mf < 2; ++mf) {                                                \
      af[mf][0] = *(const f16x8*)(Ab + ((Q) * 2 + mf) * 2048 + gb0);                \
      af[mf][1] = *(const f16x8*)(Ab + ((Q) * 2 + mf) * 2048 + gb1);                \
    }                                                                               \
    STAGE;                                                                          \
    __builtin_amdgcn_s_barrier();                                                   \
    asm volatile("s_waitcnt lgkmcnt(0)" ::: "memory");                              \
    __builtin_amdgcn_sched_barrier(0);                                              \
    __builtin_amdgcn_s_setprio(1);                                                  \
    _Pragma("unroll")                                                               \
    for (int sb = 0; sb < 2; ++sb)                                                  \
      _Pragma("unroll")                                                             \
      for (int mf = 0; mf < 2; ++mf)                                                \
        _Pragma("unroll")                                                           \
        for (int nf = 0; nf < 4; ++nf)                                              \
          acc[(Q) * 2 + mf][nf] = __builtin_amdgcn_mfma_f32_16x16x32_f16(           \
              af[mf][sb], bfr[nf][sb], acc[(Q) * 2 + mf][nf], 0, 0, 0);             \
    __builtin_amdgcn_s_setprio(0);                                                  \
    __builtin_amdgcn_s_barrier();                                                   \
  }

  for (int T = 0; T < NT; ++T) {
    const int q = T & 1;
    const char* Ab = ldsc + q * 32768 + wm * 16384 + lo * 128;
    const char* Bb = ldsc + 65536 + q * 32768 + wn * 8192 + lo * 128;
    const int tpn = tapA_off<CIN, WIN>(T + 1);
    f16x8 bfr[4][2];
#pragma unroll
    for (int nf = 0; nf < 4; ++nf) {
      bfr[nf][0] = *(const f16x8*)(Bb + nf * 2048 + gb0);
      bfr[nf][1] = *(const f16x8*)(Bb + nf * 2048 + gb1);
    }
    DO_PHASE(0, if (T + 1 < NT) { GA(0, tpn, (T + 1) & 1); GA(2, tpn, (T + 1) & 1); })
    DO_PHASE(1, if (T + 1 < NT) { GA(1, tpn, (T + 1) & 1); GA(3, tpn, (T + 1) & 1); })
    DO_PHASE(2, if (T + 2 < NT) { GB(0, T + 2); GB(1, T + 2); })
    DO_PHASE(3,
      if (T + 2 < NT) {
        GB(2, T + 2); GB(3, T + 2);
        asm volatile("s_waitcnt vmcnt(4)" ::: "memory");
      } else {
        asm volatile("s_waitcnt vmcnt(0)" ::: "memory");
      })
  }
#undef DO_PHASE
#undef GA
#undef GB

#pragma unroll
  for (int mfr = 0; mfr < 8; ++mfr) {
#pragma unroll
    for (int nf = 0; nf < 4; ++nf) {
      int m0 = mb * 256 + wm * 128 + mfr * 16 + hi * 4;
      int n = wn * 64 + nf * 16 + lo;
      float bval = bias[n];
#pragma unroll
      for (int r = 0; r < 4; ++r) {
        float v = acc[mfr][nf][r] + bval;
        if (RELU) v = fmaxf(v, 0.f);
        int o = (m0 + r) * COUT + n;
        if (OUTF16) out16[o] = (f16)v; else out32[o] = v;
      }
    }
  }
}

// ---------------- implicit-GEMM conv via f16 MFMA (m97 structure, 128x128) --------
template<int HIN, int WIN, int CIN, int HOUT, int WOUT, int COUT, int STRIDE,
         bool RELU, bool OUTF16, int SPLIT, bool ADDBIAS>
__global__ __launch_bounds__(256) void conv_mfma_kernel(const f16* __restrict__ in,
                                                        const f16* __restrict__ wt,
                                                        const float* __restrict__ bias,
                                                        f16* __restrict__ out16,
                                                        float* __restrict__ out32) {
  constexpr int KTOT = 81 * CIN;
  constexpr int NBLK = COUT / 128;
  constexpr int MTOT = 256 * HOUT * WOUT;
  constexpr int MBNB = (MTOT / 128) * NBLK;
  constexpr int NKT = (KTOT / 64) / SPLIT;
  __shared__ __align__(16) f16 lds[16384];
  int bidx = (int)blockIdx.x;
  int ks = 0;
  if (SPLIT > 1) { ks = bidx / MBNB; bidx -= ks * MBNB; }
  const int mb = bidx / NBLK;
  const int nb = bidx % NBLK;
  const int t = threadIdx.x;
  const int wave = t >> 6, lane = t & 63;
  const int hi = lane >> 4, lo = lane & 15;
  const bool isA = wave < 2;
  const int slot0 = wave << 9;

  int baseoff[8];
#pragma unroll
  for (int it = 0; it < 8; ++it) {
    int s = slot0 + it * 64 + lane;
    if (isA) {
      int row = s >> 3;
      int g = (s & 7) ^ (row & 7);
      int mg = mb * 128 + row;
      int b = mg / (HOUT * WOUT);
      int rr = mg - b * (HOUT * WOUT);
      int oh = rr / WOUT;
      int ow = rr - oh * WOUT;
      baseoff[it] = ((b * HIN + oh * STRIDE) * WIN + ow * STRIDE) * CIN + g * 8;
    } else {
      int sl = s - 1024;
      int row = sl >> 3;
      int g = (sl & 7) ^ (row & 7);
      baseoff[it] = (nb * 128 + row) * KTOT + g * 8;
    }
  }
  const f16* gsrc = isA ? in : wt;

  int aQ[4], bQ[4];
  const int wm = wave >> 1, wn = wave & 1;
#pragma unroll
  for (int f = 0; f < 4; ++f) {
    int arow = wm * 64 + f * 16 + lo;
    aQ[f] = (arow * 128) ^ ((arow & 7) << 4);
    int brow = wn * 64 + f * 16 + lo;
    bQ[f] = 16384 + ((brow * 128) ^ ((brow & 7) << 4));
  }

  f32x4 acc[4][4] = {};
  const char* ldsc = (const char*)lds;

  const int kt0 = ks * NKT;
  for (int kt = kt0; kt < kt0 + NKT; ++kt) {
    int tapoff;
    if (isA) tapoff = tapA_off<CIN, WIN>(kt);
    else     tapoff = kt << 6;
    __syncthreads();
#pragma unroll
    for (int it = 0; it < 8; ++it)
      gload_lds16(gsrc + baseoff[it] + tapoff,
                  (void*)((char*)lds + ((slot0 + it * 64) << 4)));
    __syncthreads();
#pragma unroll
    for (int sub = 0; sub < 2; ++sub) {
      const int gx = (sub * 4 + hi) << 4;
      f16x8 av[4], bv[4];
#pragma unroll
      for (int f = 0; f < 4; ++f) av[f] = *(const f16x8*)(ldsc + (aQ[f] ^ gx));
#pragma unroll
      for (int f = 0; f < 4; ++f) bv[f] = *(const f16x8*)(ldsc + (bQ[f] ^ gx));
#pragma unroll
      for (int mf = 0; mf < 4; ++mf)
#pragma unroll
        for (int nf = 0; nf < 4; ++nf)
          acc[mf][nf] = __builtin_amdgcn_mfma_f32_16x16x32_f16(av[mf], bv[nf],
                                                               acc[mf][nf], 0, 0, 0);
    }
  }

  float* o32 = out32 + (size_t)ks * MTOT * COUT;
#pragma unroll
  for (int mf = 0; mf < 4; ++mf) {
#pragma unroll
    for (int nf = 0; nf < 4; ++nf) {
      int m0 = mb * 128 + wm * 64 + mf * 16 + hi * 4;
      int n = nb * 128 + wn * 64 + nf * 16 + lo;
      float bval = ADDBIAS ? bias[n] : 0.f;
#pragma unroll
      for (int r = 0; r < 4; ++r) {
        float v = acc[mf][nf][r] + bval;
        if (RELU) v = fmaxf(v, 0.f);
        int o = (m0 + r) * COUT + n;
        if (OUTF16) out16[o] = (f16)v; else o32[o] = v;
      }
    }
  }
}

// ---------------- prim K-split reduction: p = bias + sum_s partial[s] ----------------
__global__ __launch_bounds__(256) void prim_reduce_kernel(const float* __restrict__ part,
                                                          const float* __restrict__ bias,
                                                          float* __restrict__ p) {
  int idx = blockIdx.x * 256 + threadIdx.x;  // 9216*256
  int n = idx & 255;
  float a = bias[n];
#pragma unroll
  for (int s = 0; s < 4; ++s) a += part[s * 2359296 + idx];
  p[idx] = a;
}

// ------- dense GEMM via f16 MFMA, K-split partials: A[256][K] x Bw[NP][K]^T --------
// SPLIT>1: grid = 2*NBLK*SPLIT, each block does K/SPLIT, writes f32 partials.
template<int K, int NP, int SPLIT>
__global__ __launch_bounds__(256) void gemm_mfma_kernel(const f16* __restrict__ A,
                                                        const f16* __restrict__ Bw,
                                                        float* __restrict__ dpart) {
  constexpr int NBLK = NP / 128;
  constexpr int MBNB = 2 * NBLK;
  constexpr int NKT = (K / 64) / SPLIT;
  __shared__ __align__(16) f16 lds[16384];
  int bidx = (int)blockIdx.x;
  int ks = 0;
  if (SPLIT > 1) { ks = bidx / MBNB; bidx -= ks * MBNB; }
  const int mb = bidx / NBLK;
  const int nb = bidx % NBLK;
  const int t = threadIdx.x;
  const int wave = t >> 6, lane = t & 63;
  const int hi = lane >> 4, lo = lane & 15;
  const bool isA = wave < 2;
  const int slot0 = wave << 9;

  int baseoff[8];
#pragma unroll
  for (int it = 0; it < 8; ++it) {
    int s = slot0 + it * 64 + lane;
    if (isA) {
      int row = s >> 3;
      int g = (s & 7) ^ (row & 7);
      baseoff[it] = (mb * 128 + row) * K + g * 8;
    } else {
      int sl = s - 1024;
      int row = sl >> 3;
      int g = (sl & 7) ^ (row & 7);
      baseoff[it] = (nb * 128 + row) * K + g * 8;
    }
  }
  const f16* gsrc = isA ? A : Bw;

  int aQ[4], bQ[4];
  const int wm = wave >> 1, wn = wave & 1;
#pragma unroll
  for (int f = 0; f < 4; ++f) {
    int arow = wm * 64 + f * 16 + lo;
    aQ[f] = (arow * 128) ^ ((arow & 7) << 4);
    int brow = wn * 64 + f * 16 + lo;
    bQ[f] = 16384 + ((brow * 128) ^ ((brow & 7) << 4));
  }

  f32x4 acc[4][4] = {};
  const char* ldsc = (const char*)lds;

  const int kt0 = ks * NKT;
  for (int kt = kt0; kt < kt0 + NKT; ++kt) {
    int tapoff = kt << 6;
    __syncthreads();
#pragma unroll
    for (int it = 0; it < 8; ++it)
      gload_lds16(gsrc + baseoff[it] + tapoff,
                  (void*)((char*)lds + ((slot0 + it * 64) << 4)));
    __syncthreads();
#pragma unroll
    for (int sub = 0; sub < 2; ++sub) {
      const int gx = (sub * 4 + hi) << 4;
      f16x8 av[4], bv[4];
#pragma unroll
      for (int f = 0; f < 4; ++f) av[f] = *(const f16x8*)(ldsc + (aQ[f] ^ gx));
#pragma unroll
      for (int f = 0; f < 4; ++f) bv[f] = *(const f16x8*)(ldsc + (bQ[f] ^ gx));
#pragma unroll
      for (int mf = 0; mf < 4; ++mf)
#pragma unroll
        for (int nf = 0; nf < 4; ++nf)
          acc[mf][nf] = __builtin_amdgcn_mfma_f32_16x16x32_f16(av[mf], bv[nf],
                                                               acc[mf][nf], 0, 0, 0);
    }
  }

  float* o32 = dpart + (size_t)ks * 256 * NP;
#pragma unroll
  for (int mf = 0; mf < 4; ++mf) {
#pragma unroll
    for (int nf = 0; nf < 4; ++nf) {
      int m0 = mb * 128 + wm * 64 + mf * 16 + hi * 4;
      int n = nb * 128 + wn * 64 + nf * 16 + lo;
#pragma unroll
      for (int r = 0; r < 4; ++r)
        o32[(m0 + r) * NP + n] = acc[mf][nf][r];
    }
  }
}

// ---------------- d2 reduce: r2 = relu(sum_s part + bias) f16, x4 vec ----------------
__global__ __launch_bounds__(256) void d2red_kernel(const float* __restrict__ part,
                                                    const float* __restrict__ bias,
                                                    f16* __restrict__ r2) {
  int idx = blockIdx.x * 256 + threadIdx.x;  // 512 blocks: 524288/4
  int e0 = idx * 4;
  int n0 = e0 & 2047;
  float4 a = *(const float4*)(part + e0);
  const float4 b1 = *(const float4*)(part + 524288 + e0);
  const float4 b2 = *(const float4*)(part + 1048576 + e0);
  const float4 b3 = *(const float4*)(part + 1572864 + e0);
  float v[4] = {a.x + b1.x + b2.x + b3.x, a.y + b1.y + b2.y + b3.y,
                a.z + b1.z + b2.z + b3.z, a.w + b1.w + b2.w + b3.w};
#pragma unroll
  for (int j = 0; j < 4; ++j)
    r2[e0 + j] = (f16)fmaxf(v[j] + bias[n0 + j], 0.f);
}

// ---------------- d3 reduce: recon = sigmoid(sum_s part + bias), mask n<1600 --------
__global__ __launch_bounds__(256) void d3red_kernel(const float* __restrict__ part,
                                                    const float* __restrict__ bias,
                                                    float* __restrict__ recon) {
  int idx = blockIdx.x * 256 + threadIdx.x;  // 416 blocks: 425984/4
  int e0 = idx * 4;
  int n0 = e0 % 1664;
  int m = e0 / 1664;
  float v[4] = {0.f, 0.f, 0.f, 0.f};
#pragma unroll
  for (int s = 0; s < 8; ++s) {
    float4 a = *(const float4*)(part + s * 425984 + e0);
    v[0] += a.x; v[1] += a.y; v[2] += a.z; v[3] += a.w;
  }
#pragma unroll
  for (int j = 0; j < 4; ++j) {
    int n = n0 + j;
    if (n < 1600)
      recon[m * 1600 + n] = 1.f / (1.f + expf(-(v[j] + bias[n])));
  }
}

// ======================= fused routing =======================
// uhatps: block (b, ic of 9), 320 threads. Computes uhat[b, ic*128..+128, :] (f32
// weights read directly, L2-resident) and per-half-chunk partial sums over i.
__global__ __launch_bounds__(320) void uhatps_kernel(const float* __restrict__ wf,
                                                     const float* __restrict__ u,
                                                     f16* __restrict__ uh,
                                                     float* __restrict__ parts) {
  __shared__ float pl[128][8];
  int blk = (int)blockIdx.x;
  int b = blk / 9, ic = blk - b * 9;
  int t = threadIdx.x;
  const float* pb = u + (b * 1152 + ic * 128) * 8;
  for (int e = t; e < 1024; e += 320) pl[e >> 3][e & 7] = pb[e];
  __syncthreads();
  int half = (t >= 160) ? 1 : 0;
  int jk = t - half * 160;
  int ibase = ic * 128 + half * 64;
  float sum = 0.f;
  for (int il = 0; il < 64; ++il) {
    int i = ibase + il;
    const float4* w4 = (const float4*)(wf + (i * 160 + jk) * 8);
    float4 w0 = w4[0], w1 = w4[1];
    const float* pr = pl[half * 64 + il];
    float acc = w0.x * pr[0] + w0.y * pr[1] + w0.z * pr[2] + w0.w * pr[3] +
                w1.x * pr[4] + w1.y * pr[5] + w1.z * pr[6] + w1.w * pr[7];
    uh[(b * 1152 + i) * 160 + jk] = (f16)acc;
    sum += acc;
  }
  parts[(b * 18 + ic * 2 + half) * 160 + jk] = sum;
}

// sred: s[b,jk] = cscale * sum_c parts[b][c][jk]; v = squash(s) -> vbuf (+vout last)
__global__ __launch_bounds__(160) void sred_kernel(const float* __restrict__ parts,
                                                   float cscale, int nch,
                                                   float* __restrict__ vbuf,
                                                   float* __restrict__ vout) {
  int b = blockIdx.x, t = threadIdx.x;  // t < 160
  float s = 0.f;
  for (int c = 0; c < nch; ++c) s += parts[(b * nch + c) * 160 + t];
  s *= cscale;
  float ss = s * s;
  ss += __shfl_xor(ss, 1, 16);
  ss += __shfl_xor(ss, 2, 16);
  ss += __shfl_xor(ss, 4, 16);
  ss += __shfl_xor(ss, 8, 16);
  float n = sqrtf(ss);
  float f = ss / ((1.f + ss) * (n + 1e-7f));
  float v = f * s;
  vbuf[b * 160 + t] = v;
  if (vout) vout[b * 160 + t] = v;
}

// ba: one uhat read does: agr = <uhat, v_prev>; blog' = blog + agr; c = softmax_j;
// partial s = sum_i c * uhat  ->  parts[b][9][160].  Deterministic (no atomics).
template<bool FIRST, bool WRITEB>
__global__ __launch_bounds__(256) void ba_kernel(const f16* __restrict__ uh,
                                                 const float* __restrict__ vbuf,
                                                 float* __restrict__ blog,
                                                 float* __restrict__ parts) {
  __shared__ f16 ul[128 * 172];   // 44,032 B
  __shared__ float vl[160];
  __shared__ float csm[128 * 10];
  int blk = (int)blockIdx.x;
  int b = blk / 9, ic = blk - b * 9;
  int t = threadIdx.x;
  const f16* ub = uh + (size_t)(b * 1152 + ic * 128) * 160;
  for (int e = t; e < 2560; e += 256) {  // 128 rows x 20 vec8
    int row = e / 20, col = e - row * 20;
    *(f16x8*)(ul + row * 172 + col * 8) = *(const f16x8*)(ub + row * 160 + col * 8);
  }
  if (t < 160) vl[t] = vbuf[b * 160 + t];
  __syncthreads();

  int il = t >> 1, half = t & 1, j0 = half * 5;
  const f16* ur = ul + il * 172 + j0 * 16;
  float agr[5];
#pragma unroll
  for (int j = 0; j < 5; ++j) {
    f16x8 a0 = *(const f16x8*)(ur + j * 16);
    f16x8 a1 = *(const f16x8*)(ur + j * 16 + 8);
    const float* vv = vl + (j0 + j) * 16;
    float s = (float)a0[0] * vv[0] + (float)a0[1] * vv[1] + (float)a0[2] * vv[2] +
              (float)a0[3] * vv[3] + (float)a0[4] * vv[4] + (float)a0[5] * vv[5] +
              (float)a0[6] * vv[6] + (float)a0[7] * vv[7] +
              (float)a1[0] * vv[8] + (float)a1[1] * vv[9] + (float)a1[2] * vv[10] +
              (float)a1[3] * vv[11] + (float)a1[4] * vv[12] + (float)a1[5] * vv[13] +
              (float)a1[6] * vv[14] + (float)a1[7] * vv[15];
    agr[j] = s;
  }
  int bbase = (b * 1152 + ic * 128 + il) * 10 + j0;
  float bl[5];
#pragma unroll
  for (int j = 0; j < 5; ++j) bl[j] = (FIRST ? 0.f : blog[bbase + j]) + agr[j];
  if (WRITEB) {
#pragma unroll
    for (int j = 0; j < 5; ++j) blog[bbase + j] = bl[j];
  }
  float mx = bl[0];
#pragma unroll
  for (int j = 1; j < 5; ++j) mx = fmaxf(mx, bl[j]);
  mx = fmaxf(mx, __shfl_xor(mx, 1));
  float e5[5], se = 0.f;
#pragma unroll
  for (int j = 0; j < 5; ++j) { e5[j] = expf(bl[j] - mx); se += e5[j]; }
  se += __shfl_xor(se, 1);
  float inv = 1.f / se;
#pragma unroll
  for (int j = 0; j < 5; ++j) csm[il * 10 + j0 + j] = e5[j] * inv;
  __syncthreads();

  if (t < 160) {
    int j = t >> 4;
    float s = 0.f;
    for (int il2 = 0; il2 < 128; ++il2)
      s += csm[il2 * 10 + j] * (float)ul[il2 * 172 + t];
    parts[(b * 9 + ic) * 160 + t] = s;
  }
}

// ---------------- mask by label + dense1 (160->1024, relu, f16 out) ----------------
__global__ __launch_bounds__(256) void maskd1_kernel(const float* __restrict__ vbuf,
                                                     const int* __restrict__ y,
                                                     const float* __restrict__ w1,
                                                     const float* __restrict__ b1,
                                                     f16* __restrict__ r1) {
  int idx = blockIdx.x * 256 + threadIdx.x;  // 256*1024
  int o = idx & 1023;
  int b = idx >> 10;
  int yb = y[b];
  const float* vv = vbuf + b * 160 + yb * 16;
  float acc = b1[o];
#pragma unroll
  for (int k = 0; k < 16; ++k) acc += vv[k] * w1[(yb * 16 + k) * 1024 + o];
  r1[idx] = (f16)fmaxf(acc, 0.f);
}

// ---------------- launch ----------------
extern "C" void kernel_launch(void* const* d_in, const int* in_sizes, int n_in,
                              void* d_out, int out_size, void* d_ws, size_t ws_size,
                              hipStream_t stream) {
  const float* x       = (const float*)d_in[0];
  const int*   y       = (const int*)d_in[1];
  const float* conv1_k = (const float*)d_in[2];
  const float* conv1_b = (const float*)d_in[3];
  const float* conv2_k = (const float*)d_in[4];
  const float* conv2_b = (const float*)d_in[5];
  const float* conv3_k = (const float*)d_in[6];
  const float* conv3_b = (const float*)d_in[7];
  const float* prim_k  = (const float*)d_in[8];
  const float* prim_b  = (const float*)d_in[9];
  const float* w_route = (const float*)d_in[10];
  const float* d1_w = (const float*)d_in[11];
  const float* d1_b = (const float*)d_in[12];
  const float* d2_w = (const float*)d_in[13];
  const float* d2_b = (const float*)d_in[14];
  const float* d3_w = (const float*)d_in[15];
  const float* d3_b = (const float*)d_in[16];

  // workspace layout (bytes), total 191,021,056 (same as R1-R7 -> proven fits):
  char* ws = (char*)d_ws;
  f16*   h1     = (f16*)(ws + 0);
  f16*   h2     = (f16*)(ws + 42467328);
  f16*   h3     = (f16*)(ws + 93847552);
  float* part   = (float*)(ws + 0);                  // 4 x 9,437,184 B (h1 dead)
  f16*   uhat   = (f16*)(ws + 0);                    // 94,371,840 B (alias, h1-h3 dead)
  float* dpart2 = (float*)(ws + 0);                  //  8,388,608 B (uhat dead, dense)
  float* dpart3 = (float*)(ws + 16777216);           // 13,631,488 B (ditto)
  float* parts  = (float*)(ws + 94371840);           //  2,949,120 B
  float* p      = (float*)(ws + 146276352);          //  9,437,184 B
  float* blog   = (float*)(ws + 155713536);          // 11,796,480 B
  f16*   wd2    = (f16*)(ws + 155713536);            //  4,194,304 B (alias, post-routing)
  f16*   wd3    = (f16*)(ws + 159907840);            //  6,815,744 B (alias, post-routing)
  float* vbuf   = (float*)(ws + 167510016);          //    163,840 B
  f16*   r1h    = (f16*)(ws + 167673856);            //    524,288 B
  f16*   r2h    = (f16*)(ws + 168198144);            //  1,048,576 B
  f16*   wt2    = (f16*)(ws + 170819584);            //  1,327,104 B
  f16*   wt3    = (f16*)(ws + 172146688);            //  5,308,416 B
  f16*   wtp    = (f16*)(ws + 177455104);            // 10,616,832 B

  float* vout  = (float*)d_out;            // [256,1,10,16] = 40960 f32
  float* recon = (float*)d_out + 40960;    // [256,1600]

  // weight prep
  wtrans_kernel<64, 128><<<dim3(81, 2), 256, 0, stream>>>(conv2_k, wt2);
  wtrans_kernel<128, 256><<<dim3(162, 4), 256, 0, stream>>>(conv3_k, wt3);
  wtrans_kernel<256, 256><<<dim3(324, 4), 256, 0, stream>>>(prim_k, wtp);

  // conv stack
  conv1_kernel<<<10368, 256, 0, stream>>>(x, conv1_k, conv1_b, h1);
  conv_mfma_kernel<36, 36, 64, 28, 28, 128, 1, true, true, 1, true>
      <<<1568, 256, 0, stream>>>(h1, wt2, conv2_b, h2, nullptr);
  // conv3: 8-phase 256^2 (R3 config, best measured)
  conv8p_kernel<28, 28, 128, 20, 20, 256, 1, true, true>
      <<<400, 512, 0, stream>>>(h2, wt3, conv3_b, h3, nullptr);
  // prim caps: K-split x4 (m97 structure), partials + reduce
  conv_mfma_kernel<20, 20, 256, 6, 6, 256, 2, false, false, 4, false>
      <<<576, 256, 0, stream>>>(h3, wtp, prim_b, nullptr, part);
  prim_reduce_kernel<<<9216, 256, 0, stream>>>(part, prim_b, p);

  // fused routing: uhat+partials -> v1 -> [agr/softmax/partial-s] -> v2 -> ... -> v3
  uhatps_kernel<<<2304, 320, 0, stream>>>(w_route, p, uhat, parts);
  sred_kernel<<<256, 160, 0, stream>>>(parts, 0.1f, 18, vbuf, nullptr);
  ba_kernel<true, true><<<2304, 256, 0, stream>>>(uhat, vbuf, blog, parts);
  sred_kernel<<<256, 160, 0, stream>>>(parts, 1.0f, 9, vbuf, nullptr);
  ba_kernel<false, false><<<2304, 256, 0, stream>>>(uhat, vbuf, blog, parts);
  sred_kernel<<<256, 160, 0, stream>>>(parts, 1.0f, 9, vbuf, vout);

  // masked reconstruction (dense weights -> f16 [N][K] into dead blog region)
  wtransg_kernel<<<dim3(16, 32), 256, 0, stream>>>(d2_w, wd2, 1024, 2048, 2048);
  wtransg_kernel<<<dim3(32, 26), 256, 0, stream>>>(d3_w, wd3, 2048, 1600, 1664);
  maskd1_kernel<<<1024, 256, 0, stream>>>(vbuf, y, d1_w, d1_b, r1h);
  // d2: 160->... M=256,N=2048,K=1024, K-split x4 -> 128 blocks + reduce
  gemm_mfma_kernel<1024, 2048, 4><<<128, 256, 0, stream>>>(r1h, wd2, dpart2);
  d2red_kernel<<<512, 256, 0, stream>>>(dpart2, d2_b, r2h);
  // d3: M=256,N=1664(1600),K=2048, K-split x8 -> 208 blocks + reduce
  gemm_mfma_kernel<2048, 1664, 8><<<208, 256, 0, stream>>>(r2h, wd3, dpart3);
  d3red_kernel<<<416, 256, 0, stream>>>(dpart3, d3_b, recon);
}

// Round 9
// 1225.775 us; speedup vs baseline: 1.0272x; 1.0272x over previous
//
#include <hip/hip_runtime.h>
#include <hip/hip_bf16.h>

typedef _Float16 f16;
typedef __attribute__((ext_vector_type(8))) _Float16 f16x8;
typedef __attribute__((ext_vector_type(4))) float f32x4;

// ---------------- global_load_lds helper (16B, wave-uniform LDS base + lane*16) ----
__device__ __forceinline__ void gload_lds16(const void* g, void* l) {
  __builtin_amdgcn_global_load_lds((const __attribute__((address_space(1))) void*)g,
                                   (__attribute__((address_space(3))) void*)l, 16, 0, 0);
}

// ---------------- generic weight transpose body: [K][N] f32 -> [NP][K] f16 ----------
__device__ __forceinline__ void wtrans_body(const float* __restrict__ src,
                                            f16* __restrict__ dst,
                                            int K, int N, int k0, int n0) {
  __shared__ float tile[64][65];
  int t = threadIdx.x;
#pragma unroll
  for (int i = 0; i < 16; ++i) {
    int id = t + i * 256;
    int r = id >> 6, c = id & 63;  // r = k_local, c = n_local
    tile[r][c] = (n0 + c < N) ? src[(size_t)(k0 + r) * N + n0 + c] : 0.f;
  }
  __syncthreads();
#pragma unroll
  for (int i = 0; i < 16; ++i) {
    int id = t + i * 256;
    int r = id >> 6, c = id & 63;  // r = n_local, c = k_local
    dst[(size_t)(n0 + r) * K + k0 + c] = (f16)tile[c][r];
  }
}

// wprepc: conv weight prep (3 jobs): conv2 (K=5184,N=128), conv3 (10368,256),
// prim (20736,256). Grid 162 + 648 + 1296 = 2106.
__global__ __launch_bounds__(256) void wprepc_kernel(const float* __restrict__ s0, f16* __restrict__ d0,
                                                     const float* __restrict__ s1, f16* __restrict__ d1,
                                                     const float* __restrict__ s2, f16* __restrict__ d2) {
  int bid = (int)blockIdx.x;
  if (bid < 162) {
    int bx = bid % 81, by = bid / 81;
    wtrans_body(s0, d0, 5184, 128, bx * 64, by * 64);
  } else if (bid < 810) {
    int l = bid - 162; int bx = l % 162, by = l / 162;
    wtrans_body(s1, d1, 10368, 256, bx * 64, by * 64);
  } else {
    int l = bid - 810; int bx = l % 324, by = l / 324;
    wtrans_body(s2, d2, 20736, 256, bx * 64, by * 64);
  }
}

// wprepd: dense weight prep (2 jobs): d2 (K=1024,N=2048,NP=2048, grid 512),
// d3 (K=2048,N=1600,NP=1664, grid 832). Grid 1344.
__global__ __launch_bounds__(256) void wprepd_kernel(const float* __restrict__ s0, f16* __restrict__ d0,
                                                     const float* __restrict__ s1, f16* __restrict__ d1) {
  int bid = (int)blockIdx.x;
  if (bid < 512) {
    int bx = bid % 16, by = bid / 16;
    wtrans_body(s0, d0, 1024, 2048, bx * 64, by * 64);
  } else {
    int l = bid - 512; int bx = l % 32, by = l / 32;
    wtrans_body(s1, d1, 2048, 1600, bx * 64, by * 64);
  }
}

// ---------------- conv1: 5x5, Cin=1, Cout=64, relu, f16 out (8 couts/thread) -------
__global__ __launch_bounds__(256) void conv1_kernel(const float* __restrict__ x,
                                                    const float* __restrict__ kw,
                                                    const float* __restrict__ bias,
                                                    f16* __restrict__ out) {
  int idx = blockIdx.x * 256 + threadIdx.x;  // 256*36*36*8 threads
  int g = idx & 7;
  int co0 = g * 8;
  int r = idx >> 3;
  int ow = r % 36; int r2 = r / 36; int oh = r2 % 36; int b = r2 / 36;
  float acc[8];
#pragma unroll
  for (int j = 0; j < 8; ++j) acc[j] = bias[co0 + j];
  const float* xp = x + (b * 40 + oh) * 40 + ow;
#pragma unroll
  for (int dy = 0; dy < 5; ++dy)
#pragma unroll
    for (int dx = 0; dx < 5; ++dx) {
      float xv = xp[dy * 40 + dx];
      const float* kp = kw + (dy * 5 + dx) * 64 + co0;
#pragma unroll
      for (int j = 0; j < 8; ++j) acc[j] += xv * kp[j];
    }
  f16x8 o;
#pragma unroll
  for (int j = 0; j < 8; ++j) o[j] = (f16)fmaxf(acc[j], 0.f);
  *(f16x8*)(out + r * 64 + co0) = o;
}

// ---------------- im2col tap offset helper (BK=64 chunks) ----------------
template<int CIN, int WIN>
__device__ __forceinline__ int tapA_off(int kt) {
  int tap, ci0;
  if (CIN == 64)       { tap = kt;      ci0 = 0; }
  else if (CIN == 128) { tap = kt >> 1; ci0 = (kt & 1) << 6; }
  else                 { tap = kt >> 2; ci0 = (kt & 3) << 6; }
  int dy = tap / 9, dx = tap - dy * 9;
  return (dy * WIN + dx) * CIN + ci0;
}

// ============ 8-phase 256x256 implicit-GEMM conv (HK-template port, R3 config) ======
template<int HIN, int WIN, int CIN, int HOUT, int WOUT, int COUT, int STRIDE,
         bool RELU, bool OUTF16>
__global__ __launch_bounds__(512, 2) void conv8p_kernel(const f16* __restrict__ in,
                                                        const f16* __restrict__ wt,
                                                        const float* __restrict__ bias,
                                                        f16* __restrict__ out16,
                                                        float* __restrict__ out32) {
  static_assert(COUT == 256, "BN=256 template requires COUT==256");
  constexpr int KTOT = 81 * CIN;
  constexpr int NT = KTOT / 64;
  __shared__ __align__(16) f16 lds[65536];  // 128 KiB
  const int mb = (int)blockIdx.x;
  const int t = threadIdx.x;
  const int wave = t >> 6, lane = t & 63;
  const int hi = lane >> 4, lo = lane & 15;
  const int wm = wave >> 2, wn = wave & 3;

  int Aoff[4], Boff[4];
  {
    int g = (lane & 7) ^ ((lane >> 3) & 7);  // inverse swizzle granule
#pragma unroll
    for (int rbi = 0; rbi < 4; ++rbi) {
      int r = rbi * 64 + 8 * wave + (lane >> 3);
      int m = mb * 256 + r;
      int b = m / (HOUT * WOUT);
      int rr = m - b * (HOUT * WOUT);
      int oh = rr / WOUT, ow = rr - oh * WOUT;
      Aoff[rbi] = ((b * HIN + oh * STRIDE) * WIN + ow * STRIDE) * CIN + g * 8;
      Boff[rbi] = r * KTOT + g * 8;
    }
  }
  const int gb0 = (hi ^ (lo & 7)) << 4;
  const int gb1 = ((4 + hi) ^ (lo & 7)) << 4;

  const char* ldsc = (const char*)lds;
  char* ldsw = (char*)lds;

#define GA(rbi, tpo, bq) gload_lds16(in + Aoff[rbi] + (tpo),                        \
    (void*)(ldsw + (bq) * 32768 + ((rbi) * 64 + 8 * wave) * 128))
#define GB(rbi, tile) gload_lds16(wt + Boff[rbi] + ((tile) << 6),                   \
    (void*)(ldsw + 65536 + ((tile) & 1) * 32768 + ((rbi) * 64 + 8 * wave) * 128))

  {
    int tp0 = tapA_off<CIN, WIN>(0);
    GA(0, tp0, 0); GA(2, tp0, 0); GA(1, tp0, 0); GA(3, tp0, 0);
    GB(0, 0); GB(1, 0); GB(2, 0); GB(3, 0);
    GB(0, 1); GB(1, 1); GB(2, 1); GB(3, 1);
    asm volatile("s_waitcnt vmcnt(4)" ::: "memory");
    __builtin_amdgcn_s_barrier();
  }

  f32x4 acc[8][4] = {};

#define DO_PHASE(Q, STAGE)                                                          \
  {                                                                                 \
    f16x8 af[2][2];                                                                 \
    _Pragma("unroll")                                                               \
    for (int mf = 0; mf < 2; ++mf) {                                                \
      af[mf][0] = *(const f16x8*)(Ab + ((Q) * 2 + mf) * 2048 + gb0);                \
      af[mf][1] = *(const f16x8*)(Ab + ((Q) * 2 + mf) * 2048 + gb1);                \
    }                                                                               \
    STAGE;                                                                          \
    __builtin_amdgcn_s_barrier();                                                   \
    asm volatile("s_waitcnt lgkmcnt(0)" ::: "memory");                              \
    __builtin_amdgcn_sched_barrier(0);                                              \
    __builtin_amdgcn_s_setprio(1);                                                  \
    _Pragma("unroll")                                                               \
    for (int sb = 0; sb < 2; ++sb)                                                  \
      _Pragma("unroll")                                                             \
      for (int mf = 0; mf < 2; ++mf)                                                \
        _Pragma("unroll")                                                           \
        for (int nf = 0; nf < 4; ++nf)                                              \
          acc[(Q) * 2 + mf][nf] = __builtin_amdgcn_mfma_f32_16x16x32_f16(           \
              af[mf][sb], bfr[nf][sb], acc[(Q) * 2 + mf][nf], 0, 0, 0);             \
    __builtin_amdgcn_s_setprio(0);                                                  \
    __builtin_amdgcn_s_barrier();                                                   \
  }

  for (int T = 0; T < NT; ++T) {
    const int q = T & 1;
    const char* Ab = ldsc + q * 32768 + wm * 16384 + lo * 128;
    const char* Bb = ldsc + 65536 + q * 32768 + wn * 8192 + lo * 128;
    const int tpn = tapA_off<CIN, WIN>(T + 1);
    f16x8 bfr[4][2];
#pragma unroll
    for (int nf = 0; nf < 4; ++nf) {
      bfr[nf][0] = *(const f16x8*)(Bb + nf * 2048 + gb0);
      bfr[nf][1] = *(const f16x8*)(Bb + nf * 2048 + gb1);
    }
    DO_PHASE(0, if (T + 1 < NT) { GA(0, tpn, (T + 1) & 1); GA(2, tpn, (T + 1) & 1); })
    DO_PHASE(1, if (T + 1 < NT) { GA(1, tpn, (T + 1) & 1); GA(3, tpn, (T + 1) & 1); })
    DO_PHASE(2, if (T + 2 < NT) { GB(0, T + 2); GB(1, T + 2); })
    DO_PHASE(3,
      if (T + 2 < NT) {
        GB(2, T + 2); GB(3, T + 2);
        asm volatile("s_waitcnt vmcnt(4)" ::: "memory");
      } else {
        asm volatile("s_waitcnt vmcnt(0)" ::: "memory");
      })
  }
#undef DO_PHASE
#undef GA
#undef GB

#pragma unroll
  for (int mfr = 0; mfr < 8; ++mfr) {
#pragma unroll
    for (int nf = 0; nf < 4; ++nf) {
      int m0 = mb * 256 + wm * 128 + mfr * 16 + hi * 4;
      int n = wn * 64 + nf * 16 + lo;
      float bval = bias[n];
#pragma unroll
      for (int r = 0; r < 4; ++r) {
        float v = acc[mfr][nf][r] + bval;
        if (RELU) v = fmaxf(v, 0.f);
        int o = (m0 + r) * COUT + n;
        if (OUTF16) out16[o] = (f16)v; else out32[o] = v;
      }
    }
  }
}

// ---------------- implicit-GEMM conv via f16 MFMA (m97 structure, 128x128) --------
template<int HIN, int WIN, int CIN, int HOUT, int WOUT, int COUT, int STRIDE,
         bool RELU, bool OUTF16, int SPLIT, bool ADDBIAS>
__global__ __launch_bounds__(256) void conv_mfma_kernel(const f16* __restrict__ in,
                                                        const f16* __restrict__ wt,
                                                        const float* __restrict__ bias,
                                                        f16* __restrict__ out16,
                                                        float* __restrict__ out32) {
  constexpr int KTOT = 81 * CIN;
  constexpr int NBLK = COUT / 128;
  constexpr int MTOT = 256 * HOUT * WOUT;
  constexpr int MBNB = (MTOT / 128) * NBLK;
  constexpr int NKT = (KTOT / 64) / SPLIT;
  __shared__ __align__(16) f16 lds[16384];
  int bidx = (int)blockIdx.x;
  int ks = 0;
  if (SPLIT > 1) { ks = bidx / MBNB; bidx -= ks * MBNB; }
  const int mb = bidx / NBLK;
  const int nb = bidx % NBLK;
  const int t = threadIdx.x;
  const int wave = t >> 6, lane = t & 63;
  const int hi = lane >> 4, lo = lane & 15;
  const bool isA = wave < 2;
  const int slot0 = wave << 9;

  int baseoff[8];
#pragma unroll
  for (int it = 0; it < 8; ++it) {
    int s = slot0 + it * 64 + lane;
    if (isA) {
      int row = s >> 3;
      int g = (s & 7) ^ (row & 7);
      int mg = mb * 128 + row;
      int b = mg / (HOUT * WOUT);
      int rr = mg - b * (HOUT * WOUT);
      int oh = rr / WOUT;
      int ow = rr - oh * WOUT;
      baseoff[it] = ((b * HIN + oh * STRIDE) * WIN + ow * STRIDE) * CIN + g * 8;
    } else {
      int sl = s - 1024;
      int row = sl >> 3;
      int g = (sl & 7) ^ (row & 7);
      baseoff[it] = (nb * 128 + row) * KTOT + g * 8;
    }
  }
  const f16* gsrc = isA ? in : wt;

  int aQ[4], bQ[4];
  const int wm = wave >> 1, wn = wave & 1;
#pragma unroll
  for (int f = 0; f < 4; ++f) {
    int arow = wm * 64 + f * 16 + lo;
    aQ[f] = (arow * 128) ^ ((arow & 7) << 4);
    int brow = wn * 64 + f * 16 + lo;
    bQ[f] = 16384 + ((brow * 128) ^ ((brow & 7) << 4));
  }

  f32x4 acc[4][4] = {};
  const char* ldsc = (const char*)lds;

  const int kt0 = ks * NKT;
  for (int kt = kt0; kt < kt0 + NKT; ++kt) {
    int tapoff;
    if (isA) tapoff = tapA_off<CIN, WIN>(kt);
    else     tapoff = kt << 6;
    __syncthreads();
#pragma unroll
    for (int it = 0; it < 8; ++it)
      gload_lds16(gsrc + baseoff[it] + tapoff,
                  (void*)((char*)lds + ((slot0 + it * 64) << 4)));
    __syncthreads();
#pragma unroll
    for (int sub = 0; sub < 2; ++sub) {
      const int gx = (sub * 4 + hi) << 4;
      f16x8 av[4], bv[4];
#pragma unroll
      for (int f = 0; f < 4; ++f) av[f] = *(const f16x8*)(ldsc + (aQ[f] ^ gx));
#pragma unroll
      for (int f = 0; f < 4; ++f) bv[f] = *(const f16x8*)(ldsc + (bQ[f] ^ gx));
#pragma unroll
      for (int mf = 0; mf < 4; ++mf)
#pragma unroll
        for (int nf = 0; nf < 4; ++nf)
          acc[mf][nf] = __builtin_amdgcn_mfma_f32_16x16x32_f16(av[mf], bv[nf],
                                                               acc[mf][nf], 0, 0, 0);
    }
  }

  float* o32 = out32 + (size_t)ks * MTOT * COUT;
#pragma unroll
  for (int mf = 0; mf < 4; ++mf) {
#pragma unroll
    for (int nf = 0; nf < 4; ++nf) {
      int m0 = mb * 128 + wm * 64 + mf * 16 + hi * 4;
      int n = nb * 128 + wn * 64 + nf * 16 + lo;
      float bval = ADDBIAS ? bias[n] : 0.f;
#pragma unroll
      for (int r = 0; r < 4; ++r) {
        float v = acc[mf][nf][r] + bval;
        if (RELU) v = fmaxf(v, 0.f);
        int o = (m0 + r) * COUT + n;
        if (OUTF16) out16[o] = (f16)v; else o32[o] = v;
      }
    }
  }
}

// ------- dense GEMM via f16 MFMA, K-split partials: A[256][K] x Bw[NP][K]^T --------
template<int K, int NP, int SPLIT>
__global__ __launch_bounds__(256) void gemm_mfma_kernel(const f16* __restrict__ A,
                                                        const f16* __restrict__ Bw,
                                                        float* __restrict__ dpart) {
  constexpr int NBLK = NP / 128;
  constexpr int MBNB = 2 * NBLK;
  constexpr int NKT = (K / 64) / SPLIT;
  __shared__ __align__(16) f16 lds[16384];
  int bidx = (int)blockIdx.x;
  int ks = 0;
  if (SPLIT > 1) { ks = bidx / MBNB; bidx -= ks * MBNB; }
  const int mb = bidx / NBLK;
  const int nb = bidx % NBLK;
  const int t = threadIdx.x;
  const int wave = t >> 6, lane = t & 63;
  const int hi = lane >> 4, lo = lane & 15;
  const bool isA = wave < 2;
  const int slot0 = wave << 9;

  int baseoff[8];
#pragma unroll
  for (int it = 0; it < 8; ++it) {
    int s = slot0 + it * 64 + lane;
    if (isA) {
      int row = s >> 3;
      int g = (s & 7) ^ (row & 7);
      baseoff[it] = (mb * 128 + row) * K + g * 8;
    } else {
      int sl = s - 1024;
      int row = sl >> 3;
      int g = (sl & 7) ^ (row & 7);
      baseoff[it] = (nb * 128 + row) * K + g * 8;
    }
  }
  const f16* gsrc = isA ? A : Bw;

  int aQ[4], bQ[4];
  const int wm = wave >> 1, wn = wave & 1;
#pragma unroll
  for (int f = 0; f < 4; ++f) {
    int arow = wm * 64 + f * 16 + lo;
    aQ[f] = (arow * 128) ^ ((arow & 7) << 4);
    int brow = wn * 64 + f * 16 + lo;
    bQ[f] = 16384 + ((brow * 128) ^ ((brow & 7) << 4));
  }

  f32x4 acc[4][4] = {};
  const char* ldsc = (const char*)lds;

  const int kt0 = ks * NKT;
  for (int kt = kt0; kt < kt0 + NKT; ++kt) {
    int tapoff = kt << 6;
    __syncthreads();
#pragma unroll
    for (int it = 0; it < 8; ++it)
      gload_lds16(gsrc + baseoff[it] + tapoff,
                  (void*)((char*)lds + ((slot0 + it * 64) << 4)));
    __syncthreads();
#pragma unroll
    for (int sub = 0; sub < 2; ++sub) {
      const int gx = (sub * 4 + hi) << 4;
      f16x8 av[4], bv[4];
#pragma unroll
      for (int f = 0; f < 4; ++f) av[f] = *(const f16x8*)(ldsc + (aQ[f] ^ gx));
#pragma unroll
      for (int f = 0; f < 4; ++f) bv[f] = *(const f16x8*)(ldsc + (bQ[f] ^ gx));
#pragma unroll
      for (int mf = 0; mf < 4; ++mf)
#pragma unroll
        for (int nf = 0; nf < 4; ++nf)
          acc[mf][nf] = __builtin_amdgcn_mfma_f32_16x16x32_f16(av[mf], bv[nf],
                                                               acc[mf][nf], 0, 0, 0);
    }
  }

  float* o32 = dpart + (size_t)ks * 256 * NP;
#pragma unroll
  for (int mf = 0; mf < 4; ++mf) {
#pragma unroll
    for (int nf = 0; nf < 4; ++nf) {
      int m0 = mb * 128 + wm * 64 + mf * 16 + hi * 4;
      int n = nb * 128 + wn * 64 + nf * 16 + lo;
#pragma unroll
      for (int r = 0; r < 4; ++r)
        o32[(m0 + r) * NP + n] = acc[mf][nf][r];
    }
  }
}

// ---------------- d2 reduce: r2 = relu(sum_s part + bias) f16, x4 vec ----------------
__global__ __launch_bounds__(256) void d2red_kernel(const float* __restrict__ part,
                                                    const float* __restrict__ bias,
                                                    f16* __restrict__ r2) {
  int idx = blockIdx.x * 256 + threadIdx.x;  // 512 blocks: 524288/4
  int e0 = idx * 4;
  int n0 = e0 & 2047;
  float4 a = *(const float4*)(part + e0);
  const float4 b1 = *(const float4*)(part + 524288 + e0);
  const float4 b2 = *(const float4*)(part + 1048576 + e0);
  const float4 b3 = *(const float4*)(part + 1572864 + e0);
  float v[4] = {a.x + b1.x + b2.x + b3.x, a.y + b1.y + b2.y + b3.y,
                a.z + b1.z + b2.z + b3.z, a.w + b1.w + b2.w + b3.w};
#pragma unroll
  for (int j = 0; j < 4; ++j)
    r2[e0 + j] = (f16)fmaxf(v[j] + bias[n0 + j], 0.f);
}

// ---------------- d3 reduce: recon = sigmoid(sum_s part + bias), mask n<1600 --------
__global__ __launch_bounds__(256) void d3red_kernel(const float* __restrict__ part,
                                                    const float* __restrict__ bias,
                                                    float* __restrict__ recon) {
  int idx = blockIdx.x * 256 + threadIdx.x;  // 416 blocks: 425984/4
  int e0 = idx * 4;
  int n0 = e0 % 1664;
  int m = e0 / 1664;
  float v[4] = {0.f, 0.f, 0.f, 0.f};
#pragma unroll
  for (int s = 0; s < 8; ++s) {
    float4 a = *(const float4*)(part + s * 425984 + e0);
    v[0] += a.x; v[1] += a.y; v[2] += a.z; v[3] += a.w;
  }
#pragma unroll
  for (int j = 0; j < 4; ++j) {
    int n = n0 + j;
    if (n < 1600)
      recon[m * 1600 + n] = 1.f / (1.f + expf(-(v[j] + bias[n])));
  }
}

// ======================= fused routing =======================
// uhatps: block (b, ic of 9), 320 threads. Folds prim_reduce: u = bias + sum_s part.
// Computes uhat[b, ic*128..+128, :] (f32 weights, L2-resident) and per-half-chunk
// partial sums over i -> parts[b][18][160].
__global__ __launch_bounds__(320) void uhatps_kernel(const float* __restrict__ wf,
                                                     const float* __restrict__ part,
                                                     const float* __restrict__ pbias,
                                                     f16* __restrict__ uh,
                                                     float* __restrict__ parts) {
  __shared__ float pl[128][8];
  int blk = (int)blockIdx.x;
  int b = blk / 9, ic = blk - b * 9;
  int t = threadIdx.x;
  const int base = b * 9216 + ic * 1024;
  for (int e = t; e < 1024; e += 320) {
    float a = pbias[e & 255];
#pragma unroll
    for (int s = 0; s < 4; ++s) a += part[s * 2359296 + base + e];
    pl[e >> 3][e & 7] = a;
  }
  __syncthreads();
  int half = (t >= 160) ? 1 : 0;
  int jk = t - half * 160;
  int ibase = ic * 128 + half * 64;
  float sum = 0.f;
  for (int il = 0; il < 64; ++il) {
    int i = ibase + il;
    const float4* w4 = (const float4*)(wf + (i * 160 + jk) * 8);
    float4 w0 = w4[0], w1 = w4[1];
    const float* pr = pl[half * 64 + il];
    float acc = w0.x * pr[0] + w0.y * pr[1] + w0.z * pr[2] + w0.w * pr[3] +
                w1.x * pr[4] + w1.y * pr[5] + w1.z * pr[6] + w1.w * pr[7];
    uh[(b * 1152 + i) * 160 + jk] = (f16)acc;
    sum += acc;
  }
  parts[(b * 18 + ic * 2 + half) * 160 + jk] = sum;
}

// ba: folds sred (per-block v-compute from psrc) + agreement + blog + softmax +
// partial s -> pdst[b][9][160]. psrc and pdst are DISTINCT buffers (no RW race).
template<int NCH, bool FIRST, bool WRITEB>
__global__ __launch_bounds__(256) void ba_kernel(const f16* __restrict__ uh,
                                                 const float* __restrict__ psrc,
                                                 float cscale,
                                                 float* __restrict__ blog,
                                                 float* __restrict__ pdst) {
  __shared__ f16 ul[128 * 172];   // 44,032 B
  __shared__ float vl[160];
  __shared__ float csm[128 * 10];
  int blk = (int)blockIdx.x;
  int b = blk / 9, ic = blk - b * 9;
  int t = threadIdx.x;
  const f16* ub = uh + (size_t)(b * 1152 + ic * 128) * 160;
  for (int e = t; e < 2560; e += 256) {  // 128 rows x 20 vec8
    int row = e / 20, col = e - row * 20;
    *(f16x8*)(ul + row * 172 + col * 8) = *(const f16x8*)(ub + row * 160 + col * 8);
  }
  if (t < 160) {
    float s = 0.f;
    for (int c = 0; c < NCH; ++c) s += psrc[(b * NCH + c) * 160 + t];
    s *= cscale;
    float ss = s * s;
    ss += __shfl_xor(ss, 1, 16);
    ss += __shfl_xor(ss, 2, 16);
    ss += __shfl_xor(ss, 4, 16);
    ss += __shfl_xor(ss, 8, 16);
    float n = sqrtf(ss);
    float f = ss / ((1.f + ss) * (n + 1e-7f));
    vl[t] = f * s;
  }
  __syncthreads();

  int il = t >> 1, half = t & 1, j0 = half * 5;
  const f16* ur = ul + il * 172 + j0 * 16;
  float agr[5];
#pragma unroll
  for (int j = 0; j < 5; ++j) {
    f16x8 a0 = *(const f16x8*)(ur + j * 16);
    f16x8 a1 = *(const f16x8*)(ur + j * 16 + 8);
    const float* vv = vl + (j0 + j) * 16;
    float s = (float)a0[0] * vv[0] + (float)a0[1] * vv[1] + (float)a0[2] * vv[2] +
              (float)a0[3] * vv[3] + (float)a0[4] * vv[4] + (float)a0[5] * vv[5] +
              (float)a0[6] * vv[6] + (float)a0[7] * vv[7] +
              (float)a1[0] * vv[8] + (float)a1[1] * vv[9] + (float)a1[2] * vv[10] +
              (float)a1[3] * vv[11] + (float)a1[4] * vv[12] + (float)a1[5] * vv[13] +
              (float)a1[6] * vv[14] + (float)a1[7] * vv[15];
    agr[j] = s;
  }
  int bbase = (b * 1152 + ic * 128 + il) * 10 + j0;
  float bl[5];
#pragma unroll
  for (int j = 0; j < 5; ++j) bl[j] = (FIRST ? 0.f : blog[bbase + j]) + agr[j];
  if (WRITEB) {
#pragma unroll
    for (int j = 0; j < 5; ++j) blog[bbase + j] = bl[j];
  }
  float mx = bl[0];
#pragma unroll
  for (int j = 1; j < 5; ++j) mx = fmaxf(mx, bl[j]);
  mx = fmaxf(mx, __shfl_xor(mx, 1));
  float e5[5], se = 0.f;
#pragma unroll
  for (int j = 0; j < 5; ++j) { e5[j] = expf(bl[j] - mx); se += e5[j]; }
  se += __shfl_xor(se, 1);
  float inv = 1.f / se;
#pragma unroll
  for (int j = 0; j < 5; ++j) csm[il * 10 + j0 + j] = e5[j] * inv;
  __syncthreads();

  if (t < 160) {
    int j = t >> 4;
    float s = 0.f;
    for (int il2 = 0; il2 < 128; ++il2)
      s += csm[il2 * 10 + j] * (float)ul[il2 * 172 + t];
    pdst[(b * 9 + ic) * 160 + t] = s;
  }
}

// maskd1v: folds final sred (v3 from parts, writes vout) + mask + dense1.
// Grid 256 (one per b) x 1024 threads.
__global__ __launch_bounds__(1024) void maskd1v_kernel(const float* __restrict__ parts,
                                                       const int* __restrict__ y,
                                                       const float* __restrict__ w1,
                                                       const float* __restrict__ b1,
                                                       float* __restrict__ vout,
                                                       f16* __restrict__ r1) {
  __shared__ float vl[160];
  int b = blockIdx.x, t = threadIdx.x;
  if (t < 160) {
    float s = 0.f;
    for (int c = 0; c < 9; ++c) s += parts[(b * 9 + c) * 160 + t];
    float ss = s * s;
    ss += __shfl_xor(ss, 1, 16);
    ss += __shfl_xor(ss, 2, 16);
    ss += __shfl_xor(ss, 4, 16);
    ss += __shfl_xor(ss, 8, 16);
    float n = sqrtf(ss);
    float f = ss / ((1.f + ss) * (n + 1e-7f));
    float v = f * s;
    vl[t] = v;
    vout[b * 160 + t] = v;
  }
  __syncthreads();
  int yb = y[b];
  float acc = b1[t];
#pragma unroll
  for (int k = 0; k < 16; ++k) acc += vl[yb * 16 + k] * w1[(yb * 16 + k) * 1024 + t];
  r1[b * 1024 + t] = (f16)fmaxf(acc, 0.f);
}

// ---------------- launch ----------------
extern "C" void kernel_launch(void* const* d_in, const int* in_sizes, int n_in,
                              void* d_out, int out_size, void* d_ws, size_t ws_size,
                              hipStream_t stream) {
  const float* x       = (const float*)d_in[0];
  const int*   y       = (const int*)d_in[1];
  const float* conv1_k = (const float*)d_in[2];
  const float* conv1_b = (const float*)d_in[3];
  const float* conv2_k = (const float*)d_in[4];
  const float* conv2_b = (const float*)d_in[5];
  const float* conv3_k = (const float*)d_in[6];
  const float* conv3_b = (const float*)d_in[7];
  const float* prim_k  = (const float*)d_in[8];
  const float* prim_b  = (const float*)d_in[9];
  const float* w_route = (const float*)d_in[10];
  const float* d1_w = (const float*)d_in[11];
  const float* d1_b = (const float*)d_in[12];
  const float* d2_w = (const float*)d_in[13];
  const float* d2_b = (const float*)d_in[14];
  const float* d3_w = (const float*)d_in[15];
  const float* d3_b = (const float*)d_in[16];

  // workspace layout (bytes), total 191,021,056 (same as R1-R8 -> proven fits).
  // Liveness: h1@0 (t:conv1-conv2) -> part@0 (prim-uhatps) -> dpart2@0/dpart3@16.7M
  //           h2@42.4M (conv2-conv3) / h3@93.8M (conv3-prim) -> uhat@42.4M (uhatps-ba2)
  //           wtp@177.5M dies after prim -> wd2/wd3 written there by wprepd (post-prim)
  char* ws = (char*)d_ws;
  f16*   h1      = (f16*)(ws + 0);
  float* part    = (float*)(ws + 0);                 // 4 x 9,437,184 B
  float* dpart2  = (float*)(ws + 0);                 //  8,388,608 B
  float* dpart3  = (float*)(ws + 16777216);          // 13,631,488 B
  f16*   h2      = (f16*)(ws + 42467328);
  f16*   uhat    = (f16*)(ws + 42467328);            // 94,371,840 B (h2,h3 dead)
  f16*   h3      = (f16*)(ws + 93847552);
  float* parts_a = (float*)(ws + 146276352);         //  2,949,120 B
  float* parts_b = (float*)(ws + 149225472);         //  1,474,560 B
  float* blog    = (float*)(ws + 155713536);         // 11,796,480 B
  f16*   r1h     = (f16*)(ws + 167673856);           //    524,288 B
  f16*   r2h     = (f16*)(ws + 168198144);           //  1,048,576 B
  f16*   wt2     = (f16*)(ws + 170819584);           //  1,327,104 B
  f16*   wt3     = (f16*)(ws + 172146688);           //  5,308,416 B
  f16*   wtp     = (f16*)(ws + 177455104);           // 10,616,832 B (dead after prim)
  f16*   wd2     = (f16*)(ws + 177455104);           //  4,194,304 B (alias wtp)
  f16*   wd3     = (f16*)(ws + 181649408);           //  6,815,744 B -> ends 188,465,152

  float* vout  = (float*)d_out;            // [256,1,10,16] = 40960 f32
  float* recon = (float*)d_out + 40960;    // [256,1600]

  // conv weight prep (one launch)
  wprepc_kernel<<<2106, 256, 0, stream>>>(conv2_k, wt2, conv3_k, wt3, prim_k, wtp);

  // conv stack
  conv1_kernel<<<10368, 256, 0, stream>>>(x, conv1_k, conv1_b, h1);
  conv_mfma_kernel<36, 36, 64, 28, 28, 128, 1, true, true, 1, true>
      <<<1568, 256, 0, stream>>>(h1, wt2, conv2_b, h2, nullptr);
  conv8p_kernel<28, 28, 128, 20, 20, 256, 1, true, true>
      <<<400, 512, 0, stream>>>(h2, wt3, conv3_b, h3, nullptr);
  conv_mfma_kernel<20, 20, 256, 6, 6, 256, 2, false, false, 4, false>
      <<<576, 256, 0, stream>>>(h3, wtp, prim_b, nullptr, part);

  // fused routing (prim_reduce folded into uhatps; sred folded into ba/maskd1v)
  uhatps_kernel<<<2304, 320, 0, stream>>>(w_route, part, prim_b, uhat, parts_a);
  wprepd_kernel<<<1344, 256, 0, stream>>>(d2_w, wd2, d3_w, wd3);  // wtp dead now
  ba_kernel<18, true, true><<<2304, 256, 0, stream>>>(uhat, parts_a, 0.1f, blog, parts_b);
  ba_kernel<9, false, false><<<2304, 256, 0, stream>>>(uhat, parts_b, 1.0f, blog, parts_a);

  // masked reconstruction
  maskd1v_kernel<<<256, 1024, 0, stream>>>(parts_a, y, d1_w, d1_b, vout, r1h);
  gemm_mfma_kernel<1024, 2048, 4><<<128, 256, 0, stream>>>(r1h, wd2, dpart2);
  d2red_kernel<<<512, 256, 0, stream>>>(dpart2, d2_b, r2h);
  gemm_mfma_kernel<2048, 1664, 8><<<208, 256, 0, stream>>>(r2h, wd3, dpart3);
  d3red_kernel<<<416, 256, 0, stream>>>(dpart3, d3_b, recon);
}

// Round 10
// 1200.673 us; speedup vs baseline: 1.0487x; 1.0209x over previous
//
#include <hip/hip_runtime.h>
#include <hip/hip_bf16.h>

typedef _Float16 f16;
typedef __attribute__((ext_vector_type(8))) _Float16 f16x8;
typedef __attribute__((ext_vector_type(4))) float f32x4;

// ---------------- global_load_lds helper (16B, wave-uniform LDS base + lane*16) ----
__device__ __forceinline__ void gload_lds16(const void* g, void* l) {
  __builtin_amdgcn_global_load_lds((const __attribute__((address_space(1))) void*)g,
                                   (__attribute__((address_space(3))) void*)l, 16, 0, 0);
}

// ---------------- generic weight transpose body: [K][N] f32 -> [NP][K] f16 ----------
__device__ __forceinline__ void wtrans_body(const float* __restrict__ src,
                                            f16* __restrict__ dst,
                                            int K, int N, int k0, int n0) {
  __shared__ float tile[64][65];
  int t = threadIdx.x;
#pragma unroll
  for (int i = 0; i < 16; ++i) {
    int id = t + i * 256;
    int r = id >> 6, c = id & 63;  // r = k_local, c = n_local
    tile[r][c] = (n0 + c < N) ? src[(size_t)(k0 + r) * N + n0 + c] : 0.f;
  }
  __syncthreads();
#pragma unroll
  for (int i = 0; i < 16; ++i) {
    int id = t + i * 256;
    int r = id >> 6, c = id & 63;  // r = n_local, c = k_local
    dst[(size_t)(n0 + r) * K + k0 + c] = (f16)tile[c][r];
  }
}

// wprepc: conv weight prep (3 jobs): conv2 (K=5184,N=128), conv3 (10368,256),
// prim (20736,256). Grid 162 + 648 + 1296 = 2106.
__global__ __launch_bounds__(256) void wprepc_kernel(const float* __restrict__ s0, f16* __restrict__ d0,
                                                     const float* __restrict__ s1, f16* __restrict__ d1,
                                                     const float* __restrict__ s2, f16* __restrict__ d2) {
  int bid = (int)blockIdx.x;
  if (bid < 162) {
    int bx = bid % 81, by = bid / 81;
    wtrans_body(s0, d0, 5184, 128, bx * 64, by * 64);
  } else if (bid < 810) {
    int l = bid - 162; int bx = l % 162, by = l / 162;
    wtrans_body(s1, d1, 10368, 256, bx * 64, by * 64);
  } else {
    int l = bid - 810; int bx = l % 324, by = l / 324;
    wtrans_body(s2, d2, 20736, 256, bx * 64, by * 64);
  }
}

// wprepd: dense weight prep (2 jobs): d2 (K=1024,N=2048), d3 (K=2048,N=1600,NP=1664).
__global__ __launch_bounds__(256) void wprepd_kernel(const float* __restrict__ s0, f16* __restrict__ d0,
                                                     const float* __restrict__ s1, f16* __restrict__ d1) {
  int bid = (int)blockIdx.x;
  if (bid < 512) {
    int bx = bid % 16, by = bid / 16;
    wtrans_body(s0, d0, 1024, 2048, bx * 64, by * 64);
  } else {
    int l = bid - 512; int bx = l % 32, by = l / 32;
    wtrans_body(s1, d1, 2048, 1600, bx * 64, by * 64);
  }
}

// ---------------- conv1: 5x5, Cin=1, Cout=64, relu, f16 out (8 couts/thread) -------
__global__ __launch_bounds__(256) void conv1_kernel(const float* __restrict__ x,
                                                    const float* __restrict__ kw,
                                                    const float* __restrict__ bias,
                                                    f16* __restrict__ out) {
  int idx = blockIdx.x * 256 + threadIdx.x;  // 256*36*36*8 threads
  int g = idx & 7;
  int co0 = g * 8;
  int r = idx >> 3;
  int ow = r % 36; int r2 = r / 36; int oh = r2 % 36; int b = r2 / 36;
  float acc[8];
#pragma unroll
  for (int j = 0; j < 8; ++j) acc[j] = bias[co0 + j];
  const float* xp = x + (b * 40 + oh) * 40 + ow;
#pragma unroll
  for (int dy = 0; dy < 5; ++dy)
#pragma unroll
    for (int dx = 0; dx < 5; ++dx) {
      float xv = xp[dy * 40 + dx];
      const float* kp = kw + (dy * 5 + dx) * 64 + co0;
#pragma unroll
      for (int j = 0; j < 8; ++j) acc[j] += xv * kp[j];
    }
  f16x8 o;
#pragma unroll
  for (int j = 0; j < 8; ++j) o[j] = (f16)fmaxf(acc[j], 0.f);
  *(f16x8*)(out + r * 64 + co0) = o;
}

// ---------------- im2col tap offset helper (BK=64 chunks) ----------------
template<int CIN, int WIN>
__device__ __forceinline__ int tapA_off(int kt) {
  int tap, ci0;
  if (CIN == 64)       { tap = kt;      ci0 = 0; }
  else if (CIN == 128) { tap = kt >> 1; ci0 = (kt & 1) << 6; }
  else                 { tap = kt >> 2; ci0 = (kt & 3) << 6; }
  int dy = tap / 9, dx = tap - dy * 9;
  return (dy * WIN + dx) * CIN + ci0;
}

// ============ 8-phase 256x256 implicit-GEMM conv + K-third tail smoothing ===========
// BM=BN=256, BK=64, 8 waves (2Mx4N). LDS 128KB dbuf. XOR-swizzle ((row&7)<<4).
// Grid = FULLB + 3*TAILB. bids < FULLB: full K, write out. Else: one K-third of a
// tail tile -> raw f16 partials (pieces 0,1 -> tp01; piece 2 -> tp2), reduced by
// tailred3_kernel. Buffer parity is absolute (tile&1); thirds are even (54) so
// parity is consistent; staging predicates use [kt0, kt1).
template<int HIN, int WIN, int CIN, int HOUT, int WOUT, int COUT, int STRIDE,
         bool RELU, bool OUTF16, int FULLB, int TAILB>
__global__ __launch_bounds__(512, 2) void conv8p_kernel(const f16* __restrict__ in,
                                                        const f16* __restrict__ wt,
                                                        const float* __restrict__ bias,
                                                        f16* __restrict__ out16,
                                                        float* __restrict__ out32,
                                                        f16* __restrict__ tp01,
                                                        f16* __restrict__ tp2) {
  static_assert(COUT == 256, "BN=256 template requires COUT==256");
  constexpr int KTOT = 81 * CIN;
  constexpr int NT = KTOT / 64;
  static_assert(TAILB == 0 || NT % 3 == 0, "K-third split requires NT%3==0");
  constexpr int PNT = (TAILB > 0) ? NT / 3 : NT;
  __shared__ __align__(16) f16 lds[65536];  // 128 KiB
  const int bid = (int)blockIdx.x;
  int mb, kt0, kt1;
  f16* tp = nullptr;
  if (TAILB == 0 || bid < FULLB) {
    mb = bid; kt0 = 0; kt1 = NT;
  } else {
    int idx = bid - FULLB;
    int piece = idx / TAILB;           // 0,1,2
    int loc = idx - piece * TAILB;
    mb = FULLB + loc;
    kt0 = piece * PNT; kt1 = kt0 + PNT;
    tp = (piece < 2 ? tp01 + (size_t)piece * TAILB * 65536 : tp2) + (size_t)loc * 65536;
  }
  const int t = threadIdx.x;
  const int wave = t >> 6, lane = t & 63;
  const int hi = lane >> 4, lo = lane & 15;
  const int wm = wave >> 2, wn = wave & 3;

  int Aoff[4], Boff[4];
  {
    int g = (lane & 7) ^ ((lane >> 3) & 7);  // inverse swizzle granule
#pragma unroll
    for (int rbi = 0; rbi < 4; ++rbi) {
      int r = rbi * 64 + 8 * wave + (lane >> 3);
      int m = mb * 256 + r;
      int b = m / (HOUT * WOUT);
      int rr = m - b * (HOUT * WOUT);
      int oh = rr / WOUT, ow = rr - oh * WOUT;
      Aoff[rbi] = ((b * HIN + oh * STRIDE) * WIN + ow * STRIDE) * CIN + g * 8;
      Boff[rbi] = r * KTOT + g * 8;
    }
  }
  const int gb0 = (hi ^ (lo & 7)) << 4;
  const int gb1 = ((4 + hi) ^ (lo & 7)) << 4;

  const char* ldsc = (const char*)lds;
  char* ldsw = (char*)lds;

#define GA(rbi, tpo, bq) gload_lds16(in + Aoff[rbi] + (tpo),                        \
    (void*)(ldsw + (bq) * 32768 + ((rbi) * 64 + 8 * wave) * 128))
#define GB(rbi, tile) gload_lds16(wt + Boff[rbi] + ((tile) << 6),                   \
    (void*)(ldsw + 65536 + ((tile) & 1) * 32768 + ((rbi) * 64 + 8 * wave) * 128))

  // Prologue: tile kt0 full (A then B), tile kt0+1 B. vmcnt(4) -> tile kt0 landed.
  {
    int tq = tapA_off<CIN, WIN>(kt0);
    int bq = kt0 & 1;
    GA(0, tq, bq); GA(2, tq, bq); GA(1, tq, bq); GA(3, tq, bq);
    GB(0, kt0); GB(1, kt0); GB(2, kt0); GB(3, kt0);
    GB(0, kt0 + 1); GB(1, kt0 + 1); GB(2, kt0 + 1); GB(3, kt0 + 1);
    asm volatile("s_waitcnt vmcnt(4)" ::: "memory");
    __builtin_amdgcn_s_barrier();
  }

  f32x4 acc[8][4] = {};

#define DO_PHASE(Q, STAGE)                                                          \
  {                                                                                 \
    f16x8 af[2][2];                                                                 \
    _Pragma("unroll")                                                               \
    for (int mf = 0; mf < 2; ++mf) {                                                \
      af[mf][0] = *(const f16x8*)(Ab + ((Q) * 2 + mf) * 2048 + gb0);                \
      af[mf][1] = *(const f16x8*)(Ab + ((Q) * 2 + mf) * 2048 + gb1);                \
    }                                                                               \
    STAGE;                                                                          \
    __builtin_amdgcn_s_barrier();                                                   \
    asm volatile("s_waitcnt lgkmcnt(0)" ::: "memory");                              \
    __builtin_amdgcn_sched_barrier(0);                                              \
    __builtin_amdgcn_s_setprio(1);                                                  \
    _Pragma("unroll")                                                               \
    for (int sb = 0; sb < 2; ++sb)                                                  \
      _Pragma("unroll")                                                             \
      for (int mf = 0; mf < 2; ++mf)                                                \
        _Pragma("unroll")                                                           \
        for (int nf = 0; nf < 4; ++nf)                                              \
          acc[(Q) * 2 + mf][nf] = __builtin_amdgcn_mfma_f32_16x16x32_f16(           \
              af[mf][sb], bfr[nf][sb], acc[(Q) * 2 + mf][nf], 0, 0, 0);             \
    __builtin_amdgcn_s_setprio(0);                                                  \
    __builtin_amdgcn_s_barrier();                                                   \
  }

  for (int T = kt0; T < kt1; ++T) {
    const int q = T & 1;
    const char* Ab = ldsc + q * 32768 + wm * 16384 + lo * 128;
    const char* Bb = ldsc + 65536 + q * 32768 + wn * 8192 + lo * 128;
    const int tpn = tapA_off<CIN, WIN>(T + 1);  // used only if T+1 < kt1
    f16x8 bfr[4][2];
#pragma unroll
    for (int nf = 0; nf < 4; ++nf) {
      bfr[nf][0] = *(const f16x8*)(Bb + nf * 2048 + gb0);
      bfr[nf][1] = *(const f16x8*)(Bb + nf * 2048 + gb1);
    }
    DO_PHASE(0, if (T + 1 < kt1) { GA(0, tpn, (T + 1) & 1); GA(2, tpn, (T + 1) & 1); })
    DO_PHASE(1, if (T + 1 < kt1) { GA(1, tpn, (T + 1) & 1); GA(3, tpn, (T + 1) & 1); })
    DO_PHASE(2, if (T + 2 < kt1) { GB(0, T + 2); GB(1, T + 2); })
    DO_PHASE(3,
      if (T + 2 < kt1) {
        GB(2, T + 2); GB(3, T + 2);
        asm volatile("s_waitcnt vmcnt(4)" ::: "memory");
      } else {
        asm volatile("s_waitcnt vmcnt(0)" ::: "memory");
      })
  }
#undef DO_PHASE
#undef GA
#undef GB

  // Epilogue: C/D layout col = lane&15, row = (lane>>4)*4 + reg
  if (tp == nullptr) {
#pragma unroll
    for (int mfr = 0; mfr < 8; ++mfr) {
#pragma unroll
      for (int nf = 0; nf < 4; ++nf) {
        int m0 = mb * 256 + wm * 128 + mfr * 16 + hi * 4;
        int n = wn * 64 + nf * 16 + lo;
        float bval = bias[n];
#pragma unroll
        for (int r = 0; r < 4; ++r) {
          float v = acc[mfr][nf][r] + bval;
          if (RELU) v = fmaxf(v, 0.f);
          int o = (m0 + r) * COUT + n;
          if (OUTF16) out16[o] = (f16)v; else out32[o] = v;
        }
      }
    }
  } else {
#pragma unroll
    for (int mfr = 0; mfr < 8; ++mfr) {
#pragma unroll
      for (int nf = 0; nf < 4; ++nf) {
        int rowloc = wm * 128 + mfr * 16 + hi * 4;
        int n = wn * 64 + nf * 16 + lo;
#pragma unroll
        for (int r = 0; r < 4; ++r)
          tp[(rowloc + r) * 256 + n] = (f16)acc[mfr][nf][r];
      }
    }
  }
}

// ------- tail reduce: h3[tail rows] = relu(p0 + p1 + p2 + bias), x8 vec -----------
__global__ __launch_bounds__(256) void tailred3_kernel(const f16* __restrict__ tp01,
                                                       const f16* __restrict__ tp2,
                                                       const float* __restrict__ bias,
                                                       f16* __restrict__ h3) {
  int idx = blockIdx.x * 256 + threadIdx.x;  // 4608 blocks: 9,437,184 elems / 8
  int e0 = idx * 8;
  int n0 = e0 & 255;
  f16x8 a = *(const f16x8*)(tp01 + e0);
  f16x8 b = *(const f16x8*)(tp01 + 9437184 + e0);
  f16x8 c = *(const f16x8*)(tp2 + e0);
  f16x8 o;
#pragma unroll
  for (int j = 0; j < 8; ++j) {
    float v = (float)a[j] + (float)b[j] + (float)c[j] + bias[n0 + j];
    o[j] = (f16)fmaxf(v, 0.f);
  }
  *(f16x8*)(h3 + 16777216 + e0) = o;  // tail tiles start at m = 256*256
}

// ---------------- implicit-GEMM conv via f16 MFMA (m97 structure, 128x128) --------
template<int HIN, int WIN, int CIN, int HOUT, int WOUT, int COUT, int STRIDE,
         bool RELU, bool OUTF16, int SPLIT, bool ADDBIAS>
__global__ __launch_bounds__(256) void conv_mfma_kernel(const f16* __restrict__ in,
                                                        const f16* __restrict__ wt,
                                                        const float* __restrict__ bias,
                                                        f16* __restrict__ out16,
                                                        float* __restrict__ out32) {
  constexpr int KTOT = 81 * CIN;
  constexpr int NBLK = COUT / 128;
  constexpr int MTOT = 256 * HOUT * WOUT;
  constexpr int MBNB = (MTOT / 128) * NBLK;
  constexpr int NKT = (KTOT / 64) / SPLIT;
  __shared__ __align__(16) f16 lds[16384];
  int bidx = (int)blockIdx.x;
  int ks = 0;
  if (SPLIT > 1) { ks = bidx / MBNB; bidx -= ks * MBNB; }
  const int mb = bidx / NBLK;
  const int nb = bidx % NBLK;
  const int t = threadIdx.x;
  const int wave = t >> 6, lane = t & 63;
  const int hi = lane >> 4, lo = lane & 15;
  const bool isA = wave < 2;
  const int slot0 = wave << 9;

  int baseoff[8];
#pragma unroll
  for (int it = 0; it < 8; ++it) {
    int s = slot0 + it * 64 + lane;
    if (isA) {
      int row = s >> 3;
      int g = (s & 7) ^ (row & 7);
      int mg = mb * 128 + row;
      int b = mg / (HOUT * WOUT);
      int rr = mg - b * (HOUT * WOUT);
      int oh = rr / WOUT;
      int ow = rr - oh * WOUT;
      baseoff[it] = ((b * HIN + oh * STRIDE) * WIN + ow * STRIDE) * CIN + g * 8;
    } else {
      int sl = s - 1024;
      int row = sl >> 3;
      int g = (sl & 7) ^ (row & 7);
      baseoff[it] = (nb * 128 + row) * KTOT + g * 8;
    }
  }
  const f16* gsrc = isA ? in : wt;

  int aQ[4], bQ[4];
  const int wm = wave >> 1, wn = wave & 1;
#pragma unroll
  for (int f = 0; f < 4; ++f) {
    int arow = wm * 64 + f * 16 + lo;
    aQ[f] = (arow * 128) ^ ((arow & 7) << 4);
    int brow = wn * 64 + f * 16 + lo;
    bQ[f] = 16384 + ((brow * 128) ^ ((brow & 7) << 4));
  }

  f32x4 acc[4][4] = {};
  const char* ldsc = (const char*)lds;

  const int kt0 = ks * NKT;
  for (int kt = kt0; kt < kt0 + NKT; ++kt) {
    int tapoff;
    if (isA) tapoff = tapA_off<CIN, WIN>(kt);
    else     tapoff = kt << 6;
    __syncthreads();
#pragma unroll
    for (int it = 0; it < 8; ++it)
      gload_lds16(gsrc + baseoff[it] + tapoff,
                  (void*)((char*)lds + ((slot0 + it * 64) << 4)));
    __syncthreads();
#pragma unroll
    for (int sub = 0; sub < 2; ++sub) {
      const int gx = (sub * 4 + hi) << 4;
      f16x8 av[4], bv[4];
#pragma unroll
      for (int f = 0; f < 4; ++f) av[f] = *(const f16x8*)(ldsc + (aQ[f] ^ gx));
#pragma unroll
      for (int f = 0; f < 4; ++f) bv[f] = *(const f16x8*)(ldsc + (bQ[f] ^ gx));
#pragma unroll
      for (int mf = 0; mf < 4; ++mf)
#pragma unroll
        for (int nf = 0; nf < 4; ++nf)
          acc[mf][nf] = __builtin_amdgcn_mfma_f32_16x16x32_f16(av[mf], bv[nf],
                                                               acc[mf][nf], 0, 0, 0);
    }
  }

  float* o32 = out32 + (size_t)ks * MTOT * COUT;
#pragma unroll
  for (int mf = 0; mf < 4; ++mf) {
#pragma unroll
    for (int nf = 0; nf < 4; ++nf) {
      int m0 = mb * 128 + wm * 64 + mf * 16 + hi * 4;
      int n = nb * 128 + wn * 64 + nf * 16 + lo;
      float bval = ADDBIAS ? bias[n] : 0.f;
#pragma unroll
      for (int r = 0; r < 4; ++r) {
        float v = acc[mf][nf][r] + bval;
        if (RELU) v = fmaxf(v, 0.f);
        int o = (m0 + r) * COUT + n;
        if (OUTF16) out16[o] = (f16)v; else o32[o] = v;
      }
    }
  }
}

// ------- dense GEMM via f16 MFMA, K-split partials: A[256][K] x Bw[NP][K]^T --------
template<int K, int NP, int SPLIT>
__global__ __launch_bounds__(256) void gemm_mfma_kernel(const f16* __restrict__ A,
                                                        const f16* __restrict__ Bw,
                                                        float* __restrict__ dpart) {
  constexpr int NBLK = NP / 128;
  constexpr int MBNB = 2 * NBLK;
  constexpr int NKT = (K / 64) / SPLIT;
  __shared__ __align__(16) f16 lds[16384];
  int bidx = (int)blockIdx.x;
  int ks = 0;
  if (SPLIT > 1) { ks = bidx / MBNB; bidx -= ks * MBNB; }
  const int mb = bidx / NBLK;
  const int nb = bidx % NBLK;
  const int t = threadIdx.x;
  const int wave = t >> 6, lane = t & 63;
  const int hi = lane >> 4, lo = lane & 15;
  const bool isA = wave < 2;
  const int slot0 = wave << 9;

  int baseoff[8];
#pragma unroll
  for (int it = 0; it < 8; ++it) {
    int s = slot0 + it * 64 + lane;
    if (isA) {
      int row = s >> 3;
      int g = (s & 7) ^ (row & 7);
      baseoff[it] = (mb * 128 + row) * K + g * 8;
    } else {
      int sl = s - 1024;
      int row = sl >> 3;
      int g = (sl & 7) ^ (row & 7);
      baseoff[it] = (nb * 128 + row) * K + g * 8;
    }
  }
  const f16* gsrc = isA ? A : Bw;

  int aQ[4], bQ[4];
  const int wm = wave >> 1, wn = wave & 1;
#pragma unroll
  for (int f = 0; f < 4; ++f) {
    int arow = wm * 64 + f * 16 + lo;
    aQ[f] = (arow * 128) ^ ((arow & 7) << 4);
    int brow = wn * 64 + f * 16 + lo;
    bQ[f] = 16384 + ((brow * 128) ^ ((brow & 7) << 4));
  }

  f32x4 acc[4][4] = {};
  const char* ldsc = (const char*)lds;

  const int kt0 = ks * NKT;
  for (int kt = kt0; kt < kt0 + NKT; ++kt) {
    int tapoff = kt << 6;
    __syncthreads();
#pragma unroll
    for (int it = 0; it < 8; ++it)
      gload_lds16(gsrc + baseoff[it] + tapoff,
                  (void*)((char*)lds + ((slot0 + it * 64) << 4)));
    __syncthreads();
#pragma unroll
    for (int sub = 0; sub < 2; ++sub) {
      const int gx = (sub * 4 + hi) << 4;
      f16x8 av[4], bv[4];
#pragma unroll
      for (int f = 0; f < 4; ++f) av[f] = *(const f16x8*)(ldsc + (aQ[f] ^ gx));
#pragma unroll
      for (int f = 0; f < 4; ++f) bv[f] = *(const f16x8*)(ldsc + (bQ[f] ^ gx));
#pragma unroll
      for (int mf = 0; mf < 4; ++mf)
#pragma unroll
        for (int nf = 0; nf < 4; ++nf)
          acc[mf][nf] = __builtin_amdgcn_mfma_f32_16x16x32_f16(av[mf], bv[nf],
                                                               acc[mf][nf], 0, 0, 0);
    }
  }

  float* o32 = dpart + (size_t)ks * 256 * NP;
#pragma unroll
  for (int mf = 0; mf < 4; ++mf) {
#pragma unroll
    for (int nf = 0; nf < 4; ++nf) {
      int m0 = mb * 128 + wm * 64 + mf * 16 + hi * 4;
      int n = nb * 128 + wn * 64 + nf * 16 + lo;
#pragma unroll
      for (int r = 0; r < 4; ++r)
        o32[(m0 + r) * NP + n] = acc[mf][nf][r];
    }
  }
}

// ---------------- d2 reduce: r2 = relu(sum_s part + bias) f16, x4 vec ----------------
__global__ __launch_bounds__(256) void d2red_kernel(const float* __restrict__ part,
                                                    const float* __restrict__ bias,
                                                    f16* __restrict__ r2) {
  int idx = blockIdx.x * 256 + threadIdx.x;  // 512 blocks: 524288/4
  int e0 = idx * 4;
  int n0 = e0 & 2047;
  float4 a = *(const float4*)(part + e0);
  const float4 b1 = *(const float4*)(part + 524288 + e0);
  const float4 b2 = *(const float4*)(part + 1048576 + e0);
  const float4 b3 = *(const float4*)(part + 1572864 + e0);
  float v[4] = {a.x + b1.x + b2.x + b3.x, a.y + b1.y + b2.y + b3.y,
                a.z + b1.z + b2.z + b3.z, a.w + b1.w + b2.w + b3.w};
#pragma unroll
  for (int j = 0; j < 4; ++j)
    r2[e0 + j] = (f16)fmaxf(v[j] + bias[n0 + j], 0.f);
}

// ---------------- d3 reduce: recon = sigmoid(sum_s part + bias), mask n<1600 --------
__global__ __launch_bounds__(256) void d3red_kernel(const float* __restrict__ part,
                                                    const float* __restrict__ bias,
                                                    float* __restrict__ recon) {
  int idx = blockIdx.x * 256 + threadIdx.x;  // 416 blocks: 425984/4
  int e0 = idx * 4;
  int n0 = e0 % 1664;
  int m = e0 / 1664;
  float v[4] = {0.f, 0.f, 0.f, 0.f};
#pragma unroll
  for (int s = 0; s < 8; ++s) {
    float4 a = *(const float4*)(part + s * 425984 + e0);
    v[0] += a.x; v[1] += a.y; v[2] += a.z; v[3] += a.w;
  }
#pragma unroll
  for (int j = 0; j < 4; ++j) {
    int n = n0 + j;
    if (n < 1600)
      recon[m * 1600 + n] = 1.f / (1.f + expf(-(v[j] + bias[n])));
  }
}

// ======================= fused routing =======================
__global__ __launch_bounds__(320) void uhatps_kernel(const float* __restrict__ wf,
                                                     const float* __restrict__ part,
                                                     const float* __restrict__ pbias,
                                                     f16* __restrict__ uh,
                                                     float* __restrict__ parts) {
  __shared__ float pl[128][8];
  int blk = (int)blockIdx.x;
  int b = blk / 9, ic = blk - b * 9;
  int t = threadIdx.x;
  const int base = b * 9216 + ic * 1024;
  for (int e = t; e < 1024; e += 320) {
    float a = pbias[e & 255];
#pragma unroll
    for (int s = 0; s < 4; ++s) a += part[s * 2359296 + base + e];
    pl[e >> 3][e & 7] = a;
  }
  __syncthreads();
  int half = (t >= 160) ? 1 : 0;
  int jk = t - half * 160;
  int ibase = ic * 128 + half * 64;
  float sum = 0.f;
  for (int il = 0; il < 64; ++il) {
    int i = ibase + il;
    const float4* w4 = (const float4*)(wf + (i * 160 + jk) * 8);
    float4 w0 = w4[0], w1 = w4[1];
    const float* pr = pl[half * 64 + il];
    float acc = w0.x * pr[0] + w0.y * pr[1] + w0.z * pr[2] + w0.w * pr[3] +
                w1.x * pr[4] + w1.y * pr[5] + w1.z * pr[6] + w1.w * pr[7];
    uh[(b * 1152 + i) * 160 + jk] = (f16)acc;
    sum += acc;
  }
  parts[(b * 18 + ic * 2 + half) * 160 + jk] = sum;
}

template<int NCH, bool FIRST, bool WRITEB>
__global__ __launch_bounds__(256) void ba_kernel(const f16* __restrict__ uh,
                                                 const float* __restrict__ psrc,
                                                 float cscale,
                                                 float* __restrict__ blog,
                                                 float* __restrict__ pdst) {
  __shared__ f16 ul[128 * 172];   // 44,032 B
  __shared__ float vl[160];
  __shared__ float csm[128 * 10];
  int blk = (int)blockIdx.x;
  int b = blk / 9, ic = blk - b * 9;
  int t = threadIdx.x;
  const f16* ub = uh + (size_t)(b * 1152 + ic * 128) * 160;
  for (int e = t; e < 2560; e += 256) {  // 128 rows x 20 vec8
    int row = e / 20, col = e - row * 20;
    *(f16x8*)(ul + row * 172 + col * 8) = *(const f16x8*)(ub + row * 160 + col * 8);
  }
  if (t < 160) {
    float s = 0.f;
    for (int c = 0; c < NCH; ++c) s += psrc[(b * NCH + c) * 160 + t];
    s *= cscale;
    float ss = s * s;
    ss += __shfl_xor(ss, 1, 16);
    ss += __shfl_xor(ss, 2, 16);
    ss += __shfl_xor(ss, 4, 16);
    ss += __shfl_xor(ss, 8, 16);
    float n = sqrtf(ss);
    float f = ss / ((1.f + ss) * (n + 1e-7f));
    vl[t] = f * s;
  }
  __syncthreads();

  int il = t >> 1, half = t & 1, j0 = half * 5;
  const f16* ur = ul + il * 172 + j0 * 16;
  float agr[5];
#pragma unroll
  for (int j = 0; j < 5; ++j) {
    f16x8 a0 = *(const f16x8*)(ur + j * 16);
    f16x8 a1 = *(const f16x8*)(ur + j * 16 + 8);
    const float* vv = vl + (j0 + j) * 16;
    float s = (float)a0[0] * vv[0] + (float)a0[1] * vv[1] + (float)a0[2] * vv[2] +
              (float)a0[3] * vv[3] + (float)a0[4] * vv[4] + (float)a0[5] * vv[5] +
              (float)a0[6] * vv[6] + (float)a0[7] * vv[7] +
              (float)a1[0] * vv[8] + (float)a1[1] * vv[9] + (float)a1[2] * vv[10] +
              (float)a1[3] * vv[11] + (float)a1[4] * vv[12] + (float)a1[5] * vv[13] +
              (float)a1[6] * vv[14] + (float)a1[7] * vv[15];
    agr[j] = s;
  }
  int bbase = (b * 1152 + ic * 128 + il) * 10 + j0;
  float bl[5];
#pragma unroll
  for (int j = 0; j < 5; ++j) bl[j] = (FIRST ? 0.f : blog[bbase + j]) + agr[j];
  if (WRITEB) {
#pragma unroll
    for (int j = 0; j < 5; ++j) blog[bbase + j] = bl[j];
  }
  float mx = bl[0];
#pragma unroll
  for (int j = 1; j < 5; ++j) mx = fmaxf(mx, bl[j]);
  mx = fmaxf(mx, __shfl_xor(mx, 1));
  float e5[5], se = 0.f;
#pragma unroll
  for (int j = 0; j < 5; ++j) { e5[j] = expf(bl[j] - mx); se += e5[j]; }
  se += __shfl_xor(se, 1);
  float inv = 1.f / se;
#pragma unroll
  for (int j = 0; j < 5; ++j) csm[il * 10 + j0 + j] = e5[j] * inv;
  __syncthreads();

  if (t < 160) {
    int j = t >> 4;
    float s = 0.f;
    for (int il2 = 0; il2 < 128; ++il2)
      s += csm[il2 * 10 + j] * (float)ul[il2 * 172 + t];
    pdst[(b * 9 + ic) * 160 + t] = s;
  }
}

// maskd1v: folds final sred (v3 from parts, writes vout) + mask + dense1.
__global__ __launch_bounds__(1024) void maskd1v_kernel(const float* __restrict__ parts,
                                                       const int* __restrict__ y,
                                                       const float* __restrict__ w1,
                                                       const float* __restrict__ b1,
                                                       float* __restrict__ vout,
                                                       f16* __restrict__ r1) {
  __shared__ float vl[160];
  int b = blockIdx.x, t = threadIdx.x;
  if (t < 160) {
    float s = 0.f;
    for (int c = 0; c < 9; ++c) s += parts[(b * 9 + c) * 160 + t];
    float ss = s * s;
    ss += __shfl_xor(ss, 1, 16);
    ss += __shfl_xor(ss, 2, 16);
    ss += __shfl_xor(ss, 4, 16);
    ss += __shfl_xor(ss, 8, 16);
    float n = sqrtf(ss);
    float f = ss / ((1.f + ss) * (n + 1e-7f));
    float v = f * s;
    vl[t] = v;
    vout[b * 160 + t] = v;
  }
  __syncthreads();
  int yb = y[b];
  float acc = b1[t];
#pragma unroll
  for (int k = 0; k < 16; ++k) acc += vl[yb * 16 + k] * w1[(yb * 16 + k) * 1024 + t];
  r1[b * 1024 + t] = (f16)fmaxf(acc, 0.f);
}

// ---------------- launch ----------------
extern "C" void kernel_launch(void* const* d_in, const int* in_sizes, int n_in,
                              void* d_out, int out_size, void* d_ws, size_t ws_size,
                              hipStream_t stream) {
  const float* x       = (const float*)d_in[0];
  const int*   y       = (const int*)d_in[1];
  const float* conv1_k = (const float*)d_in[2];
  const float* conv1_b = (const float*)d_in[3];
  const float* conv2_k = (const float*)d_in[4];
  const float* conv2_b = (const float*)d_in[5];
  const float* conv3_k = (const float*)d_in[6];
  const float* conv3_b = (const float*)d_in[7];
  const float* prim_k  = (const float*)d_in[8];
  const float* prim_b  = (const float*)d_in[9];
  const float* w_route = (const float*)d_in[10];
  const float* d1_w = (const float*)d_in[11];
  const float* d1_b = (const float*)d_in[12];
  const float* d2_w = (const float*)d_in[13];
  const float* d2_b = (const float*)d_in[14];
  const float* d3_w = (const float*)d_in[15];
  const float* d3_b = (const float*)d_in[16];

  // workspace layout (bytes), total 191,021,056 (same as R1-R9 -> proven fits).
  // Liveness: h1@0 (conv1-conv2) -> tpart01@0 (conv3 tail, 37.7M) -> part@0 (prim)
  //   -> dpart2@0/dpart3@16.7M (dense). tpart2@146.3M (conv3 tail; parts/blog dead
  //   then). h2@42.4M -> uhat@42.4M. h3@93.8M. wtp@177.5M dies after prim -> wd2/wd3.
  char* ws = (char*)d_ws;
  f16*   h1      = (f16*)(ws + 0);
  f16*   tpart01 = (f16*)(ws + 0);                   // 2 x 18,874,368 B
  float* part    = (float*)(ws + 0);                 // 4 x 9,437,184 B
  float* dpart2  = (float*)(ws + 0);                 //  8,388,608 B
  float* dpart3  = (float*)(ws + 16777216);          // 13,631,488 B
  f16*   h2      = (f16*)(ws + 42467328);
  f16*   uhat    = (f16*)(ws + 42467328);            // 94,371,840 B (h2,h3 dead)
  f16*   h3      = (f16*)(ws + 93847552);
  f16*   tpart2  = (f16*)(ws + 146276352);           // 18,874,368 B (pre-routing)
  float* parts_a = (float*)(ws + 146276352);         //  2,949,120 B
  float* parts_b = (float*)(ws + 149225472);         //  1,474,560 B
  float* blog    = (float*)(ws + 155713536);         // 11,796,480 B
  f16*   r1h     = (f16*)(ws + 167673856);           //    524,288 B
  f16*   r2h     = (f16*)(ws + 168198144);           //  1,048,576 B
  f16*   wt2     = (f16*)(ws + 170819584);           //  1,327,104 B
  f16*   wt3     = (f16*)(ws + 172146688);           //  5,308,416 B
  f16*   wtp     = (f16*)(ws + 177455104);           // 10,616,832 B (dead after prim)
  f16*   wd2     = (f16*)(ws + 177455104);           //  4,194,304 B (alias wtp)
  f16*   wd3     = (f16*)(ws + 181649408);           //  6,815,744 B -> ends 188,465,152

  float* vout  = (float*)d_out;            // [256,1,10,16] = 40960 f32
  float* recon = (float*)d_out + 40960;    // [256,1600]

  // conv weight prep (one launch)
  wprepc_kernel<<<2106, 256, 0, stream>>>(conv2_k, wt2, conv3_k, wt3, prim_k, wtp);

  // conv stack
  conv1_kernel<<<10368, 256, 0, stream>>>(x, conv1_k, conv1_b, h1);
  conv_mfma_kernel<36, 36, 64, 28, 28, 128, 1, true, true, 1, true>
      <<<1568, 256, 0, stream>>>(h1, wt2, conv2_b, h2, nullptr);
  // conv3: 8-phase 256^2 + K-third tail smoothing (256 fulls + 432 thirds)
  conv8p_kernel<28, 28, 128, 20, 20, 256, 1, true, true, 256, 144>
      <<<688, 512, 0, stream>>>(h2, wt3, conv3_b, h3, nullptr, tpart01, tpart2);
  tailred3_kernel<<<4608, 256, 0, stream>>>(tpart01, tpart2, conv3_b, h3);
  // prim caps: K-split x4 (m97 structure), partials (reduced inside uhatps)
  conv_mfma_kernel<20, 20, 256, 6, 6, 256, 2, false, false, 4, false>
      <<<576, 256, 0, stream>>>(h3, wtp, prim_b, nullptr, part);

  // fused routing
  uhatps_kernel<<<2304, 320, 0, stream>>>(w_route, part, prim_b, uhat, parts_a);
  wprepd_kernel<<<1344, 256, 0, stream>>>(d2_w, wd2, d3_w, wd3);  // wtp dead now
  ba_kernel<18, true, true><<<2304, 256, 0, stream>>>(uhat, parts_a, 0.1f, blog, parts_b);
  ba_kernel<9, false, false><<<2304, 256, 0, stream>>>(uhat, parts_b, 1.0f, blog, parts_a);

  // masked reconstruction
  maskd1v_kernel<<<256, 1024, 0, stream>>>(parts_a, y, d1_w, d1_b, vout, r1h);
  gemm_mfma_kernel<1024, 2048, 4><<<128, 256, 0, stream>>>(r1h, wd2, dpart2);
  d2red_kernel<<<512, 256, 0, stream>>>(dpart2, d2_b, r2h);
  gemm_mfma_kernel<2048, 1664, 8><<<208, 256, 0, stream>>>(r2h, wd3, dpart3);
  d3red_kernel<<<416, 256, 0, stream>>>(dpart3, d3_b, recon);
}

// Round 11
// 1174.448 us; speedup vs baseline: 1.0721x; 1.0223x over previous
//
#include <hip/hip_runtime.h>
#include <hip/hip_bf16.h>

typedef _Float16 f16;
typedef __attribute__((ext_vector_type(8))) _Float16 f16x8;
typedef __attribute__((ext_vector_type(4))) float f32x4;

// ---------------- global_load_lds helper (16B, wave-uniform LDS base + lane*16) ----
__device__ __forceinline__ void gload_lds16(const void* g, void* l) {
  __builtin_amdgcn_global_load_lds((const __attribute__((address_space(1))) void*)g,
                                   (__attribute__((address_space(3))) void*)l, 16, 0, 0);
}

// ---------------- generic weight transpose body: [K][N] f32 -> [NP][K] f16 ----------
__device__ __forceinline__ void wtrans_body(const float* __restrict__ src,
                                            f16* __restrict__ dst,
                                            int K, int N, int k0, int n0) {
  __shared__ float tile[64][65];
  int t = threadIdx.x;
#pragma unroll
  for (int i = 0; i < 16; ++i) {
    int id = t + i * 256;
    int r = id >> 6, c = id & 63;  // r = k_local, c = n_local
    tile[r][c] = (n0 + c < N) ? src[(size_t)(k0 + r) * N + n0 + c] : 0.f;
  }
  __syncthreads();
#pragma unroll
  for (int i = 0; i < 16; ++i) {
    int id = t + i * 256;
    int r = id >> 6, c = id & 63;  // r = n_local, c = k_local
    dst[(size_t)(n0 + r) * K + k0 + c] = (f16)tile[c][r];
  }
}

// wprepc: conv weight prep (3 jobs) + conv1 fused (grid tail).
// Jobs: conv2 (K=5184,N=128) 162, conv3 (10368,256) 648, prim (20736,256) 1296,
// conv1 10368. Grid = 2106 + 10368 = 12474.
__global__ __launch_bounds__(256) void wprepc_kernel(const float* __restrict__ s0, f16* __restrict__ d0,
                                                     const float* __restrict__ s1, f16* __restrict__ d1,
                                                     const float* __restrict__ s2, f16* __restrict__ d2,
                                                     const float* __restrict__ x,
                                                     const float* __restrict__ c1k,
                                                     const float* __restrict__ c1b,
                                                     f16* __restrict__ h1) {
  int bid = (int)blockIdx.x;
  if (bid < 162) {
    int bx = bid % 81, by = bid / 81;
    wtrans_body(s0, d0, 5184, 128, bx * 64, by * 64);
  } else if (bid < 810) {
    int l = bid - 162; int bx = l % 162, by = l / 162;
    wtrans_body(s1, d1, 10368, 256, bx * 64, by * 64);
  } else if (bid < 2106) {
    int l = bid - 810; int bx = l % 324, by = l / 324;
    wtrans_body(s2, d2, 20736, 256, bx * 64, by * 64);
  } else {
    // conv1: 5x5, Cin=1, Cout=64, relu, f16 out (8 couts/thread)
    int idx = (bid - 2106) * 256 + threadIdx.x;  // 256*36*36*8 threads
    int g = idx & 7;
    int co0 = g * 8;
    int r = idx >> 3;
    int ow = r % 36; int r2 = r / 36; int oh = r2 % 36; int b = r2 / 36;
    float acc[8];
#pragma unroll
    for (int j = 0; j < 8; ++j) acc[j] = c1b[co0 + j];
    const float* xp = x + (b * 40 + oh) * 40 + ow;
#pragma unroll
    for (int dy = 0; dy < 5; ++dy)
#pragma unroll
      for (int dx = 0; dx < 5; ++dx) {
        float xv = xp[dy * 40 + dx];
        const float* kp = c1k + (dy * 5 + dx) * 64 + co0;
#pragma unroll
        for (int j = 0; j < 8; ++j) acc[j] += xv * kp[j];
      }
    f16x8 o;
#pragma unroll
    for (int j = 0; j < 8; ++j) o[j] = (f16)fmaxf(acc[j], 0.f);
    *(f16x8*)(h1 + r * 64 + co0) = o;
  }
}

// wprepd: dense weight prep (2 jobs): d2 (K=1024,N=2048), d3 (K=2048,N=1600,NP=1664).
__global__ __launch_bounds__(256) void wprepd_kernel(const float* __restrict__ s0, f16* __restrict__ d0,
                                                     const float* __restrict__ s1, f16* __restrict__ d1) {
  int bid = (int)blockIdx.x;
  if (bid < 512) {
    int bx = bid % 16, by = bid / 16;
    wtrans_body(s0, d0, 1024, 2048, bx * 64, by * 64);
  } else {
    int l = bid - 512; int bx = l % 32, by = l / 32;
    wtrans_body(s1, d1, 2048, 1600, bx * 64, by * 64);
  }
}

// ---------------- im2col tap offset helper (BK=64 chunks) ----------------
template<int CIN, int WIN>
__device__ __forceinline__ int tapA_off(int kt) {
  int tap, ci0;
  if (CIN == 64)       { tap = kt;      ci0 = 0; }
  else if (CIN == 128) { tap = kt >> 1; ci0 = (kt & 1) << 6; }
  else                 { tap = kt >> 2; ci0 = (kt & 3) << 6; }
  int dy = tap / 9, dx = tap - dy * 9;
  return (dy * WIN + dx) * CIN + ci0;
}

// ============ 8-phase 256x256 implicit-GEMM conv + K-third tail smoothing ===========
template<int HIN, int WIN, int CIN, int HOUT, int WOUT, int COUT, int STRIDE,
         bool RELU, bool OUTF16, int FULLB, int TAILB>
__global__ __launch_bounds__(512, 2) void conv8p_kernel(const f16* __restrict__ in,
                                                        const f16* __restrict__ wt,
                                                        const float* __restrict__ bias,
                                                        f16* __restrict__ out16,
                                                        float* __restrict__ out32,
                                                        f16* __restrict__ tp01,
                                                        f16* __restrict__ tp2) {
  static_assert(COUT == 256, "BN=256 template requires COUT==256");
  constexpr int KTOT = 81 * CIN;
  constexpr int NT = KTOT / 64;
  static_assert(TAILB == 0 || NT % 3 == 0, "K-third split requires NT%3==0");
  constexpr int PNT = (TAILB > 0) ? NT / 3 : NT;
  __shared__ __align__(16) f16 lds[65536];  // 128 KiB
  const int bid = (int)blockIdx.x;
  int mb, kt0, kt1;
  f16* tp = nullptr;
  if (TAILB == 0 || bid < FULLB) {
    mb = bid; kt0 = 0; kt1 = NT;
  } else {
    int idx = bid - FULLB;
    int piece = idx / TAILB;           // 0,1,2
    int loc = idx - piece * TAILB;
    mb = FULLB + loc;
    kt0 = piece * PNT; kt1 = kt0 + PNT;
    tp = (piece < 2 ? tp01 + (size_t)piece * TAILB * 65536 : tp2) + (size_t)loc * 65536;
  }
  const int t = threadIdx.x;
  const int wave = t >> 6, lane = t & 63;
  const int hi = lane >> 4, lo = lane & 15;
  const int wm = wave >> 2, wn = wave & 3;

  int Aoff[4], Boff[4];
  {
    int g = (lane & 7) ^ ((lane >> 3) & 7);  // inverse swizzle granule
#pragma unroll
    for (int rbi = 0; rbi < 4; ++rbi) {
      int r = rbi * 64 + 8 * wave + (lane >> 3);
      int m = mb * 256 + r;
      int b = m / (HOUT * WOUT);
      int rr = m - b * (HOUT * WOUT);
      int oh = rr / WOUT, ow = rr - oh * WOUT;
      Aoff[rbi] = ((b * HIN + oh * STRIDE) * WIN + ow * STRIDE) * CIN + g * 8;
      Boff[rbi] = r * KTOT + g * 8;
    }
  }
  const int gb0 = (hi ^ (lo & 7)) << 4;
  const int gb1 = ((4 + hi) ^ (lo & 7)) << 4;

  const char* ldsc = (const char*)lds;
  char* ldsw = (char*)lds;

#define GA(rbi, tpo, bq) gload_lds16(in + Aoff[rbi] + (tpo),                        \
    (void*)(ldsw + (bq) * 32768 + ((rbi) * 64 + 8 * wave) * 128))
#define GB(rbi, tile) gload_lds16(wt + Boff[rbi] + ((tile) << 6),                   \
    (void*)(ldsw + 65536 + ((tile) & 1) * 32768 + ((rbi) * 64 + 8 * wave) * 128))

  // Prologue: tile kt0 full (A then B), tile kt0+1 B. vmcnt(4) -> tile kt0 landed.
  {
    int tq = tapA_off<CIN, WIN>(kt0);
    int bq = kt0 & 1;
    GA(0, tq, bq); GA(2, tq, bq); GA(1, tq, bq); GA(3, tq, bq);
    GB(0, kt0); GB(1, kt0); GB(2, kt0); GB(3, kt0);
    GB(0, kt0 + 1); GB(1, kt0 + 1); GB(2, kt0 + 1); GB(3, kt0 + 1);
    asm volatile("s_waitcnt vmcnt(4)" ::: "memory");
    __builtin_amdgcn_s_barrier();
  }

  f32x4 acc[8][4] = {};

#define DO_PHASE(Q, STAGE)                                                          \
  {                                                                                 \
    f16x8 af[2][2];                                                                 \
    _Pragma("unroll")                                                               \
    for (int mf = 0; mf < 2; ++mf) {                                                \
      af[mf][0] = *(const f16x8*)(Ab + ((Q) * 2 + mf) * 2048 + gb0);                \
      af[mf][1] = *(const f16x8*)(Ab + ((Q) * 2 + mf) * 2048 + gb1);                \
    }                                                                               \
    STAGE;                                                                          \
    __builtin_amdgcn_s_barrier();                                                   \
    asm volatile("s_waitcnt lgkmcnt(0)" ::: "memory");                              \
    __builtin_amdgcn_sched_barrier(0);                                              \
    __builtin_amdgcn_s_setprio(1);                                                  \
    _Pragma("unroll")                                                               \
    for (int sb = 0; sb < 2; ++sb)                                                  \
      _Pragma("unroll")                                                             \
      for (int mf = 0; mf < 2; ++mf)                                                \
        _Pragma("unroll")                                                           \
        for (int nf = 0; nf < 4; ++nf)                                              \
          acc[(Q) * 2 + mf][nf] = __builtin_amdgcn_mfma_f32_16x16x32_f16(           \
              af[mf][sb], bfr[nf][sb], acc[(Q) * 2 + mf][nf], 0, 0, 0);             \
    __builtin_amdgcn_s_setprio(0);                                                  \
    __builtin_amdgcn_s_barrier();                                                   \
  }

  for (int T = kt0; T < kt1; ++T) {
    const int q = T & 1;
    const char* Ab = ldsc + q * 32768 + wm * 16384 + lo * 128;
    const char* Bb = ldsc + 65536 + q * 32768 + wn * 8192 + lo * 128;
    const int tpn = tapA_off<CIN, WIN>(T + 1);  // used only if T+1 < kt1
    f16x8 bfr[4][2];
#pragma unroll
    for (int nf = 0; nf < 4; ++nf) {
      bfr[nf][0] = *(const f16x8*)(Bb + nf * 2048 + gb0);
      bfr[nf][1] = *(const f16x8*)(Bb + nf * 2048 + gb1);
    }
    DO_PHASE(0, if (T + 1 < kt1) { GA(0, tpn, (T + 1) & 1); GA(2, tpn, (T + 1) & 1); })
    DO_PHASE(1, if (T + 1 < kt1) { GA(1, tpn, (T + 1) & 1); GA(3, tpn, (T + 1) & 1); })
    DO_PHASE(2, if (T + 2 < kt1) { GB(0, T + 2); GB(1, T + 2); })
    DO_PHASE(3,
      if (T + 2 < kt1) {
        GB(2, T + 2); GB(3, T + 2);
        asm volatile("s_waitcnt vmcnt(4)" ::: "memory");
      } else {
        asm volatile("s_waitcnt vmcnt(0)" ::: "memory");
      })
  }
#undef DO_PHASE
#undef GA
#undef GB

  // Epilogue: C/D layout col = lane&15, row = (lane>>4)*4 + reg
  if (tp == nullptr) {
#pragma unroll
    for (int mfr = 0; mfr < 8; ++mfr) {
#pragma unroll
      for (int nf = 0; nf < 4; ++nf) {
        int m0 = mb * 256 + wm * 128 + mfr * 16 + hi * 4;
        int n = wn * 64 + nf * 16 + lo;
        float bval = bias[n];
#pragma unroll
        for (int r = 0; r < 4; ++r) {
          float v = acc[mfr][nf][r] + bval;
          if (RELU) v = fmaxf(v, 0.f);
          int o = (m0 + r) * COUT + n;
          if (OUTF16) out16[o] = (f16)v; else out32[o] = v;
        }
      }
    }
  } else {
#pragma unroll
    for (int mfr = 0; mfr < 8; ++mfr) {
#pragma unroll
      for (int nf = 0; nf < 4; ++nf) {
        int rowloc = wm * 128 + mfr * 16 + hi * 4;
        int n = wn * 64 + nf * 16 + lo;
#pragma unroll
        for (int r = 0; r < 4; ++r)
          tp[(rowloc + r) * 256 + n] = (f16)acc[mfr][nf][r];
      }
    }
  }
}

// ------- tail reduce: h3[tail rows] = relu(p0 + p1 + p2 + bias), x8 vec -----------
__global__ __launch_bounds__(256) void tailred3_kernel(const f16* __restrict__ tp01,
                                                       const f16* __restrict__ tp2,
                                                       const float* __restrict__ bias,
                                                       f16* __restrict__ h3) {
  int idx = blockIdx.x * 256 + threadIdx.x;  // 4608 blocks: 9,437,184 elems / 8
  int e0 = idx * 8;
  int n0 = e0 & 255;
  f16x8 a = *(const f16x8*)(tp01 + e0);
  f16x8 b = *(const f16x8*)(tp01 + 9437184 + e0);
  f16x8 c = *(const f16x8*)(tp2 + e0);
  f16x8 o;
#pragma unroll
  for (int j = 0; j < 8; ++j) {
    float v = (float)a[j] + (float)b[j] + (float)c[j] + bias[n0 + j];
    o[j] = (f16)fmaxf(v, 0.f);
  }
  *(f16x8*)(h3 + 16777216 + e0) = o;  // tail tiles start at m = 256*256
}

// ---------------- implicit-GEMM conv via f16 MFMA (m97 structure, 128x128) --------
template<int HIN, int WIN, int CIN, int HOUT, int WOUT, int COUT, int STRIDE,
         bool RELU, bool OUTF16, int SPLIT, bool ADDBIAS>
__global__ __launch_bounds__(256) void conv_mfma_kernel(const f16* __restrict__ in,
                                                        const f16* __restrict__ wt,
                                                        const float* __restrict__ bias,
                                                        f16* __restrict__ out16,
                                                        float* __restrict__ out32) {
  constexpr int KTOT = 81 * CIN;
  constexpr int NBLK = COUT / 128;
  constexpr int MTOT = 256 * HOUT * WOUT;
  constexpr int MBNB = (MTOT / 128) * NBLK;
  constexpr int NKT = (KTOT / 64) / SPLIT;
  __shared__ __align__(16) f16 lds[16384];
  int bidx = (int)blockIdx.x;
  int ks = 0;
  if (SPLIT > 1) { ks = bidx / MBNB; bidx -= ks * MBNB; }
  const int mb = bidx / NBLK;
  const int nb = bidx % NBLK;
  const int t = threadIdx.x;
  const int wave = t >> 6, lane = t & 63;
  const int hi = lane >> 4, lo = lane & 15;
  const bool isA = wave < 2;
  const int slot0 = wave << 9;

  int baseoff[8];
#pragma unroll
  for (int it = 0; it < 8; ++it) {
    int s = slot0 + it * 64 + lane;
    if (isA) {
      int row = s >> 3;
      int g = (s & 7) ^ (row & 7);
      int mg = mb * 128 + row;
      int b = mg / (HOUT * WOUT);
      int rr = mg - b * (HOUT * WOUT);
      int oh = rr / WOUT;
      int ow = rr - oh * WOUT;
      baseoff[it] = ((b * HIN + oh * STRIDE) * WIN + ow * STRIDE) * CIN + g * 8;
    } else {
      int sl = s - 1024;
      int row = sl >> 3;
      int g = (sl & 7) ^ (row & 7);
      baseoff[it] = (nb * 128 + row) * KTOT + g * 8;
    }
  }
  const f16* gsrc = isA ? in : wt;

  int aQ[4], bQ[4];
  const int wm = wave >> 1, wn = wave & 1;
#pragma unroll
  for (int f = 0; f < 4; ++f) {
    int arow = wm * 64 + f * 16 + lo;
    aQ[f] = (arow * 128) ^ ((arow & 7) << 4);
    int brow = wn * 64 + f * 16 + lo;
    bQ[f] = 16384 + ((brow * 128) ^ ((brow & 7) << 4));
  }

  f32x4 acc[4][4] = {};
  const char* ldsc = (const char*)lds;

  const int kt0 = ks * NKT;
  for (int kt = kt0; kt < kt0 + NKT; ++kt) {
    int tapoff;
    if (isA) tapoff = tapA_off<CIN, WIN>(kt);
    else     tapoff = kt << 6;
    __syncthreads();
#pragma unroll
    for (int it = 0; it < 8; ++it)
      gload_lds16(gsrc + baseoff[it] + tapoff,
                  (void*)((char*)lds + ((slot0 + it * 64) << 4)));
    __syncthreads();
#pragma unroll
    for (int sub = 0; sub < 2; ++sub) {
      const int gx = (sub * 4 + hi) << 4;
      f16x8 av[4], bv[4];
#pragma unroll
      for (int f = 0; f < 4; ++f) av[f] = *(const f16x8*)(ldsc + (aQ[f] ^ gx));
#pragma unroll
      for (int f = 0; f < 4; ++f) bv[f] = *(const f16x8*)(ldsc + (bQ[f] ^ gx));
#pragma unroll
      for (int mf = 0; mf < 4; ++mf)
#pragma unroll
        for (int nf = 0; nf < 4; ++nf)
          acc[mf][nf] = __builtin_amdgcn_mfma_f32_16x16x32_f16(av[mf], bv[nf],
                                                               acc[mf][nf], 0, 0, 0);
    }
  }

  float* o32 = out32 + (size_t)ks * MTOT * COUT;
#pragma unroll
  for (int mf = 0; mf < 4; ++mf) {
#pragma unroll
    for (int nf = 0; nf < 4; ++nf) {
      int m0 = mb * 128 + wm * 64 + mf * 16 + hi * 4;
      int n = nb * 128 + wn * 64 + nf * 16 + lo;
      float bval = ADDBIAS ? bias[n] : 0.f;
#pragma unroll
      for (int r = 0; r < 4; ++r) {
        float v = acc[mf][nf][r] + bval;
        if (RELU) v = fmaxf(v, 0.f);
        int o = (m0 + r) * COUT + n;
        if (OUTF16) out16[o] = (f16)v; else o32[o] = v;
      }
    }
  }
}

// ------- dense GEMM via f16 MFMA, K-split partials: A[256][K] x Bw[NP][K]^T --------
template<int K, int NP, int SPLIT>
__global__ __launch_bounds__(256) void gemm_mfma_kernel(const f16* __restrict__ A,
                                                        const f16* __restrict__ Bw,
                                                        float* __restrict__ dpart) {
  constexpr int NBLK = NP / 128;
  constexpr int MBNB = 2 * NBLK;
  constexpr int NKT = (K / 64) / SPLIT;
  __shared__ __align__(16) f16 lds[16384];
  int bidx = (int)blockIdx.x;
  int ks = 0;
  if (SPLIT > 1) { ks = bidx / MBNB; bidx -= ks * MBNB; }
  const int mb = bidx / NBLK;
  const int nb = bidx % NBLK;
  const int t = threadIdx.x;
  const int wave = t >> 6, lane = t & 63;
  const int hi = lane >> 4, lo = lane & 15;
  const bool isA = wave < 2;
  const int slot0 = wave << 9;

  int baseoff[8];
#pragma unroll
  for (int it = 0; it < 8; ++it) {
    int s = slot0 + it * 64 + lane;
    if (isA) {
      int row = s >> 3;
      int g = (s & 7) ^ (row & 7);
      baseoff[it] = (mb * 128 + row) * K + g * 8;
    } else {
      int sl = s - 1024;
      int row = sl >> 3;
      int g = (sl & 7) ^ (row & 7);
      baseoff[it] = (nb * 128 + row) * K + g * 8;
    }
  }
  const f16* gsrc = isA ? A : Bw;

  int aQ[4], bQ[4];
  const int wm = wave >> 1, wn = wave & 1;
#pragma unroll
  for (int f = 0; f < 4; ++f) {
    int arow = wm * 64 + f * 16 + lo;
    aQ[f] = (arow * 128) ^ ((arow & 7) << 4);
    int brow = wn * 64 + f * 16 + lo;
    bQ[f] = 16384 + ((brow * 128) ^ ((brow & 7) << 4));
  }

  f32x4 acc[4][4] = {};
  const char* ldsc = (const char*)lds;

  const int kt0 = ks * NKT;
  for (int kt = kt0; kt < kt0 + NKT; ++kt) {
    int tapoff = kt << 6;
    __syncthreads();
#pragma unroll
    for (int it = 0; it < 8; ++it)
      gload_lds16(gsrc + baseoff[it] + tapoff,
                  (void*)((char*)lds + ((slot0 + it * 64) << 4)));
    __syncthreads();
#pragma unroll
    for (int sub = 0; sub < 2; ++sub) {
      const int gx = (sub * 4 + hi) << 4;
      f16x8 av[4], bv[4];
#pragma unroll
      for (int f = 0; f < 4; ++f) av[f] = *(const f16x8*)(ldsc + (aQ[f] ^ gx));
#pragma unroll
      for (int f = 0; f < 4; ++f) bv[f] = *(const f16x8*)(ldsc + (bQ[f] ^ gx));
#pragma unroll
      for (int mf = 0; mf < 4; ++mf)
#pragma unroll
        for (int nf = 0; nf < 4; ++nf)
          acc[mf][nf] = __builtin_amdgcn_mfma_f32_16x16x32_f16(av[mf], bv[nf],
                                                               acc[mf][nf], 0, 0, 0);
    }
  }

  float* o32 = dpart + (size_t)ks * 256 * NP;
#pragma unroll
  for (int mf = 0; mf < 4; ++mf) {
#pragma unroll
    for (int nf = 0; nf < 4; ++nf) {
      int m0 = mb * 128 + wm * 64 + mf * 16 + hi * 4;
      int n = nb * 128 + wn * 64 + nf * 16 + lo;
#pragma unroll
      for (int r = 0; r < 4; ++r)
        o32[(m0 + r) * NP + n] = acc[mf][nf][r];
    }
  }
}

// ---------------- d2 reduce: r2 = relu(sum_s part + bias) f16, x4 vec ----------------
__global__ __launch_bounds__(256) void d2red_kernel(const float* __restrict__ part,
                                                    const float* __restrict__ bias,
                                                    f16* __restrict__ r2) {
  int idx = blockIdx.x * 256 + threadIdx.x;  // 512 blocks: 524288/4
  int e0 = idx * 4;
  int n0 = e0 & 2047;
  float4 a = *(const float4*)(part + e0);
  const float4 b1 = *(const float4*)(part + 524288 + e0);
  const float4 b2 = *(const float4*)(part + 1048576 + e0);
  const float4 b3 = *(const float4*)(part + 1572864 + e0);
  float v[4] = {a.x + b1.x + b2.x + b3.x, a.y + b1.y + b2.y + b3.y,
                a.z + b1.z + b2.z + b3.z, a.w + b1.w + b2.w + b3.w};
#pragma unroll
  for (int j = 0; j < 4; ++j)
    r2[e0 + j] = (f16)fmaxf(v[j] + bias[n0 + j], 0.f);
}

// ---------------- d3 reduce: recon = sigmoid(sum_s part + bias), mask n<1600 --------
__global__ __launch_bounds__(256) void d3red_kernel(const float* __restrict__ part,
                                                    const float* __restrict__ bias,
                                                    float* __restrict__ recon) {
  int idx = blockIdx.x * 256 + threadIdx.x;  // 416 blocks: 425984/4
  int e0 = idx * 4;
  int n0 = e0 % 1664;
  int m = e0 / 1664;
  float v[4] = {0.f, 0.f, 0.f, 0.f};
#pragma unroll
  for (int s = 0; s < 8; ++s) {
    float4 a = *(const float4*)(part + s * 425984 + e0);
    v[0] += a.x; v[1] += a.y; v[2] += a.z; v[3] += a.w;
  }
#pragma unroll
  for (int j = 0; j < 4; ++j) {
    int n = n0 + j;
    if (n < 1600)
      recon[m * 1600 + n] = 1.f / (1.f + expf(-(v[j] + bias[n])));
  }
}

// ======================= fused routing =======================
// uhatps: block (ic of 9, bg of 32) batches 8 b's -> w_route L2 re-reads cut 8x
// (1.5 GB -> 188 MB). Folds prim_reduce (u = bias + sum_s part). Per-thread
// accumulation order identical to the unbatched version (bitwise-same parts).
__global__ __launch_bounds__(320) void uhatps_kernel(const float* __restrict__ wf,
                                                     const float* __restrict__ part,
                                                     const float* __restrict__ pbias,
                                                     f16* __restrict__ uh,
                                                     float* __restrict__ parts) {
  __shared__ float pl[8][128][8];  // 32 KB
  int blk = (int)blockIdx.x;       // 9 * 32 = 288
  int ic = blk / 32, bg = blk - ic * 32;
  int b0 = bg * 8;
  int t = threadIdx.x;
  for (int e = t; e < 8192; e += 320) {
    int b8 = e >> 10;
    int el = e & 1023;
    float a = pbias[el & 255];
    int gi = (b0 + b8) * 9216 + ic * 1024 + el;
#pragma unroll
    for (int s = 0; s < 4; ++s) a += part[s * 2359296 + gi];
    pl[b8][el >> 3][el & 7] = a;
  }
  __syncthreads();
  int half = (t >= 160) ? 1 : 0;
  int jk = t - half * 160;
  int ibase = ic * 128 + half * 64;
  float sum[8] = {};
  for (int il = 0; il < 64; ++il) {
    int i = ibase + il;
    const float4* w4 = (const float4*)(wf + (i * 160 + jk) * 8);
    float4 w0 = w4[0], w1 = w4[1];
    int row = half * 64 + il;
#pragma unroll
    for (int b8 = 0; b8 < 8; ++b8) {
      const float* pr = pl[b8][row];
      float acc = w0.x * pr[0] + w0.y * pr[1] + w0.z * pr[2] + w0.w * pr[3] +
                  w1.x * pr[4] + w1.y * pr[5] + w1.z * pr[6] + w1.w * pr[7];
      uh[((size_t)(b0 + b8) * 1152 + i) * 160 + jk] = (f16)acc;
      sum[b8] += acc;
    }
  }
#pragma unroll
  for (int b8 = 0; b8 < 8; ++b8)
    parts[((b0 + b8) * 18 + ic * 2 + half) * 160 + jk] = sum[b8];
}

template<int NCH, bool FIRST, bool WRITEB>
__global__ __launch_bounds__(256) void ba_kernel(const f16* __restrict__ uh,
                                                 const float* __restrict__ psrc,
                                                 float cscale,
                                                 float* __restrict__ blog,
                                                 float* __restrict__ pdst) {
  __shared__ f16 ul[128 * 172];   // 44,032 B
  __shared__ float vl[160];
  __shared__ float csm[128 * 10];
  int blk = (int)blockIdx.x;
  int b = blk / 9, ic = blk - b * 9;
  int t = threadIdx.x;
  const f16* ub = uh + (size_t)(b * 1152 + ic * 128) * 160;
  for (int e = t; e < 2560; e += 256) {  // 128 rows x 20 vec8
    int row = e / 20, col = e - row * 20;
    *(f16x8*)(ul + row * 172 + col * 8) = *(const f16x8*)(ub + row * 160 + col * 8);
  }
  if (t < 160) {
    float s = 0.f;
    for (int c = 0; c < NCH; ++c) s += psrc[(b * NCH + c) * 160 + t];
    s *= cscale;
    float ss = s * s;
    ss += __shfl_xor(ss, 1, 16);
    ss += __shfl_xor(ss, 2, 16);
    ss += __shfl_xor(ss, 4, 16);
    ss += __shfl_xor(ss, 8, 16);
    float n = sqrtf(ss);
    float f = ss / ((1.f + ss) * (n + 1e-7f));
    vl[t] = f * s;
  }
  __syncthreads();

  int il = t >> 1, half = t & 1, j0 = half * 5;
  const f16* ur = ul + il * 172 + j0 * 16;
  float agr[5];
#pragma unroll
  for (int j = 0; j < 5; ++j) {
    f16x8 a0 = *(const f16x8*)(ur + j * 16);
    f16x8 a1 = *(const f16x8*)(ur + j * 16 + 8);
    const float* vv = vl + (j0 + j) * 16;
    float s = (float)a0[0] * vv[0] + (float)a0[1] * vv[1] + (float)a0[2] * vv[2] +
              (float)a0[3] * vv[3] + (float)a0[4] * vv[4] + (float)a0[5] * vv[5] +
              (float)a0[6] * vv[6] + (float)a0[7] * vv[7] +
              (float)a1[0] * vv[8] + (float)a1[1] * vv[9] + (float)a1[2] * vv[10] +
              (float)a1[3] * vv[11] + (float)a1[4] * vv[12] + (float)a1[5] * vv[13] +
              (float)a1[6] * vv[14] + (float)a1[7] * vv[15];
    agr[j] = s;
  }
  int bbase = (b * 1152 + ic * 128 + il) * 10 + j0;
  float bl[5];
#pragma unroll
  for (int j = 0; j < 5; ++j) bl[j] = (FIRST ? 0.f : blog[bbase + j]) + agr[j];
  if (WRITEB) {
#pragma unroll
    for (int j = 0; j < 5; ++j) blog[bbase + j] = bl[j];
  }
  float mx = bl[0];
#pragma unroll
  for (int j = 1; j < 5; ++j) mx = fmaxf(mx, bl[j]);
  mx = fmaxf(mx, __shfl_xor(mx, 1));
  float e5[5], se = 0.f;
#pragma unroll
  for (int j = 0; j < 5; ++j) { e5[j] = expf(bl[j] - mx); se += e5[j]; }
  se += __shfl_xor(se, 1);
  float inv = 1.f / se;
#pragma unroll
  for (int j = 0; j < 5; ++j) csm[il * 10 + j0 + j] = e5[j] * inv;
  __syncthreads();

  if (t < 160) {
    int j = t >> 4;
    float s = 0.f;
    for (int il2 = 0; il2 < 128; ++il2)
      s += csm[il2 * 10 + j] * (float)ul[il2 * 172 + t];
    pdst[(b * 9 + ic) * 160 + t] = s;
  }
}

// maskd1v: folds final sred (v3 from parts, writes vout) + mask + dense1.
__global__ __launch_bounds__(1024) void maskd1v_kernel(const float* __restrict__ parts,
                                                       const int* __restrict__ y,
                                                       const float* __restrict__ w1,
                                                       const float* __restrict__ b1,
                                                       float* __restrict__ vout,
                                                       f16* __restrict__ r1) {
  __shared__ float vl[160];
  int b = blockIdx.x, t = threadIdx.x;
  if (t < 160) {
    float s = 0.f;
    for (int c = 0; c < 9; ++c) s += parts[(b * 9 + c) * 160 + t];
    float ss = s * s;
    ss += __shfl_xor(ss, 1, 16);
    ss += __shfl_xor(ss, 2, 16);
    ss += __shfl_xor(ss, 4, 16);
    ss += __shfl_xor(ss, 8, 16);
    float n = sqrtf(ss);
    float f = ss / ((1.f + ss) * (n + 1e-7f));
    float v = f * s;
    vl[t] = v;
    vout[b * 160 + t] = v;
  }
  __syncthreads();
  int yb = y[b];
  float acc = b1[t];
#pragma unroll
  for (int k = 0; k < 16; ++k) acc += vl[yb * 16 + k] * w1[(yb * 16 + k) * 1024 + t];
  r1[b * 1024 + t] = (f16)fmaxf(acc, 0.f);
}

// ---------------- launch ----------------
extern "C" void kernel_launch(void* const* d_in, const int* in_sizes, int n_in,
                              void* d_out, int out_size, void* d_ws, size_t ws_size,
                              hipStream_t stream) {
  const float* x       = (const float*)d_in[0];
  const int*   y       = (const int*)d_in[1];
  const float* conv1_k = (const float*)d_in[2];
  const float* conv1_b = (const float*)d_in[3];
  const float* conv2_k = (const float*)d_in[4];
  const float* conv2_b = (const float*)d_in[5];
  const float* conv3_k = (const float*)d_in[6];
  const float* conv3_b = (const float*)d_in[7];
  const float* prim_k  = (const float*)d_in[8];
  const float* prim_b  = (const float*)d_in[9];
  const float* w_route = (const float*)d_in[10];
  const float* d1_w = (const float*)d_in[11];
  const float* d1_b = (const float*)d_in[12];
  const float* d2_w = (const float*)d_in[13];
  const float* d2_b = (const float*)d_in[14];
  const float* d3_w = (const float*)d_in[15];
  const float* d3_b = (const float*)d_in[16];

  // workspace layout (bytes), total 191,021,056 (same as R1-R10 -> proven fits).
  char* ws = (char*)d_ws;
  f16*   h1      = (f16*)(ws + 0);
  f16*   tpart01 = (f16*)(ws + 0);                   // 2 x 18,874,368 B
  float* part    = (float*)(ws + 0);                 // 4 x 9,437,184 B
  float* dpart2  = (float*)(ws + 0);                 //  8,388,608 B
  float* dpart3  = (float*)(ws + 16777216);          // 13,631,488 B
  f16*   h2      = (f16*)(ws + 42467328);
  f16*   uhat    = (f16*)(ws + 42467328);            // 94,371,840 B (h2,h3 dead)
  f16*   h3      = (f16*)(ws + 93847552);
  f16*   tpart2  = (f16*)(ws + 146276352);           // 18,874,368 B (pre-routing)
  float* parts_a = (float*)(ws + 146276352);         //  2,949,120 B
  float* parts_b = (float*)(ws + 149225472);         //  1,474,560 B
  float* blog    = (float*)(ws + 155713536);         // 11,796,480 B
  f16*   r1h     = (f16*)(ws + 167673856);           //    524,288 B
  f16*   r2h     = (f16*)(ws + 168198144);           //  1,048,576 B
  f16*   wt2     = (f16*)(ws + 170819584);           //  1,327,104 B
  f16*   wt3     = (f16*)(ws + 172146688);           //  5,308,416 B
  f16*   wtp     = (f16*)(ws + 177455104);           // 10,616,832 B (dead after prim)
  f16*   wd2     = (f16*)(ws + 177455104);           //  4,194,304 B (alias wtp)
  f16*   wd3     = (f16*)(ws + 181649408);           //  6,815,744 B -> ends 188,465,152

  float* vout  = (float*)d_out;            // [256,1,10,16] = 40960 f32
  float* recon = (float*)d_out + 40960;    // [256,1600]

  // conv weight prep + conv1 (one launch)
  wprepc_kernel<<<12474, 256, 0, stream>>>(conv2_k, wt2, conv3_k, wt3, prim_k, wtp,
                                           x, conv1_k, conv1_b, h1);

  // conv stack
  conv_mfma_kernel<36, 36, 64, 28, 28, 128, 1, true, true, 1, true>
      <<<1568, 256, 0, stream>>>(h1, wt2, conv2_b, h2, nullptr);
  // conv3: 8-phase 256^2 + K-third tail smoothing (256 fulls + 432 thirds)
  conv8p_kernel<28, 28, 128, 20, 20, 256, 1, true, true, 256, 144>
      <<<688, 512, 0, stream>>>(h2, wt3, conv3_b, h3, nullptr, tpart01, tpart2);
  tailred3_kernel<<<4608, 256, 0, stream>>>(tpart01, tpart2, conv3_b, h3);
  // prim caps: K-split x4 (m97 structure), partials (reduced inside uhatps)
  conv_mfma_kernel<20, 20, 256, 6, 6, 256, 2, false, false, 4, false>
      <<<576, 256, 0, stream>>>(h3, wtp, prim_b, nullptr, part);

  // fused routing (uhatps batches 8 b's/block: w_route L2 traffic 1.5GB -> 188MB)
  uhatps_kernel<<<288, 320, 0, stream>>>(w_route, part, prim_b, uhat, parts_a);
  wprepd_kernel<<<1344, 256, 0, stream>>>(d2_w, wd2, d3_w, wd3);  // wtp dead now
  ba_kernel<18, true, true><<<2304, 256, 0, stream>>>(uhat, parts_a, 0.1f, blog, parts_b);
  ba_kernel<9, false, false><<<2304, 256, 0, stream>>>(uhat, parts_b, 1.0f, blog, parts_a);

  // masked reconstruction
  maskd1v_kernel<<<256, 1024, 0, stream>>>(parts_a, y, d1_w, d1_b, vout, r1h);
  gemm_mfma_kernel<1024, 2048, 4><<<128, 256, 0, stream>>>(r1h, wd2, dpart2);
  d2red_kernel<<<512, 256, 0, stream>>>(dpart2, d2_b, r2h);
  gemm_mfma_kernel<2048, 1664, 8><<<208, 256, 0, stream>>>(r2h, wd3, dpart3);
  d3red_kernel<<<416, 256, 0, stream>>>(dpart3, d3_b, recon);
}

// Round 12
// 1147.347 us; speedup vs baseline: 1.0974x; 1.0236x over previous
//
#include <hip/hip_runtime.h>
#include <hip/hip_bf16.h>

typedef _Float16 f16;
typedef __attribute__((ext_vector_type(8))) _Float16 f16x8;
typedef __attribute__((ext_vector_type(4))) float f32x4;

// ---------------- global_load_lds helper (16B, wave-uniform LDS base + lane*16) ----
__device__ __forceinline__ void gload_lds16(const void* g, void* l) {
  __builtin_amdgcn_global_load_lds((const __attribute__((address_space(1))) void*)g,
                                   (__attribute__((address_space(3))) void*)l, 16, 0, 0);
}

// ---------------- generic weight transpose body: [K][N] f32 -> [NP][K] f16 ----------
__device__ __forceinline__ void wtrans_body(const float* __restrict__ src,
                                            f16* __restrict__ dst,
                                            int K, int N, int k0, int n0) {
  __shared__ float tile[64][65];
  int t = threadIdx.x;
#pragma unroll
  for (int i = 0; i < 16; ++i) {
    int id = t + i * 256;
    int r = id >> 6, c = id & 63;  // r = k_local, c = n_local
    tile[r][c] = (n0 + c < N) ? src[(size_t)(k0 + r) * N + n0 + c] : 0.f;
  }
  __syncthreads();
#pragma unroll
  for (int i = 0; i < 16; ++i) {
    int id = t + i * 256;
    int r = id >> 6, c = id & 63;  // r = n_local, c = k_local
    dst[(size_t)(n0 + r) * K + k0 + c] = (f16)tile[c][r];
  }
}

// wprepc: conv weight prep (3 jobs) + conv1 fused (grid tail).
__global__ __launch_bounds__(256) void wprepc_kernel(const float* __restrict__ s0, f16* __restrict__ d0,
                                                     const float* __restrict__ s1, f16* __restrict__ d1,
                                                     const float* __restrict__ s2, f16* __restrict__ d2,
                                                     const float* __restrict__ x,
                                                     const float* __restrict__ c1k,
                                                     const float* __restrict__ c1b,
                                                     f16* __restrict__ h1) {
  int bid = (int)blockIdx.x;
  if (bid < 162) {
    int bx = bid % 81, by = bid / 81;
    wtrans_body(s0, d0, 5184, 128, bx * 64, by * 64);
  } else if (bid < 810) {
    int l = bid - 162; int bx = l % 162, by = l / 162;
    wtrans_body(s1, d1, 10368, 256, bx * 64, by * 64);
  } else if (bid < 2106) {
    int l = bid - 810; int bx = l % 324, by = l / 324;
    wtrans_body(s2, d2, 20736, 256, bx * 64, by * 64);
  } else {
    // conv1: 5x5, Cin=1, Cout=64, relu, f16 out (8 couts/thread)
    int idx = (bid - 2106) * 256 + threadIdx.x;  // 256*36*36*8 threads
    int g = idx & 7;
    int co0 = g * 8;
    int r = idx >> 3;
    int ow = r % 36; int r2 = r / 36; int oh = r2 % 36; int b = r2 / 36;
    float acc[8];
#pragma unroll
    for (int j = 0; j < 8; ++j) acc[j] = c1b[co0 + j];
    const float* xp = x + (b * 40 + oh) * 40 + ow;
#pragma unroll
    for (int dy = 0; dy < 5; ++dy)
#pragma unroll
      for (int dx = 0; dx < 5; ++dx) {
        float xv = xp[dy * 40 + dx];
        const float* kp = c1k + (dy * 5 + dx) * 64 + co0;
#pragma unroll
        for (int j = 0; j < 8; ++j) acc[j] += xv * kp[j];
      }
    f16x8 o;
#pragma unroll
    for (int j = 0; j < 8; ++j) o[j] = (f16)fmaxf(acc[j], 0.f);
    *(f16x8*)(h1 + r * 64 + co0) = o;
  }
}

// wprepd: dense weight prep (2 jobs): d2 (K=1024,N=2048), d3 (K=2048,N=1600,NP=1664).
__global__ __launch_bounds__(256) void wprepd_kernel(const float* __restrict__ s0, f16* __restrict__ d0,
                                                     const float* __restrict__ s1, f16* __restrict__ d1) {
  int bid = (int)blockIdx.x;
  if (bid < 512) {
    int bx = bid % 16, by = bid / 16;
    wtrans_body(s0, d0, 1024, 2048, bx * 64, by * 64);
  } else {
    int l = bid - 512; int bx = l % 32, by = l / 32;
    wtrans_body(s1, d1, 2048, 1600, bx * 64, by * 64);
  }
}

// ---------------- im2col tap offset helper (BK=64 chunks) ----------------
template<int CIN, int WIN>
__device__ __forceinline__ int tapA_off(int kt) {
  int tap, ci0;
  if (CIN == 64)       { tap = kt;      ci0 = 0; }
  else if (CIN == 128) { tap = kt >> 1; ci0 = (kt & 1) << 6; }
  else                 { tap = kt >> 2; ci0 = (kt & 3) << 6; }
  int dy = tap / 9, dx = tap - dy * 9;
  return (dy * WIN + dx) * CIN + ci0;
}

// ============ 8-phase 256x256 implicit-GEMM conv + K-third tail smoothing ===========
template<int HIN, int WIN, int CIN, int HOUT, int WOUT, int COUT, int STRIDE,
         bool RELU, bool OUTF16, int FULLB, int TAILB>
__global__ __launch_bounds__(512, 2) void conv8p_kernel(const f16* __restrict__ in,
                                                        const f16* __restrict__ wt,
                                                        const float* __restrict__ bias,
                                                        f16* __restrict__ out16,
                                                        float* __restrict__ out32,
                                                        f16* __restrict__ tp01,
                                                        f16* __restrict__ tp2) {
  static_assert(COUT == 256, "BN=256 template requires COUT==256");
  constexpr int KTOT = 81 * CIN;
  constexpr int NT = KTOT / 64;
  static_assert(TAILB == 0 || NT % 3 == 0, "K-third split requires NT%3==0");
  constexpr int PNT = (TAILB > 0) ? NT / 3 : NT;
  __shared__ __align__(16) f16 lds[65536];  // 128 KiB
  const int bid = (int)blockIdx.x;
  int mb, kt0, kt1;
  f16* tp = nullptr;
  if (TAILB == 0 || bid < FULLB) {
    mb = bid; kt0 = 0; kt1 = NT;
  } else {
    int idx = bid - FULLB;
    int piece = idx / TAILB;           // 0,1,2
    int loc = idx - piece * TAILB;
    mb = FULLB + loc;
    kt0 = piece * PNT; kt1 = kt0 + PNT;
    tp = (piece < 2 ? tp01 + (size_t)piece * TAILB * 65536 : tp2) + (size_t)loc * 65536;
  }
  const int t = threadIdx.x;
  const int wave = t >> 6, lane = t & 63;
  const int hi = lane >> 4, lo = lane & 15;
  const int wm = wave >> 2, wn = wave & 3;

  int Aoff[4], Boff[4];
  {
    int g = (lane & 7) ^ ((lane >> 3) & 7);  // inverse swizzle granule
#pragma unroll
    for (int rbi = 0; rbi < 4; ++rbi) {
      int r = rbi * 64 + 8 * wave + (lane >> 3);
      int m = mb * 256 + r;
      int b = m / (HOUT * WOUT);
      int rr = m - b * (HOUT * WOUT);
      int oh = rr / WOUT, ow = rr - oh * WOUT;
      Aoff[rbi] = ((b * HIN + oh * STRIDE) * WIN + ow * STRIDE) * CIN + g * 8;
      Boff[rbi] = r * KTOT + g * 8;
    }
  }
  const int gb0 = (hi ^ (lo & 7)) << 4;
  const int gb1 = ((4 + hi) ^ (lo & 7)) << 4;

  const char* ldsc = (const char*)lds;
  char* ldsw = (char*)lds;

#define GA(rbi, tpo, bq) gload_lds16(in + Aoff[rbi] + (tpo),                        \
    (void*)(ldsw + (bq) * 32768 + ((rbi) * 64 + 8 * wave) * 128))
#define GB(rbi, tile) gload_lds16(wt + Boff[rbi] + ((tile) << 6),                   \
    (void*)(ldsw + 65536 + ((tile) & 1) * 32768 + ((rbi) * 64 + 8 * wave) * 128))

  // Prologue: tile kt0 full (A then B), tile kt0+1 B. vmcnt(4) -> tile kt0 landed.
  {
    int tq = tapA_off<CIN, WIN>(kt0);
    int bq = kt0 & 1;
    GA(0, tq, bq); GA(2, tq, bq); GA(1, tq, bq); GA(3, tq, bq);
    GB(0, kt0); GB(1, kt0); GB(2, kt0); GB(3, kt0);
    GB(0, kt0 + 1); GB(1, kt0 + 1); GB(2, kt0 + 1); GB(3, kt0 + 1);
    asm volatile("s_waitcnt vmcnt(4)" ::: "memory");
    __builtin_amdgcn_s_barrier();
  }

  f32x4 acc[8][4] = {};

#define DO_PHASE(Q, STAGE)                                                          \
  {                                                                                 \
    f16x8 af[2][2];                                                                 \
    _Pragma("unroll")                                                               \
    for (int mf = 0; mf < 2; ++mf) {                                                \
      af[mf][0] = *(const f16x8*)(Ab + ((Q) * 2 + mf) * 2048 + gb0);                \
      af[mf][1] = *(const f16x8*)(Ab + ((Q) * 2 + mf) * 2048 + gb1);                \
    }                                                                               \
    STAGE;                                                                          \
    __builtin_amdgcn_s_barrier();                                                   \
    asm volatile("s_waitcnt lgkmcnt(0)" ::: "memory");                              \
    __builtin_amdgcn_sched_barrier(0);                                              \
    __builtin_amdgcn_s_setprio(1);                                                  \
    _Pragma("unroll")                                                               \
    for (int sb = 0; sb < 2; ++sb)                                                  \
      _Pragma("unroll")                                                             \
      for (int mf = 0; mf < 2; ++mf)                                                \
        _Pragma("unroll")                                                           \
        for (int nf = 0; nf < 4; ++nf)                                              \
          acc[(Q) * 2 + mf][nf] = __builtin_amdgcn_mfma_f32_16x16x32_f16(           \
              af[mf][sb], bfr[nf][sb], acc[(Q) * 2 + mf][nf], 0, 0, 0);             \
    __builtin_amdgcn_s_setprio(0);                                                  \
    __builtin_amdgcn_s_barrier();                                                   \
  }

  for (int T = kt0; T < kt1; ++T) {
    const int q = T & 1;
    const char* Ab = ldsc + q * 32768 + wm * 16384 + lo * 128;
    const char* Bb = ldsc + 65536 + q * 32768 + wn * 8192 + lo * 128;
    const int tpn = tapA_off<CIN, WIN>(T + 1);  // used only if T+1 < kt1
    f16x8 bfr[4][2];
#pragma unroll
    for (int nf = 0; nf < 4; ++nf) {
      bfr[nf][0] = *(const f16x8*)(Bb + nf * 2048 + gb0);
      bfr[nf][1] = *(const f16x8*)(Bb + nf * 2048 + gb1);
    }
    DO_PHASE(0, if (T + 1 < kt1) { GA(0, tpn, (T + 1) & 1); GA(2, tpn, (T + 1) & 1); })
    DO_PHASE(1, if (T + 1 < kt1) { GA(1, tpn, (T + 1) & 1); GA(3, tpn, (T + 1) & 1); })
    DO_PHASE(2, if (T + 2 < kt1) { GB(0, T + 2); GB(1, T + 2); })
    DO_PHASE(3,
      if (T + 2 < kt1) {
        GB(2, T + 2); GB(3, T + 2);
        asm volatile("s_waitcnt vmcnt(4)" ::: "memory");
      } else {
        asm volatile("s_waitcnt vmcnt(0)" ::: "memory");
      })
  }
#undef DO_PHASE
#undef GA
#undef GB

  // Epilogue: C/D layout col = lane&15, row = (lane>>4)*4 + reg
  if (tp == nullptr) {
#pragma unroll
    for (int mfr = 0; mfr < 8; ++mfr) {
#pragma unroll
      for (int nf = 0; nf < 4; ++nf) {
        int m0 = mb * 256 + wm * 128 + mfr * 16 + hi * 4;
        int n = wn * 64 + nf * 16 + lo;
        float bval = bias[n];
#pragma unroll
        for (int r = 0; r < 4; ++r) {
          float v = acc[mfr][nf][r] + bval;
          if (RELU) v = fmaxf(v, 0.f);
          int o = (m0 + r) * COUT + n;
          if (OUTF16) out16[o] = (f16)v; else out32[o] = v;
        }
      }
    }
  } else {
#pragma unroll
    for (int mfr = 0; mfr < 8; ++mfr) {
#pragma unroll
      for (int nf = 0; nf < 4; ++nf) {
        int rowloc = wm * 128 + mfr * 16 + hi * 4;
        int n = wn * 64 + nf * 16 + lo;
#pragma unroll
        for (int r = 0; r < 4; ++r)
          tp[(rowloc + r) * 256 + n] = (f16)acc[mfr][nf][r];
      }
    }
  }
}

// ------- tail reduce: h3[tail rows] = relu(p0 + p1 + p2 + bias), x8 vec -----------
__global__ __launch_bounds__(256) void tailred3_kernel(const f16* __restrict__ tp01,
                                                       const f16* __restrict__ tp2,
                                                       const float* __restrict__ bias,
                                                       f16* __restrict__ h3) {
  int idx = blockIdx.x * 256 + threadIdx.x;  // 4608 blocks: 9,437,184 elems / 8
  int e0 = idx * 8;
  int n0 = e0 & 255;
  f16x8 a = *(const f16x8*)(tp01 + e0);
  f16x8 b = *(const f16x8*)(tp01 + 9437184 + e0);
  f16x8 c = *(const f16x8*)(tp2 + e0);
  f16x8 o;
#pragma unroll
  for (int j = 0; j < 8; ++j) {
    float v = (float)a[j] + (float)b[j] + (float)c[j] + bias[n0 + j];
    o[j] = (f16)fmaxf(v, 0.f);
  }
  *(f16x8*)(h3 + 16777216 + e0) = o;  // tail tiles start at m = 256*256
}

// ---------------- implicit-GEMM conv via f16 MFMA (m97 structure, 128x128) --------
template<int HIN, int WIN, int CIN, int HOUT, int WOUT, int COUT, int STRIDE,
         bool RELU, bool OUTF16, int SPLIT, bool ADDBIAS>
__global__ __launch_bounds__(256) void conv_mfma_kernel(const f16* __restrict__ in,
                                                        const f16* __restrict__ wt,
                                                        const float* __restrict__ bias,
                                                        f16* __restrict__ out16,
                                                        float* __restrict__ out32) {
  constexpr int KTOT = 81 * CIN;
  constexpr int NBLK = COUT / 128;
  constexpr int MTOT = 256 * HOUT * WOUT;
  constexpr int MBNB = (MTOT / 128) * NBLK;
  constexpr int NKT = (KTOT / 64) / SPLIT;
  __shared__ __align__(16) f16 lds[16384];
  int bidx = (int)blockIdx.x;
  int ks = 0;
  if (SPLIT > 1) { ks = bidx / MBNB; bidx -= ks * MBNB; }
  const int mb = bidx / NBLK;
  const int nb = bidx % NBLK;
  const int t = threadIdx.x;
  const int wave = t >> 6, lane = t & 63;
  const int hi = lane >> 4, lo = lane & 15;
  const bool isA = wave < 2;
  const int slot0 = wave << 9;

  int baseoff[8];
#pragma unroll
  for (int it = 0; it < 8; ++it) {
    int s = slot0 + it * 64 + lane;
    if (isA) {
      int row = s >> 3;
      int g = (s & 7) ^ (row & 7);
      int mg = mb * 128 + row;
      int b = mg / (HOUT * WOUT);
      int rr = mg - b * (HOUT * WOUT);
      int oh = rr / WOUT;
      int ow = rr - oh * WOUT;
      baseoff[it] = ((b * HIN + oh * STRIDE) * WIN + ow * STRIDE) * CIN + g * 8;
    } else {
      int sl = s - 1024;
      int row = sl >> 3;
      int g = (sl & 7) ^ (row & 7);
      baseoff[it] = (nb * 128 + row) * KTOT + g * 8;
    }
  }
  const f16* gsrc = isA ? in : wt;

  int aQ[4], bQ[4];
  const int wm = wave >> 1, wn = wave & 1;
#pragma unroll
  for (int f = 0; f < 4; ++f) {
    int arow = wm * 64 + f * 16 + lo;
    aQ[f] = (arow * 128) ^ ((arow & 7) << 4);
    int brow = wn * 64 + f * 16 + lo;
    bQ[f] = 16384 + ((brow * 128) ^ ((brow & 7) << 4));
  }

  f32x4 acc[4][4] = {};
  const char* ldsc = (const char*)lds;

  const int kt0 = ks * NKT;
  for (int kt = kt0; kt < kt0 + NKT; ++kt) {
    int tapoff;
    if (isA) tapoff = tapA_off<CIN, WIN>(kt);
    else     tapoff = kt << 6;
    __syncthreads();
#pragma unroll
    for (int it = 0; it < 8; ++it)
      gload_lds16(gsrc + baseoff[it] + tapoff,
                  (void*)((char*)lds + ((slot0 + it * 64) << 4)));
    __syncthreads();
#pragma unroll
    for (int sub = 0; sub < 2; ++sub) {
      const int gx = (sub * 4 + hi) << 4;
      f16x8 av[4], bv[4];
#pragma unroll
      for (int f = 0; f < 4; ++f) av[f] = *(const f16x8*)(ldsc + (aQ[f] ^ gx));
#pragma unroll
      for (int f = 0; f < 4; ++f) bv[f] = *(const f16x8*)(ldsc + (bQ[f] ^ gx));
#pragma unroll
      for (int mf = 0; mf < 4; ++mf)
#pragma unroll
        for (int nf = 0; nf < 4; ++nf)
          acc[mf][nf] = __builtin_amdgcn_mfma_f32_16x16x32_f16(av[mf], bv[nf],
                                                               acc[mf][nf], 0, 0, 0);
    }
  }

  float* o32 = out32 + (size_t)ks * MTOT * COUT;
#pragma unroll
  for (int mf = 0; mf < 4; ++mf) {
#pragma unroll
    for (int nf = 0; nf < 4; ++nf) {
      int m0 = mb * 128 + wm * 64 + mf * 16 + hi * 4;
      int n = nb * 128 + wn * 64 + nf * 16 + lo;
      float bval = ADDBIAS ? bias[n] : 0.f;
#pragma unroll
      for (int r = 0; r < 4; ++r) {
        float v = acc[mf][nf][r] + bval;
        if (RELU) v = fmaxf(v, 0.f);
        int o = (m0 + r) * COUT + n;
        if (OUTF16) out16[o] = (f16)v; else o32[o] = v;
      }
    }
  }
}

// ------- dense GEMM via f16 MFMA, K-split partials: A[256][K] x Bw[NP][K]^T --------
template<int K, int NP, int SPLIT>
__global__ __launch_bounds__(256) void gemm_mfma_kernel(const f16* __restrict__ A,
                                                        const f16* __restrict__ Bw,
                                                        float* __restrict__ dpart) {
  constexpr int NBLK = NP / 128;
  constexpr int MBNB = 2 * NBLK;
  constexpr int NKT = (K / 64) / SPLIT;
  __shared__ __align__(16) f16 lds[16384];
  int bidx = (int)blockIdx.x;
  int ks = 0;
  if (SPLIT > 1) { ks = bidx / MBNB; bidx -= ks * MBNB; }
  const int mb = bidx / NBLK;
  const int nb = bidx % NBLK;
  const int t = threadIdx.x;
  const int wave = t >> 6, lane = t & 63;
  const int hi = lane >> 4, lo = lane & 15;
  const bool isA = wave < 2;
  const int slot0 = wave << 9;

  int baseoff[8];
#pragma unroll
  for (int it = 0; it < 8; ++it) {
    int s = slot0 + it * 64 + lane;
    if (isA) {
      int row = s >> 3;
      int g = (s & 7) ^ (row & 7);
      baseoff[it] = (mb * 128 + row) * K + g * 8;
    } else {
      int sl = s - 1024;
      int row = sl >> 3;
      int g = (sl & 7) ^ (row & 7);
      baseoff[it] = (nb * 128 + row) * K + g * 8;
    }
  }
  const f16* gsrc = isA ? A : Bw;

  int aQ[4], bQ[4];
  const int wm = wave >> 1, wn = wave & 1;
#pragma unroll
  for (int f = 0; f < 4; ++f) {
    int arow = wm * 64 + f * 16 + lo;
    aQ[f] = (arow * 128) ^ ((arow & 7) << 4);
    int brow = wn * 64 + f * 16 + lo;
    bQ[f] = 16384 + ((brow * 128) ^ ((brow & 7) << 4));
  }

  f32x4 acc[4][4] = {};
  const char* ldsc = (const char*)lds;

  const int kt0 = ks * NKT;
  for (int kt = kt0; kt < kt0 + NKT; ++kt) {
    int tapoff = kt << 6;
    __syncthreads();
#pragma unroll
    for (int it = 0; it < 8; ++it)
      gload_lds16(gsrc + baseoff[it] + tapoff,
                  (void*)((char*)lds + ((slot0 + it * 64) << 4)));
    __syncthreads();
#pragma unroll
    for (int sub = 0; sub < 2; ++sub) {
      const int gx = (sub * 4 + hi) << 4;
      f16x8 av[4], bv[4];
#pragma unroll
      for (int f = 0; f < 4; ++f) av[f] = *(const f16x8*)(ldsc + (aQ[f] ^ gx));
#pragma unroll
      for (int f = 0; f < 4; ++f) bv[f] = *(const f16x8*)(ldsc + (bQ[f] ^ gx));
#pragma unroll
      for (int mf = 0; mf < 4; ++mf)
#pragma unroll
        for (int nf = 0; nf < 4; ++nf)
          acc[mf][nf] = __builtin_amdgcn_mfma_f32_16x16x32_f16(av[mf], bv[nf],
                                                               acc[mf][nf], 0, 0, 0);
    }
  }

  float* o32 = dpart + (size_t)ks * 256 * NP;
#pragma unroll
  for (int mf = 0; mf < 4; ++mf) {
#pragma unroll
    for (int nf = 0; nf < 4; ++nf) {
      int m0 = mb * 128 + wm * 64 + mf * 16 + hi * 4;
      int n = nb * 128 + wn * 64 + nf * 16 + lo;
#pragma unroll
      for (int r = 0; r < 4; ++r)
        o32[(m0 + r) * NP + n] = acc[mf][nf][r];
    }
  }
}

// ---------------- d2 reduce: r2 = relu(sum_s part + bias) f16, x4 vec ----------------
__global__ __launch_bounds__(256) void d2red_kernel(const float* __restrict__ part,
                                                    const float* __restrict__ bias,
                                                    f16* __restrict__ r2) {
  int idx = blockIdx.x * 256 + threadIdx.x;  // 512 blocks: 524288/4
  int e0 = idx * 4;
  int n0 = e0 & 2047;
  float4 a = *(const float4*)(part + e0);
  const float4 b1 = *(const float4*)(part + 524288 + e0);
  const float4 b2 = *(const float4*)(part + 1048576 + e0);
  const float4 b3 = *(const float4*)(part + 1572864 + e0);
  float v[4] = {a.x + b1.x + b2.x + b3.x, a.y + b1.y + b2.y + b3.y,
                a.z + b1.z + b2.z + b3.z, a.w + b1.w + b2.w + b3.w};
#pragma unroll
  for (int j = 0; j < 4; ++j)
    r2[e0 + j] = (f16)fmaxf(v[j] + bias[n0 + j], 0.f);
}

// ---------------- d3 reduce: recon = sigmoid(sum_s part + bias), mask n<1600 --------
__global__ __launch_bounds__(256) void d3red_kernel(const float* __restrict__ part,
                                                    const float* __restrict__ bias,
                                                    float* __restrict__ recon) {
  int idx = blockIdx.x * 256 + threadIdx.x;  // 416 blocks: 425984/4
  int e0 = idx * 4;
  int n0 = e0 % 1664;
  int m = e0 / 1664;
  float v[4] = {0.f, 0.f, 0.f, 0.f};
#pragma unroll
  for (int s = 0; s < 8; ++s) {
    float4 a = *(const float4*)(part + s * 425984 + e0);
    v[0] += a.x; v[1] += a.y; v[2] += a.z; v[3] += a.w;
  }
#pragma unroll
  for (int j = 0; j < 4; ++j) {
    int n = n0 + j;
    if (n < 1600)
      recon[m * 1600 + n] = 1.f / (1.f + expf(-(v[j] + bias[n])));
  }
}

// ======================= fused routing =======================
// uhatps: block (ic of 9, bg of 32) batches 8 b's; folds prim_reduce over 6 K-split
// partial slices (u = bias + sum_{s<6} part[s]).
__global__ __launch_bounds__(320) void uhatps_kernel(const float* __restrict__ wf,
                                                     const float* __restrict__ part,
                                                     const float* __restrict__ pbias,
                                                     f16* __restrict__ uh,
                                                     float* __restrict__ parts) {
  __shared__ float pl[8][128][8];  // 32 KB
  int blk = (int)blockIdx.x;       // 9 * 32 = 288
  int ic = blk / 32, bg = blk - ic * 32;
  int b0 = bg * 8;
  int t = threadIdx.x;
  for (int e = t; e < 8192; e += 320) {
    int b8 = e >> 10;
    int el = e & 1023;
    float a = pbias[el & 255];
    int gi = (b0 + b8) * 9216 + ic * 1024 + el;
#pragma unroll
    for (int s = 0; s < 6; ++s) a += part[s * 2359296 + gi];
    pl[b8][el >> 3][el & 7] = a;
  }
  __syncthreads();
  int half = (t >= 160) ? 1 : 0;
  int jk = t - half * 160;
  int ibase = ic * 128 + half * 64;
  float sum[8] = {};
  for (int il = 0; il < 64; ++il) {
    int i = ibase + il;
    const float4* w4 = (const float4*)(wf + (i * 160 + jk) * 8);
    float4 w0 = w4[0], w1 = w4[1];
    int row = half * 64 + il;
#pragma unroll
    for (int b8 = 0; b8 < 8; ++b8) {
      const float* pr = pl[b8][row];
      float acc = w0.x * pr[0] + w0.y * pr[1] + w0.z * pr[2] + w0.w * pr[3] +
                  w1.x * pr[4] + w1.y * pr[5] + w1.z * pr[6] + w1.w * pr[7];
      uh[((size_t)(b0 + b8) * 1152 + i) * 160 + jk] = (f16)acc;
      sum[b8] += acc;
    }
  }
#pragma unroll
  for (int b8 = 0; b8 < 8; ++b8)
    parts[((b0 + b8) * 18 + ic * 2 + half) * 160 + jk] = sum[b8];
}

template<int NCH, bool FIRST, bool WRITEB>
__global__ __launch_bounds__(256) void ba_kernel(const f16* __restrict__ uh,
                                                 const float* __restrict__ psrc,
                                                 float cscale,
                                                 float* __restrict__ blog,
                                                 float* __restrict__ pdst) {
  __shared__ f16 ul[128 * 172];   // 44,032 B
  __shared__ float vl[160];
  __shared__ float csm[128 * 10];
  int blk = (int)blockIdx.x;
  int b = blk / 9, ic = blk - b * 9;
  int t = threadIdx.x;
  const f16* ub = uh + (size_t)(b * 1152 + ic * 128) * 160;
  for (int e = t; e < 2560; e += 256) {  // 128 rows x 20 vec8
    int row = e / 20, col = e - row * 20;
    *(f16x8*)(ul + row * 172 + col * 8) = *(const f16x8*)(ub + row * 160 + col * 8);
  }
  if (t < 160) {
    float s = 0.f;
    for (int c = 0; c < NCH; ++c) s += psrc[(b * NCH + c) * 160 + t];
    s *= cscale;
    float ss = s * s;
    ss += __shfl_xor(ss, 1, 16);
    ss += __shfl_xor(ss, 2, 16);
    ss += __shfl_xor(ss, 4, 16);
    ss += __shfl_xor(ss, 8, 16);
    float n = sqrtf(ss);
    float f = ss / ((1.f + ss) * (n + 1e-7f));
    vl[t] = f * s;
  }
  __syncthreads();

  int il = t >> 1, half = t & 1, j0 = half * 5;
  const f16* ur = ul + il * 172 + j0 * 16;
  float agr[5];
#pragma unroll
  for (int j = 0; j < 5; ++j) {
    f16x8 a0 = *(const f16x8*)(ur + j * 16);
    f16x8 a1 = *(const f16x8*)(ur + j * 16 + 8);
    const float* vv = vl + (j0 + j) * 16;
    float s = (float)a0[0] * vv[0] + (float)a0[1] * vv[1] + (float)a0[2] * vv[2] +
              (float)a0[3] * vv[3] + (float)a0[4] * vv[4] + (float)a0[5] * vv[5] +
              (float)a0[6] * vv[6] + (float)a0[7] * vv[7] +
              (float)a1[0] * vv[8] + (float)a1[1] * vv[9] + (float)a1[2] * vv[10] +
              (float)a1[3] * vv[11] + (float)a1[4] * vv[12] + (float)a1[5] * vv[13] +
              (float)a1[6] * vv[14] + (float)a1[7] * vv[15];
    agr[j] = s;
  }
  int bbase = (b * 1152 + ic * 128 + il) * 10 + j0;
  float bl[5];
#pragma unroll
  for (int j = 0; j < 5; ++j) bl[j] = (FIRST ? 0.f : blog[bbase + j]) + agr[j];
  if (WRITEB) {
#pragma unroll
    for (int j = 0; j < 5; ++j) blog[bbase + j] = bl[j];
  }
  float mx = bl[0];
#pragma unroll
  for (int j = 1; j < 5; ++j) mx = fmaxf(mx, bl[j]);
  mx = fmaxf(mx, __shfl_xor(mx, 1));
  float e5[5], se = 0.f;
#pragma unroll
  for (int j = 0; j < 5; ++j) { e5[j] = expf(bl[j] - mx); se += e5[j]; }
  se += __shfl_xor(se, 1);
  float inv = 1.f / se;
#pragma unroll
  for (int j = 0; j < 5; ++j) csm[il * 10 + j0 + j] = e5[j] * inv;
  __syncthreads();

  if (t < 160) {
    int j = t >> 4;
    float s = 0.f;
    for (int il2 = 0; il2 < 128; ++il2)
      s += csm[il2 * 10 + j] * (float)ul[il2 * 172 + t];
    pdst[(b * 9 + ic) * 160 + t] = s;
  }
}

// maskd1v: folds final sred (v3 from parts, writes vout) + mask + dense1.
__global__ __launch_bounds__(1024) void maskd1v_kernel(const float* __restrict__ parts,
                                                       const int* __restrict__ y,
                                                       const float* __restrict__ w1,
                                                       const float* __restrict__ b1,
                                                       float* __restrict__ vout,
                                                       f16* __restrict__ r1) {
  __shared__ float vl[160];
  int b = blockIdx.x, t = threadIdx.x;
  if (t < 160) {
    float s = 0.f;
    for (int c = 0; c < 9; ++c) s += parts[(b * 9 + c) * 160 + t];
    float ss = s * s;
    ss += __shfl_xor(ss, 1, 16);
    ss += __shfl_xor(ss, 2, 16);
    ss += __shfl_xor(ss, 4, 16);
    ss += __shfl_xor(ss, 8, 16);
    float n = sqrtf(ss);
    float f = ss / ((1.f + ss) * (n + 1e-7f));
    float v = f * s;
    vl[t] = v;
    vout[b * 160 + t] = v;
  }
  __syncthreads();
  int yb = y[b];
  float acc = b1[t];
#pragma unroll
  for (int k = 0; k < 16; ++k) acc += vl[yb * 16 + k] * w1[(yb * 16 + k) * 1024 + t];
  r1[b * 1024 + t] = (f16)fmaxf(acc, 0.f);
}

// ---------------- launch ----------------
extern "C" void kernel_launch(void* const* d_in, const int* in_sizes, int n_in,
                              void* d_out, int out_size, void* d_ws, size_t ws_size,
                              hipStream_t stream) {
  const float* x       = (const float*)d_in[0];
  const int*   y       = (const int*)d_in[1];
  const float* conv1_k = (const float*)d_in[2];
  const float* conv1_b = (const float*)d_in[3];
  const float* conv2_k = (const float*)d_in[4];
  const float* conv2_b = (const float*)d_in[5];
  const float* conv3_k = (const float*)d_in[6];
  const float* conv3_b = (const float*)d_in[7];
  const float* prim_k  = (const float*)d_in[8];
  const float* prim_b  = (const float*)d_in[9];
  const float* w_route = (const float*)d_in[10];
  const float* d1_w = (const float*)d_in[11];
  const float* d1_b = (const float*)d_in[12];
  const float* d2_w = (const float*)d_in[13];
  const float* d2_b = (const float*)d_in[14];
  const float* d3_w = (const float*)d_in[15];
  const float* d3_b = (const float*)d_in[16];

  // workspace layout (bytes), total 191,021,056 (same as R1-R11 -> proven fits).
  // Liveness (re-derived for prim SPLIT=6):
  //  conv1/2-era: h1[0,42.5M), h2[42.5M,93.8M)
  //  conv3-era:   tpart01[0,37.7M), h2 live, h3[93.8M,146.3M), tpart2[146.3M,165.2M)
  //  prim-era:    part[0,56.6M) (tparts dead), h3+wtp live
  //  uhatps-era:  reads part[0,56.6M); writes uhat[56.6M,151.0M), parts_a[151.0M,153.9M)
  //  ba-era:      uhat live; parts_b[153.9M,155.4M); blog[155.7M,167.5M)
  //  dense-era:   dpart2[0,8.4M), dpart3[16.8M,30.4M) (part/uhat dead)
  char* ws = (char*)d_ws;
  f16*   h1      = (f16*)(ws + 0);
  f16*   tpart01 = (f16*)(ws + 0);                   // 2 x 18,874,368 B
  float* part    = (float*)(ws + 0);                 // 6 x 9,437,184 B = 56,623,104
  float* dpart2  = (float*)(ws + 0);                 //  8,388,608 B
  float* dpart3  = (float*)(ws + 16777216);          // 13,631,488 B
  f16*   h2      = (f16*)(ws + 42467328);
  f16*   uhat    = (f16*)(ws + 56623104);            // 94,371,840 B -> ends 150,994,944
  f16*   h3      = (f16*)(ws + 93847552);
  f16*   tpart2  = (f16*)(ws + 146276352);           // 18,874,368 B (conv3-era only)
  float* parts_a = (float*)(ws + 150994944);         //  2,949,120 B -> ends 153,944,064
  float* parts_b = (float*)(ws + 153944064);         //  1,474,560 B -> ends 155,418,624
  float* blog    = (float*)(ws + 155713536);         // 11,796,480 B -> ends 167,510,016
  f16*   r1h     = (f16*)(ws + 167673856);           //    524,288 B
  f16*   r2h     = (f16*)(ws + 168198144);           //  1,048,576 B
  f16*   wt2     = (f16*)(ws + 170819584);           //  1,327,104 B
  f16*   wt3     = (f16*)(ws + 172146688);           //  5,308,416 B
  f16*   wtp     = (f16*)(ws + 177455104);           // 10,616,832 B (dead after prim)
  f16*   wd2     = (f16*)(ws + 177455104);           //  4,194,304 B (alias wtp)
  f16*   wd3     = (f16*)(ws + 181649408);           //  6,815,744 B -> ends 188,465,152

  float* vout  = (float*)d_out;            // [256,1,10,16] = 40960 f32
  float* recon = (float*)d_out + 40960;    // [256,1600]

  // conv weight prep + conv1 (one launch)
  wprepc_kernel<<<12474, 256, 0, stream>>>(conv2_k, wt2, conv3_k, wt3, prim_k, wtp,
                                           x, conv1_k, conv1_b, h1);

  // conv stack
  conv_mfma_kernel<36, 36, 64, 28, 28, 128, 1, true, true, 1, true>
      <<<1568, 256, 0, stream>>>(h1, wt2, conv2_b, h2, nullptr);
  // conv3: 8-phase 256^2 + K-third tail smoothing (256 fulls + 432 thirds)
  conv8p_kernel<28, 28, 128, 20, 20, 256, 1, true, true, 256, 144>
      <<<688, 512, 0, stream>>>(h2, wt3, conv3_b, h3, nullptr, tpart01, tpart2);
  tailred3_kernel<<<4608, 256, 0, stream>>>(tpart01, tpart2, conv3_b, h3);
  // prim caps: K-split x6 (864 blocks = 3.375/CU, m97 rate-saturating occupancy)
  conv_mfma_kernel<20, 20, 256, 6, 6, 256, 2, false, false, 6, false>
      <<<864, 256, 0, stream>>>(h3, wtp, prim_b, nullptr, part);

  // fused routing (uhatps folds 6-way prim reduce; batches 8 b's/block)
  uhatps_kernel<<<288, 320, 0, stream>>>(w_route, part, prim_b, uhat, parts_a);
  wprepd_kernel<<<1344, 256, 0, stream>>>(d2_w, wd2, d3_w, wd3);  // wtp dead now
  ba_kernel<18, true, true><<<2304, 256, 0, stream>>>(uhat, parts_a, 0.1f, blog, parts_b);
  ba_kernel<9, false, false><<<2304, 256, 0, stream>>>(uhat, parts_b, 1.0f, blog, parts_a);

  // masked reconstruction
  maskd1v_kernel<<<256, 1024, 0, stream>>>(parts_a, y, d1_w, d1_b, vout, r1h);
  gemm_mfma_kernel<1024, 2048, 4><<<128, 256, 0, stream>>>(r1h, wd2, dpart2);
  d2red_kernel<<<512, 256, 0, stream>>>(dpart2, d2_b, r2h);
  gemm_mfma_kernel<2048, 1664, 8><<<208, 256, 0, stream>>>(r2h, wd3, dpart3);
  d3red_kernel<<<416, 256, 0, stream>>>(dpart3, d3_b, recon);
}

// Round 13
// 1118.918 us; speedup vs baseline: 1.1253x; 1.0254x over previous
//
#include <hip/hip_runtime.h>
#include <hip/hip_bf16.h>

typedef _Float16 f16;
typedef __attribute__((ext_vector_type(8))) _Float16 f16x8;
typedef __attribute__((ext_vector_type(4))) float f32x4;

// ---------------- global_load_lds helper (16B, wave-uniform LDS base + lane*16) ----
__device__ __forceinline__ void gload_lds16(const void* g, void* l) {
  __builtin_amdgcn_global_load_lds((const __attribute__((address_space(1))) void*)g,
                                   (__attribute__((address_space(3))) void*)l, 16, 0, 0);
}

// ---------------- generic weight transpose body: [K][N] f32 -> [NP][K] f16 ----------
__device__ __forceinline__ void wtrans_body(const float* __restrict__ src,
                                            f16* __restrict__ dst,
                                            int K, int N, int k0, int n0) {
  __shared__ float tile[64][65];
  int t = threadIdx.x;
#pragma unroll
  for (int i = 0; i < 16; ++i) {
    int id = t + i * 256;
    int r = id >> 6, c = id & 63;  // r = k_local, c = n_local
    tile[r][c] = (n0 + c < N) ? src[(size_t)(k0 + r) * N + n0 + c] : 0.f;
  }
  __syncthreads();
#pragma unroll
  for (int i = 0; i < 16; ++i) {
    int id = t + i * 256;
    int r = id >> 6, c = id & 63;  // r = n_local, c = k_local
    dst[(size_t)(n0 + r) * K + k0 + c] = (f16)tile[c][r];
  }
}

// wprepc: conv weight prep (3 jobs) + conv1 fused (grid tail).
__global__ __launch_bounds__(256) void wprepc_kernel(const float* __restrict__ s0, f16* __restrict__ d0,
                                                     const float* __restrict__ s1, f16* __restrict__ d1,
                                                     const float* __restrict__ s2, f16* __restrict__ d2,
                                                     const float* __restrict__ x,
                                                     const float* __restrict__ c1k,
                                                     const float* __restrict__ c1b,
                                                     f16* __restrict__ h1) {
  int bid = (int)blockIdx.x;
  if (bid < 162) {
    int bx = bid % 81, by = bid / 81;
    wtrans_body(s0, d0, 5184, 128, bx * 64, by * 64);
  } else if (bid < 810) {
    int l = bid - 162; int bx = l % 162, by = l / 162;
    wtrans_body(s1, d1, 10368, 256, bx * 64, by * 64);
  } else if (bid < 2106) {
    int l = bid - 810; int bx = l % 324, by = l / 324;
    wtrans_body(s2, d2, 20736, 256, bx * 64, by * 64);
  } else {
    // conv1: 5x5, Cin=1, Cout=64, relu, f16 out (8 couts/thread)
    int idx = (bid - 2106) * 256 + threadIdx.x;  // 256*36*36*8 threads
    int g = idx & 7;
    int co0 = g * 8;
    int r = idx >> 3;
    int ow = r % 36; int r2 = r / 36; int oh = r2 % 36; int b = r2 / 36;
    float acc[8];
#pragma unroll
    for (int j = 0; j < 8; ++j) acc[j] = c1b[co0 + j];
    const float* xp = x + (b * 40 + oh) * 40 + ow;
#pragma unroll
    for (int dy = 0; dy < 5; ++dy)
#pragma unroll
      for (int dx = 0; dx < 5; ++dx) {
        float xv = xp[dy * 40 + dx];
        const float* kp = c1k + (dy * 5 + dx) * 64 + co0;
#pragma unroll
        for (int j = 0; j < 8; ++j) acc[j] += xv * kp[j];
      }
    f16x8 o;
#pragma unroll
    for (int j = 0; j < 8; ++j) o[j] = (f16)fmaxf(acc[j], 0.f);
    *(f16x8*)(h1 + r * 64 + co0) = o;
  }
}

// wprepd: dense weight prep (2 jobs): d2 (K=1024,N=2048), d3 (K=2048,N=1600,NP=1664).
__global__ __launch_bounds__(256) void wprepd_kernel(const float* __restrict__ s0, f16* __restrict__ d0,
                                                     const float* __restrict__ s1, f16* __restrict__ d1) {
  int bid = (int)blockIdx.x;
  if (bid < 512) {
    int bx = bid % 16, by = bid / 16;
    wtrans_body(s0, d0, 1024, 2048, bx * 64, by * 64);
  } else {
    int l = bid - 512; int bx = l % 32, by = l / 32;
    wtrans_body(s1, d1, 2048, 1600, bx * 64, by * 64);
  }
}

// ---------------- im2col tap offset helpers ----------------
template<int CIN, int WIN>
__device__ __forceinline__ int tapA_off(int kt) {  // BK=64 chunks
  int tap, ci0;
  if (CIN == 64)       { tap = kt;      ci0 = 0; }
  else if (CIN == 128) { tap = kt >> 1; ci0 = (kt & 1) << 6; }
  else                 { tap = kt >> 2; ci0 = (kt & 3) << 6; }
  int dy = tap / 9, dx = tap - dy * 9;
  return (dy * WIN + dx) * CIN + ci0;
}

template<int CIN, int WIN>
__device__ __forceinline__ int tap32_off(int kt) {  // BK=32 chunks
  constexpr int CPT = CIN / 32;
  int tap = kt / CPT, ci0 = (kt % CPT) * 32;
  int dy = tap / 9, dx = tap - dy * 9;
  return (dy * WIN + dx) * CIN + ci0;
}

// ============ 8-phase 256x256 implicit-GEMM conv + K-third tail smoothing ===========
template<int HIN, int WIN, int CIN, int HOUT, int WOUT, int COUT, int STRIDE,
         bool RELU, bool OUTF16, int FULLB, int TAILB>
__global__ __launch_bounds__(512, 2) void conv8p_kernel(const f16* __restrict__ in,
                                                        const f16* __restrict__ wt,
                                                        const float* __restrict__ bias,
                                                        f16* __restrict__ out16,
                                                        float* __restrict__ out32,
                                                        f16* __restrict__ tp01,
                                                        f16* __restrict__ tp2) {
  static_assert(COUT == 256, "BN=256 template requires COUT==256");
  constexpr int KTOT = 81 * CIN;
  constexpr int NT = KTOT / 64;
  static_assert(TAILB == 0 || NT % 3 == 0, "K-third split requires NT%3==0");
  constexpr int PNT = (TAILB > 0) ? NT / 3 : NT;
  __shared__ __align__(16) f16 lds[65536];  // 128 KiB
  const int bid = (int)blockIdx.x;
  int mb, kt0, kt1;
  f16* tp = nullptr;
  if (TAILB == 0 || bid < FULLB) {
    mb = bid; kt0 = 0; kt1 = NT;
  } else {
    int idx = bid - FULLB;
    int piece = idx / TAILB;           // 0,1,2
    int loc = idx - piece * TAILB;
    mb = FULLB + loc;
    kt0 = piece * PNT; kt1 = kt0 + PNT;
    tp = (piece < 2 ? tp01 + (size_t)piece * TAILB * 65536 : tp2) + (size_t)loc * 65536;
  }
  const int t = threadIdx.x;
  const int wave = t >> 6, lane = t & 63;
  const int hi = lane >> 4, lo = lane & 15;
  const int wm = wave >> 2, wn = wave & 3;

  int Aoff[4], Boff[4];
  {
    int g = (lane & 7) ^ ((lane >> 3) & 7);  // inverse swizzle granule
#pragma unroll
    for (int rbi = 0; rbi < 4; ++rbi) {
      int r = rbi * 64 + 8 * wave + (lane >> 3);
      int m = mb * 256 + r;
      int b = m / (HOUT * WOUT);
      int rr = m - b * (HOUT * WOUT);
      int oh = rr / WOUT, ow = rr - oh * WOUT;
      Aoff[rbi] = ((b * HIN + oh * STRIDE) * WIN + ow * STRIDE) * CIN + g * 8;
      Boff[rbi] = r * KTOT + g * 8;
    }
  }
  const int gb0 = (hi ^ (lo & 7)) << 4;
  const int gb1 = ((4 + hi) ^ (lo & 7)) << 4;

  const char* ldsc = (const char*)lds;
  char* ldsw = (char*)lds;

#define GA(rbi, tpo, bq) gload_lds16(in + Aoff[rbi] + (tpo),                        \
    (void*)(ldsw + (bq) * 32768 + ((rbi) * 64 + 8 * wave) * 128))
#define GB(rbi, tile) gload_lds16(wt + Boff[rbi] + ((tile) << 6),                   \
    (void*)(ldsw + 65536 + ((tile) & 1) * 32768 + ((rbi) * 64 + 8 * wave) * 128))

  // Prologue: tile kt0 full (A then B), tile kt0+1 B. vmcnt(4) -> tile kt0 landed.
  {
    int tq = tapA_off<CIN, WIN>(kt0);
    int bq = kt0 & 1;
    GA(0, tq, bq); GA(2, tq, bq); GA(1, tq, bq); GA(3, tq, bq);
    GB(0, kt0); GB(1, kt0); GB(2, kt0); GB(3, kt0);
    GB(0, kt0 + 1); GB(1, kt0 + 1); GB(2, kt0 + 1); GB(3, kt0 + 1);
    asm volatile("s_waitcnt vmcnt(4)" ::: "memory");
    __builtin_amdgcn_s_barrier();
  }

  f32x4 acc[8][4] = {};

#define DO_PHASE(Q, STAGE)                                                          \
  {                                                                                 \
    f16x8 af[2][2];                                                                 \
    _Pragma("unroll")                                                               \
    for (int mf = 0; mf < 2; ++mf) {                                                \
      af[mf][0] = *(const f16x8*)(Ab + ((Q) * 2 + mf) * 2048 + gb0);                \
      af[mf][1] = *(const f16x8*)(Ab + ((Q) * 2 + mf) * 2048 + gb1);                \
    }                                                                               \
    STAGE;                                                                          \
    __builtin_amdgcn_s_barrier();                                                   \
    asm volatile("s_waitcnt lgkmcnt(0)" ::: "memory");                              \
    __builtin_amdgcn_sched_barrier(0);                                              \
    __builtin_amdgcn_s_setprio(1);                                                  \
    _Pragma("unroll")                                                               \
    for (int sb = 0; sb < 2; ++sb)                                                  \
      _Pragma("unroll")                                                             \
      for (int mf = 0; mf < 2; ++mf)                                                \
        _Pragma("unroll")                                                           \
        for (int nf = 0; nf < 4; ++nf)                                              \
          acc[(Q) * 2 + mf][nf] = __builtin_amdgcn_mfma_f32_16x16x32_f16(           \
              af[mf][sb], bfr[nf][sb], acc[(Q) * 2 + mf][nf], 0, 0, 0);             \
    __builtin_amdgcn_s_setprio(0);                                                  \
    __builtin_amdgcn_s_barrier();                                                   \
  }

  for (int T = kt0; T < kt1; ++T) {
    const int q = T & 1;
    const char* Ab = ldsc + q * 32768 + wm * 16384 + lo * 128;
    const char* Bb = ldsc + 65536 + q * 32768 + wn * 8192 + lo * 128;
    const int tpn = tapA_off<CIN, WIN>(T + 1);  // used only if T+1 < kt1
    f16x8 bfr[4][2];
#pragma unroll
    for (int nf = 0; nf < 4; ++nf) {
      bfr[nf][0] = *(const f16x8*)(Bb + nf * 2048 + gb0);
      bfr[nf][1] = *(const f16x8*)(Bb + nf * 2048 + gb1);
    }
    DO_PHASE(0, if (T + 1 < kt1) { GA(0, tpn, (T + 1) & 1); GA(2, tpn, (T + 1) & 1); })
    DO_PHASE(1, if (T + 1 < kt1) { GA(1, tpn, (T + 1) & 1); GA(3, tpn, (T + 1) & 1); })
    DO_PHASE(2, if (T + 2 < kt1) { GB(0, T + 2); GB(1, T + 2); })
    DO_PHASE(3,
      if (T + 2 < kt1) {
        GB(2, T + 2); GB(3, T + 2);
        asm volatile("s_waitcnt vmcnt(4)" ::: "memory");
      } else {
        asm volatile("s_waitcnt vmcnt(0)" ::: "memory");
      })
  }
#undef DO_PHASE
#undef GA
#undef GB

  // Epilogue: C/D layout col = lane&15, row = (lane>>4)*4 + reg
  if (tp == nullptr) {
#pragma unroll
    for (int mfr = 0; mfr < 8; ++mfr) {
#pragma unroll
      for (int nf = 0; nf < 4; ++nf) {
        int m0 = mb * 256 + wm * 128 + mfr * 16 + hi * 4;
        int n = wn * 64 + nf * 16 + lo;
        float bval = bias[n];
#pragma unroll
        for (int r = 0; r < 4; ++r) {
          float v = acc[mfr][nf][r] + bval;
          if (RELU) v = fmaxf(v, 0.f);
          int o = (m0 + r) * COUT + n;
          if (OUTF16) out16[o] = (f16)v; else out32[o] = v;
        }
      }
    }
  } else {
#pragma unroll
    for (int mfr = 0; mfr < 8; ++mfr) {
#pragma unroll
      for (int nf = 0; nf < 4; ++nf) {
        int rowloc = wm * 128 + mfr * 16 + hi * 4;
        int n = wn * 64 + nf * 16 + lo;
#pragma unroll
        for (int r = 0; r < 4; ++r)
          tp[(rowloc + r) * 256 + n] = (f16)acc[mfr][nf][r];
      }
    }
  }
}

// ============ BM=512 x BN=128, BK=32 deep-pipelined conv (conv2 shape) ==============
// 8 waves (4M x 2N), per-wave C = 128x64 (acc[8][4]). LDS 80KB: A dbuf 2x32K @0,
// B dbuf 2x8K @65536 (byte offsets). Swizzle (convdp-verified, BK=32): source
// granule g = (lane&3)^((lane>>3)&3); read granule slot = hi ^ ((lo>>1)&3).
// Per K-tile (2 phases x 16 MFMA): P0 reads mfr0..3, stages A(T+1) calls 0,1;
// P1 reads mfr4..7, stages A(T+1) calls 2,3 + B(T+2), vmcnt(1) (newest-1 =
// B(T+2) flies; A(T+1) & B(T+1) enforced landed). B-overwrite of buf T&1 by
// B(T+2) is issued after P0's end barrier => all waves' bfr hoists complete.
// K-third tail smoothing: grid = FULLB + 3*TAILB (NT=162, thirds of 54).
template<int HIN, int WIN, int CIN, int HOUT, int WOUT, int COUT, int STRIDE,
         bool RELU, int FULLB, int TAILB>
__global__ __launch_bounds__(512, 2) void conv8pw_kernel(const f16* __restrict__ in,
                                                         const f16* __restrict__ wt,
                                                         const float* __restrict__ bias,
                                                         f16* __restrict__ out16,
                                                         f16* __restrict__ tp01,
                                                         f16* __restrict__ tp2) {
  static_assert(COUT == 128, "BN=128 template requires COUT==128");
  constexpr int KTOT = 81 * CIN;
  constexpr int NT = KTOT / 32;
  static_assert(TAILB == 0 || NT % 3 == 0, "K-third split requires NT%3==0");
  constexpr int PNT = (TAILB > 0) ? NT / 3 : NT;
  __shared__ __align__(16) f16 lds[40960];  // 80 KiB
  const int bid = (int)blockIdx.x;
  int mb, kt0, kt1;
  f16* tp = nullptr;
  if (TAILB == 0 || bid < FULLB) {
    mb = bid; kt0 = 0; kt1 = NT;
  } else {
    int idx = bid - FULLB;
    int piece = idx / TAILB;           // 0,1,2
    int loc = idx - piece * TAILB;
    mb = FULLB + loc;
    kt0 = piece * PNT; kt1 = kt0 + PNT;
    tp = (piece < 2 ? tp01 + (size_t)piece * TAILB * 65536 : tp2) + (size_t)loc * 65536;
  }
  const int t = threadIdx.x;
  const int wave = t >> 6, lane = t & 63;
  const int hi = lane >> 4, lo = lane & 15;
  const int wm = wave >> 1, wn = wave & 1;  // 4M x 2N

  // Staging source offsets. Call c covers A rows c*128 + 16*wave + (lane>>2);
  // B call covers rows 16*wave + (lane>>2). Row = 32 f16 = 64B (4 granules).
  int Aoff[4], Boff;
  {
    int g = (lane & 3) ^ ((lane >> 3) & 3);  // inverse-swizzled data granule
#pragma unroll
    for (int c = 0; c < 4; ++c) {
      int r = c * 128 + 16 * wave + (lane >> 2);
      int m = mb * 512 + r;
      int b = m / (HOUT * WOUT);
      int rr = m - b * (HOUT * WOUT);
      int oh = rr / WOUT, ow = rr - oh * WOUT;
      Aoff[c] = ((b * HIN + oh * STRIDE) * WIN + ow * STRIDE) * CIN + g * 8;
    }
    Boff = (16 * wave + (lane >> 2)) * KTOT + g * 8;
  }
  const int gbx = (hi ^ ((lo >> 1) & 3)) << 4;  // fragment-read granule bytes

  const char* ldsc = (const char*)lds;
  char* ldsw = (char*)lds;

#define GA(c, tpo, bq) gload_lds16(in + Aoff[c] + (tpo),                            \
    (void*)(ldsw + (bq) * 32768 + ((c) * 128 + 16 * wave) * 64))
#define GB(tile) gload_lds16(wt + Boff + (tile) * 32,                               \
    (void*)(ldsw + 65536 + ((tile) & 1) * 8192 + (16 * wave) * 64))

  // Prologue: A(kt0) x4, B(kt0), B(kt0+1). vmcnt(1) -> A(kt0),B(kt0) landed.
  {
    int tq = tap32_off<CIN, WIN>(kt0);
    int bq = kt0 & 1;
    GA(0, tq, bq); GA(1, tq, bq); GA(2, tq, bq); GA(3, tq, bq);
    GB(kt0); GB(kt0 + 1);
    asm volatile("s_waitcnt vmcnt(1)" ::: "memory");
    __builtin_amdgcn_s_barrier();
  }

  f32x4 acc[8][4] = {};

  for (int T = kt0; T < kt1; ++T) {
    const int q = T & 1;
    const char* Ab = ldsc + q * 32768 + (wm * 128 + lo) * 64;          // + mfr*1024
    const char* Bb = ldsc + 65536 + q * 8192 + (wn * 64 + lo) * 64;    // + nf*1024
    const int tpn = tap32_off<CIN, WIN>(T + 1);  // used only if T+1 < kt1
    f16x8 bfr[4];
#pragma unroll
    for (int nf = 0; nf < 4; ++nf)
      bfr[nf] = *(const f16x8*)(Bb + nf * 1024 + gbx);
    // ---- P0: mfr 0..3 ----
    {
      f16x8 af[4];
#pragma unroll
      for (int mf = 0; mf < 4; ++mf)
        af[mf] = *(const f16x8*)(Ab + mf * 1024 + gbx);
      if (T + 1 < kt1) { GA(0, tpn, (T + 1) & 1); GA(1, tpn, (T + 1) & 1); }
      __builtin_amdgcn_s_barrier();
      asm volatile("s_waitcnt lgkmcnt(0)" ::: "memory");
      __builtin_amdgcn_sched_barrier(0);
      __builtin_amdgcn_s_setprio(1);
#pragma unroll
      for (int mf = 0; mf < 4; ++mf)
#pragma unroll
        for (int nf = 0; nf < 4; ++nf)
          acc[mf][nf] = __builtin_amdgcn_mfma_f32_16x16x32_f16(af[mf], bfr[nf],
                                                               acc[mf][nf], 0, 0, 0);
      __builtin_amdgcn_s_setprio(0);
      __builtin_amdgcn_s_barrier();
    }
    // ---- P1: mfr 4..7 ----
    {
      f16x8 af[4];
#pragma unroll
      for (int mf = 0; mf < 4; ++mf)
        af[mf] = *(const f16x8*)(Ab + (4 + mf) * 1024 + gbx);
      if (T + 1 < kt1) { GA(2, tpn, (T + 1) & 1); GA(3, tpn, (T + 1) & 1); }
      if (T + 2 < kt1) {
        GB(T + 2);
        asm volatile("s_waitcnt vmcnt(1)" ::: "memory");
      } else {
        asm volatile("s_waitcnt vmcnt(0)" ::: "memory");
      }
      __builtin_amdgcn_s_barrier();
      asm volatile("s_waitcnt lgkmcnt(0)" ::: "memory");
      __builtin_amdgcn_sched_barrier(0);
      __builtin_amdgcn_s_setprio(1);
#pragma unroll
      for (int mf = 0; mf < 4; ++mf)
#pragma unroll
        for (int nf = 0; nf < 4; ++nf)
          acc[4 + mf][nf] = __builtin_amdgcn_mfma_f32_16x16x32_f16(af[mf], bfr[nf],
                                                                   acc[4 + mf][nf], 0, 0, 0);
      __builtin_amdgcn_s_setprio(0);
      __builtin_amdgcn_s_barrier();
    }
  }
#undef GA
#undef GB

  // Epilogue: C/D layout col = lane&15, row = (lane>>4)*4 + reg
  if (tp == nullptr) {
#pragma unroll
    for (int mfr = 0; mfr < 8; ++mfr) {
#pragma unroll
      for (int nf = 0; nf < 4; ++nf) {
        int m0 = mb * 512 + wm * 128 + mfr * 16 + hi * 4;
        int n = wn * 64 + nf * 16 + lo;
        float bval = bias[n];
#pragma unroll
        for (int r = 0; r < 4; ++r) {
          float v = acc[mfr][nf][r] + bval;
          if (RELU) v = fmaxf(v, 0.f);
          out16[(m0 + r) * COUT + n] = (f16)v;
        }
      }
    }
  } else {
#pragma unroll
    for (int mfr = 0; mfr < 8; ++mfr) {
#pragma unroll
      for (int nf = 0; nf < 4; ++nf) {
        int rowloc = wm * 128 + mfr * 16 + hi * 4;
        int n = wn * 64 + nf * 16 + lo;
#pragma unroll
        for (int r = 0; r < 4; ++r)
          tp[(rowloc + r) * 128 + n] = (f16)acc[mfr][nf][r];
      }
    }
  }
}

// ------- conv2 tail reduce: h2[tail rows] = relu(p0+p1+p2+bias), x8 vec ------------
__global__ __launch_bounds__(256) void tailredw_kernel(const f16* __restrict__ tp01,
                                                       const f16* __restrict__ tp2,
                                                       const float* __restrict__ bias,
                                                       f16* __restrict__ h2) {
  int idx = blockIdx.x * 256 + threadIdx.x;  // 4352 blocks: 8,912,896 elems / 8
  int e0 = idx * 8;
  int n0 = e0 & 127;
  f16x8 a = *(const f16x8*)(tp01 + e0);
  f16x8 b = *(const f16x8*)(tp01 + 8912896 + e0);
  f16x8 c = *(const f16x8*)(tp2 + e0);
  f16x8 o;
#pragma unroll
  for (int j = 0; j < 8; ++j) {
    float v = (float)a[j] + (float)b[j] + (float)c[j] + bias[n0 + j];
    o[j] = (f16)fmaxf(v, 0.f);
  }
  *(f16x8*)(h2 + 16777216 + e0) = o;  // tail tiles start at m = 256*512
}

// ------- conv3 tail reduce: h3[tail rows] = relu(p0+p1+p2+bias), x8 vec ------------
__global__ __launch_bounds__(256) void tailred3_kernel(const f16* __restrict__ tp01,
                                                       const f16* __restrict__ tp2,
                                                       const float* __restrict__ bias,
                                                       f16* __restrict__ h3) {
  int idx = blockIdx.x * 256 + threadIdx.x;  // 4608 blocks: 9,437,184 elems / 8
  int e0 = idx * 8;
  int n0 = e0 & 255;
  f16x8 a = *(const f16x8*)(tp01 + e0);
  f16x8 b = *(const f16x8*)(tp01 + 9437184 + e0);
  f16x8 c = *(const f16x8*)(tp2 + e0);
  f16x8 o;
#pragma unroll
  for (int j = 0; j < 8; ++j) {
    float v = (float)a[j] + (float)b[j] + (float)c[j] + bias[n0 + j];
    o[j] = (f16)fmaxf(v, 0.f);
  }
  *(f16x8*)(h3 + 16777216 + e0) = o;  // tail tiles start at m = 256*256
}

// ---------------- implicit-GEMM conv via f16 MFMA (m97 structure, 128x128) --------
template<int HIN, int WIN, int CIN, int HOUT, int WOUT, int COUT, int STRIDE,
         bool RELU, bool OUTF16, int SPLIT, bool ADDBIAS>
__global__ __launch_bounds__(256) void conv_mfma_kernel(const f16* __restrict__ in,
                                                        const f16* __restrict__ wt,
                                                        const float* __restrict__ bias,
                                                        f16* __restrict__ out16,
                                                        float* __restrict__ out32) {
  constexpr int KTOT = 81 * CIN;
  constexpr int NBLK = COUT / 128;
  constexpr int MTOT = 256 * HOUT * WOUT;
  constexpr int MBNB = (MTOT / 128) * NBLK;
  constexpr int NKT = (KTOT / 64) / SPLIT;
  __shared__ __align__(16) f16 lds[16384];
  int bidx = (int)blockIdx.x;
  int ks = 0;
  if (SPLIT > 1) { ks = bidx / MBNB; bidx -= ks * MBNB; }
  const int mb = bidx / NBLK;
  const int nb = bidx % NBLK;
  const int t = threadIdx.x;
  const int wave = t >> 6, lane = t & 63;
  const int hi = lane >> 4, lo = lane & 15;
  const bool isA = wave < 2;
  const int slot0 = wave << 9;

  int baseoff[8];
#pragma unroll
  for (int it = 0; it < 8; ++it) {
    int s = slot0 + it * 64 + lane;
    if (isA) {
      int row = s >> 3;
      int g = (s & 7) ^ (row & 7);
      int mg = mb * 128 + row;
      int b = mg / (HOUT * WOUT);
      int rr = mg - b * (HOUT * WOUT);
      int oh = rr / WOUT;
      int ow = rr - oh * WOUT;
      baseoff[it] = ((b * HIN + oh * STRIDE) * WIN + ow * STRIDE) * CIN + g * 8;
    } else {
      int sl = s - 1024;
      int row = sl >> 3;
      int g = (sl & 7) ^ (row & 7);
      baseoff[it] = (nb * 128 + row) * KTOT + g * 8;
    }
  }
  const f16* gsrc = isA ? in : wt;

  int aQ[4], bQ[4];
  const int wm = wave >> 1, wn = wave & 1;
#pragma unroll
  for (int f = 0; f < 4; ++f) {
    int arow = wm * 64 + f * 16 + lo;
    aQ[f] = (arow * 128) ^ ((arow & 7) << 4);
    int brow = wn * 64 + f * 16 + lo;
    bQ[f] = 16384 + ((brow * 128) ^ ((brow & 7) << 4));
  }

  f32x4 acc[4][4] = {};
  const char* ldsc = (const char*)lds;

  const int kt0 = ks * NKT;
  for (int kt = kt0; kt < kt0 + NKT; ++kt) {
    int tapoff;
    if (isA) tapoff = tapA_off<CIN, WIN>(kt);
    else     tapoff = kt << 6;
    __syncthreads();
#pragma unroll
    for (int it = 0; it < 8; ++it)
      gload_lds16(gsrc + baseoff[it] + tapoff,
                  (void*)((char*)lds + ((slot0 + it * 64) << 4)));
    __syncthreads();
#pragma unroll
    for (int sub = 0; sub < 2; ++sub) {
      const int gx = (sub * 4 + hi) << 4;
      f16x8 av[4], bv[4];
#pragma unroll
      for (int f = 0; f < 4; ++f) av[f] = *(const f16x8*)(ldsc + (aQ[f] ^ gx));
#pragma unroll
      for (int f = 0; f < 4; ++f) bv[f] = *(const f16x8*)(ldsc + (bQ[f] ^ gx));
#pragma unroll
      for (int mf = 0; mf < 4; ++mf)
#pragma unroll
        for (int nf = 0; nf < 4; ++nf)
          acc[mf][nf] = __builtin_amdgcn_mfma_f32_16x16x32_f16(av[mf], bv[nf],
                                                               acc[mf][nf], 0, 0, 0);
    }
  }

  float* o32 = out32 + (size_t)ks * MTOT * COUT;
#pragma unroll
  for (int mf = 0; mf < 4; ++mf) {
#pragma unroll
    for (int nf = 0; nf < 4; ++nf) {
      int m0 = mb * 128 + wm * 64 + mf * 16 + hi * 4;
      int n = nb * 128 + wn * 64 + nf * 16 + lo;
      float bval = ADDBIAS ? bias[n] : 0.f;
#pragma unroll
      for (int r = 0; r < 4; ++r) {
        float v = acc[mf][nf][r] + bval;
        if (RELU) v = fmaxf(v, 0.f);
        int o = (m0 + r) * COUT + n;
        if (OUTF16) out16[o] = (f16)v; else o32[o] = v;
      }
    }
  }
}

// ------- dense GEMM via f16 MFMA, K-split partials: A[256][K] x Bw[NP][K]^T --------
template<int K, int NP, int SPLIT>
__global__ __launch_bounds__(256) void gemm_mfma_kernel(const f16* __restrict__ A,
                                                        const f16* __restrict__ Bw,
                                                        float* __restrict__ dpart) {
  constexpr int NBLK = NP / 128;
  constexpr int MBNB = 2 * NBLK;
  constexpr int NKT = (K / 64) / SPLIT;
  __shared__ __align__(16) f16 lds[16384];
  int bidx = (int)blockIdx.x;
  int ks = 0;
  if (SPLIT > 1) { ks = bidx / MBNB; bidx -= ks * MBNB; }
  const int mb = bidx / NBLK;
  const int nb = bidx % NBLK;
  const int t = threadIdx.x;
  const int wave = t >> 6, lane = t & 63;
  const int hi = lane >> 4, lo = lane & 15;
  const bool isA = wave < 2;
  const int slot0 = wave << 9;

  int baseoff[8];
#pragma unroll
  for (int it = 0; it < 8; ++it) {
    int s = slot0 + it * 64 + lane;
    if (isA) {
      int row = s >> 3;
      int g = (s & 7) ^ (row & 7);
      baseoff[it] = (mb * 128 + row) * K + g * 8;
    } else {
      int sl = s - 1024;
      int row = sl >> 3;
      int g = (sl & 7) ^ (row & 7);
      baseoff[it] = (nb * 128 + row) * K + g * 8;
    }
  }
  const f16* gsrc = isA ? A : Bw;

  int aQ[4], bQ[4];
  const int wm = wave >> 1, wn = wave & 1;
#pragma unroll
  for (int f = 0; f < 4; ++f) {
    int arow = wm * 64 + f * 16 + lo;
    aQ[f] = (arow * 128) ^ ((arow & 7) << 4);
    int brow = wn * 64 + f * 16 + lo;
    bQ[f] = 16384 + ((brow * 128) ^ ((brow & 7) << 4));
  }

  f32x4 acc[4][4] = {};
  const char* ldsc = (const char*)lds;

  const int kt0 = ks * NKT;
  for (int kt = kt0; kt < kt0 + NKT; ++kt) {
    int tapoff = kt << 6;
    __syncthreads();
#pragma unroll
    for (int it = 0; it < 8; ++it)
      gload_lds16(gsrc + baseoff[it] + tapoff,
                  (void*)((char*)lds + ((slot0 + it * 64) << 4)));
    __syncthreads();
#pragma unroll
    for (int sub = 0; sub < 2; ++sub) {
      const int gx = (sub * 4 + hi) << 4;
      f16x8 av[4], bv[4];
#pragma unroll
      for (int f = 0; f < 4; ++f) av[f] = *(const f16x8*)(ldsc + (aQ[f] ^ gx));
#pragma unroll
      for (int f = 0; f < 4; ++f) bv[f] = *(const f16x8*)(ldsc + (bQ[f] ^ gx));
#pragma unroll
      for (int mf = 0; mf < 4; ++mf)
#pragma unroll
        for (int nf = 0; nf < 4; ++nf)
          acc[mf][nf] = __builtin_amdgcn_mfma_f32_16x16x32_f16(av[mf], bv[nf],
                                                               acc[mf][nf], 0, 0, 0);
    }
  }

  float* o32 = dpart + (size_t)ks * 256 * NP;
#pragma unroll
  for (int mf = 0; mf < 4; ++mf) {
#pragma unroll
    for (int nf = 0; nf < 4; ++nf) {
      int m0 = mb * 128 + wm * 64 + mf * 16 + hi * 4;
      int n = nb * 128 + wn * 64 + nf * 16 + lo;
#pragma unroll
      for (int r = 0; r < 4; ++r)
        o32[(m0 + r) * NP + n] = acc[mf][nf][r];
    }
  }
}

// ---------------- d2 reduce: r2 = relu(sum_s part + bias) f16, x4 vec ----------------
__global__ __launch_bounds__(256) void d2red_kernel(const float* __restrict__ part,
                                                    const float* __restrict__ bias,
                                                    f16* __restrict__ r2) {
  int idx = blockIdx.x * 256 + threadIdx.x;  // 512 blocks: 524288/4
  int e0 = idx * 4;
  int n0 = e0 & 2047;
  float4 a = *(const float4*)(part + e0);
  const float4 b1 = *(const float4*)(part + 524288 + e0);
  const float4 b2 = *(const float4*)(part + 1048576 + e0);
  const float4 b3 = *(const float4*)(part + 1572864 + e0);
  float v[4] = {a.x + b1.x + b2.x + b3.x, a.y + b1.y + b2.y + b3.y,
                a.z + b1.z + b2.z + b3.z, a.w + b1.w + b2.w + b3.w};
#pragma unroll
  for (int j = 0; j < 4; ++j)
    r2[e0 + j] = (f16)fmaxf(v[j] + bias[n0 + j], 0.f);
}

// ---------------- d3 reduce: recon = sigmoid(sum_s part + bias), mask n<1600 --------
__global__ __launch_bounds__(256) void d3red_kernel(const float* __restrict__ part,
                                                    const float* __restrict__ bias,
                                                    float* __restrict__ recon) {
  int idx = blockIdx.x * 256 + threadIdx.x;  // 416 blocks: 425984/4
  int e0 = idx * 4;
  int n0 = e0 % 1664;
  int m = e0 / 1664;
  float v[4] = {0.f, 0.f, 0.f, 0.f};
#pragma unroll
  for (int s = 0; s < 8; ++s) {
    float4 a = *(const float4*)(part + s * 425984 + e0);
    v[0] += a.x; v[1] += a.y; v[2] += a.z; v[3] += a.w;
  }
#pragma unroll
  for (int j = 0; j < 4; ++j) {
    int n = n0 + j;
    if (n < 1600)
      recon[m * 1600 + n] = 1.f / (1.f + expf(-(v[j] + bias[n])));
  }
}

// ======================= fused routing =======================
// uhatps: block (ic of 9, bg of 32) batches 8 b's; folds prim_reduce over 6 K-split
// partial slices (u = bias + sum_{s<6} part[s]).
__global__ __launch_bounds__(320) void uhatps_kernel(const float* __restrict__ wf,
                                                     const float* __restrict__ part,
                                                     const float* __restrict__ pbias,
                                                     f16* __restrict__ uh,
                                                     float* __restrict__ parts) {
  __shared__ float pl[8][128][8];  // 32 KB
  int blk = (int)blockIdx.x;       // 9 * 32 = 288
  int ic = blk / 32, bg = blk - ic * 32;
  int b0 = bg * 8;
  int t = threadIdx.x;
  for (int e = t; e < 8192; e += 320) {
    int b8 = e >> 10;
    int el = e & 1023;
    float a = pbias[el & 255];
    int gi = (b0 + b8) * 9216 + ic * 1024 + el;
#pragma unroll
    for (int s = 0; s < 6; ++s) a += part[s * 2359296 + gi];
    pl[b8][el >> 3][el & 7] = a;
  }
  __syncthreads();
  int half = (t >= 160) ? 1 : 0;
  int jk = t - half * 160;
  int ibase = ic * 128 + half * 64;
  float sum[8] = {};
  for (int il = 0; il < 64; ++il) {
    int i = ibase + il;
    const float4* w4 = (const float4*)(wf + (i * 160 + jk) * 8);
    float4 w0 = w4[0], w1 = w4[1];
    int row = half * 64 + il;
#pragma unroll
    for (int b8 = 0; b8 < 8; ++b8) {
      const float* pr = pl[b8][row];
      float acc = w0.x * pr[0] + w0.y * pr[1] + w0.z * pr[2] + w0.w * pr[3] +
                  w1.x * pr[4] + w1.y * pr[5] + w1.z * pr[6] + w1.w * pr[7];
      uh[((size_t)(b0 + b8) * 1152 + i) * 160 + jk] = (f16)acc;
      sum[b8] += acc;
    }
  }
#pragma unroll
  for (int b8 = 0; b8 < 8; ++b8)
    parts[((b0 + b8) * 18 + ic * 2 + half) * 160 + jk] = sum[b8];
}

template<int NCH, bool FIRST, bool WRITEB>
__global__ __launch_bounds__(256) void ba_kernel(const f16* __restrict__ uh,
                                                 const float* __restrict__ psrc,
                                                 float cscale,
                                                 float* __restrict__ blog,
                                                 float* __restrict__ pdst) {
  __shared__ f16 ul[128 * 172];   // 44,032 B
  __shared__ float vl[160];
  __shared__ float csm[128 * 10];
  int blk = (int)blockIdx.x;
  int b = blk / 9, ic = blk - b * 9;
  int t = threadIdx.x;
  const f16* ub = uh + (size_t)(b * 1152 + ic * 128) * 160;
  for (int e = t; e < 2560; e += 256) {  // 128 rows x 20 vec8
    int row = e / 20, col = e - row * 20;
    *(f16x8*)(ul + row * 172 + col * 8) = *(const f16x8*)(ub + row * 160 + col * 8);
  }
  if (t < 160) {
    float s = 0.f;
    for (int c = 0; c < NCH; ++c) s += psrc[(b * NCH + c) * 160 + t];
    s *= cscale;
    float ss = s * s;
    ss += __shfl_xor(ss, 1, 16);
    ss += __shfl_xor(ss, 2, 16);
    ss += __shfl_xor(ss, 4, 16);
    ss += __shfl_xor(ss, 8, 16);
    float n = sqrtf(ss);
    float f = ss / ((1.f + ss) * (n + 1e-7f));
    vl[t] = f * s;
  }
  __syncthreads();

  int il = t >> 1, half = t & 1, j0 = half * 5;
  const f16* ur = ul + il * 172 + j0 * 16;
  float agr[5];
#pragma unroll
  for (int j = 0; j < 5; ++j) {
    f16x8 a0 = *(const f16x8*)(ur + j * 16);
    f16x8 a1 = *(const f16x8*)(ur + j * 16 + 8);
    const float* vv = vl + (j0 + j) * 16;
    float s = (float)a0[0] * vv[0] + (float)a0[1] * vv[1] + (float)a0[2] * vv[2] +
              (float)a0[3] * vv[3] + (float)a0[4] * vv[4] + (float)a0[5] * vv[5] +
              (float)a0[6] * vv[6] + (float)a0[7] * vv[7] +
              (float)a1[0] * vv[8] + (float)a1[1] * vv[9] + (float)a1[2] * vv[10] +
              (float)a1[3] * vv[11] + (float)a1[4] * vv[12] + (float)a1[5] * vv[13] +
              (float)a1[6] * vv[14] + (float)a1[7] * vv[15];
    agr[j] = s;
  }
  int bbase = (b * 1152 + ic * 128 + il) * 10 + j0;
  float bl[5];
#pragma unroll
  for (int j = 0; j < 5; ++j) bl[j] = (FIRST ? 0.f : blog[bbase + j]) + agr[j];
  if (WRITEB) {
#pragma unroll
    for (int j = 0; j < 5; ++j) blog[bbase + j] = bl[j];
  }
  float mx = bl[0];
#pragma unroll
  for (int j = 1; j < 5; ++j) mx = fmaxf(mx, bl[j]);
  mx = fmaxf(mx, __shfl_xor(mx, 1));
  float e5[5], se = 0.f;
#pragma unroll
  for (int j = 0; j < 5; ++j) { e5[j] = expf(bl[j] - mx); se += e5[j]; }
  se += __shfl_xor(se, 1);
  float inv = 1.f / se;
#pragma unroll
  for (int j = 0; j < 5; ++j) csm[il * 10 + j0 + j] = e5[j] * inv;
  __syncthreads();

  if (t < 160) {
    int j = t >> 4;
    float s = 0.f;
    for (int il2 = 0; il2 < 128; ++il2)
      s += csm[il2 * 10 + j] * (float)ul[il2 * 172 + t];
    pdst[(b * 9 + ic) * 160 + t] = s;
  }
}

// maskd1v: folds final sred (v3 from parts, writes vout) + mask + dense1.
__global__ __launch_bounds__(1024) void maskd1v_kernel(const float* __restrict__ parts,
                                                       const int* __restrict__ y,
                                                       const float* __restrict__ w1,
                                                       const float* __restrict__ b1,
                                                       float* __restrict__ vout,
                                                       f16* __restrict__ r1) {
  __shared__ float vl[160];
  int b = blockIdx.x, t = threadIdx.x;
  if (t < 160) {
    float s = 0.f;
    for (int c = 0; c < 9; ++c) s += parts[(b * 9 + c) * 160 + t];
    float ss = s * s;
    ss += __shfl_xor(ss, 1, 16);
    ss += __shfl_xor(ss, 2, 16);
    ss += __shfl_xor(ss, 4, 16);
    ss += __shfl_xor(ss, 8, 16);
    float n = sqrtf(ss);
    float f = ss / ((1.f + ss) * (n + 1e-7f));
    float v = f * s;
    vl[t] = v;
    vout[b * 160 + t] = v;
  }
  __syncthreads();
  int yb = y[b];
  float acc = b1[t];
#pragma unroll
  for (int k = 0; k < 16; ++k) acc += vl[yb * 16 + k] * w1[(yb * 16 + k) * 1024 + t];
  r1[b * 1024 + t] = (f16)fmaxf(acc, 0.f);
}

// ---------------- launch ----------------
extern "C" void kernel_launch(void* const* d_in, const int* in_sizes, int n_in,
                              void* d_out, int out_size, void* d_ws, size_t ws_size,
                              hipStream_t stream) {
  const float* x       = (const float*)d_in[0];
  const int*   y       = (const int*)d_in[1];
  const float* conv1_k = (const float*)d_in[2];
  const float* conv1_b = (const float*)d_in[3];
  const float* conv2_k = (const float*)d_in[4];
  const float* conv2_b = (const float*)d_in[5];
  const float* conv3_k = (const float*)d_in[6];
  const float* conv3_b = (const float*)d_in[7];
  const float* prim_k  = (const float*)d_in[8];
  const float* prim_b  = (const float*)d_in[9];
  const float* w_route = (const float*)d_in[10];
  const float* d1_w = (const float*)d_in[11];
  const float* d1_b = (const float*)d_in[12];
  const float* d2_w = (const float*)d_in[13];
  const float* d2_b = (const float*)d_in[14];
  const float* d3_w = (const float*)d_in[15];
  const float* d3_b = (const float*)d_in[16];

  // workspace layout (bytes), total 191,021,056 (same as R1-R12 -> proven fits).
  // Liveness (re-derived incl. conv2 tail partials):
  //  conv2-era:   h1[0,42.5M) input, h2[42.5M,93.8M) out,
  //               tpc2_01[93.8M,129.5M) + tpc2_2[129.5M,147.3M) (free zone, < wt2)
  //  conv3-era:   tpart01[0,37.7M) (h1 dead), h3[93.8M,146.3M) over dead tpc2,
  //               tpart2[146.3M,165.2M) (dead tpc2 tail + pre-parts zone)
  //  prim-era:    part[0,56.6M)
  //  uhatps-era:  uhat[56.6M,151.0M), parts_a[151.0M,153.9M)
  //  ba-era:      parts_b[153.9M,155.4M), blog[155.7M,167.5M)
  //  dense-era:   dpart2[0,8.4M), dpart3[16.8M,30.4M)
  char* ws = (char*)d_ws;
  f16*   h1      = (f16*)(ws + 0);
  f16*   tpart01 = (f16*)(ws + 0);                   // 2 x 18,874,368 B
  float* part    = (float*)(ws + 0);                 // 6 x 9,437,184 B = 56,623,104
  float* dpart2  = (float*)(ws + 0);                 //  8,388,608 B
  float* dpart3  = (float*)(ws + 16777216);          // 13,631,488 B
  f16*   h2      = (f16*)(ws + 42467328);
  f16*   uhat    = (f16*)(ws + 56623104);            // 94,371,840 B -> ends 150,994,944
  f16*   h3      = (f16*)(ws + 93847552);
  f16*   tpc2_01 = (f16*)(ws + 93847552);            // 2 x 17,825,792 B (conv2-era)
  f16*   tpc2_2  = (f16*)(ws + 129499136);           // 17,825,792 B -> ends 147,324,928
  f16*   tpart2  = (f16*)(ws + 146276352);           // 18,874,368 B (conv3-era only)
  float* parts_a = (float*)(ws + 150994944);         //  2,949,120 B -> ends 153,944,064
  float* parts_b = (float*)(ws + 153944064);         //  1,474,560 B -> ends 155,418,624
  float* blog    = (float*)(ws + 155713536);         // 11,796,480 B -> ends 167,510,016
  f16*   r1h     = (f16*)(ws + 167673856);           //    524,288 B
  f16*   r2h     = (f16*)(ws + 168198144);           //  1,048,576 B
  f16*   wt2     = (f16*)(ws + 170819584);           //  1,327,104 B
  f16*   wt3     = (f16*)(ws + 172146688);           //  5,308,416 B
  f16*   wtp     = (f16*)(ws + 177455104);           // 10,616,832 B (dead after prim)
  f16*   wd2     = (f16*)(ws + 177455104);           //  4,194,304 B (alias wtp)
  f16*   wd3     = (f16*)(ws + 181649408);           //  6,815,744 B -> ends 188,465,152

  float* vout  = (float*)d_out;            // [256,1,10,16] = 40960 f32
  float* recon = (float*)d_out + 40960;    // [256,1600]

  // conv weight prep + conv1 (one launch)
  wprepc_kernel<<<12474, 256, 0, stream>>>(conv2_k, wt2, conv3_k, wt3, prim_k, wtp,
                                           x, conv1_k, conv1_b, h1);

  // conv2: BM=512xBN=128 BK=32 deep-pipelined + K-third tail (256 fulls + 408 thirds)
  conv8pw_kernel<36, 36, 64, 28, 28, 128, 1, true, 256, 136>
      <<<664, 512, 0, stream>>>(h1, wt2, conv2_b, h2, tpc2_01, tpc2_2);
  tailredw_kernel<<<4352, 256, 0, stream>>>(tpc2_01, tpc2_2, conv2_b, h2);
  // conv3: 8-phase 256^2 + K-third tail smoothing (256 fulls + 432 thirds)
  conv8p_kernel<28, 28, 128, 20, 20, 256, 1, true, true, 256, 144>
      <<<688, 512, 0, stream>>>(h2, wt3, conv3_b, h3, nullptr, tpart01, tpart2);
  tailred3_kernel<<<4608, 256, 0, stream>>>(tpart01, tpart2, conv3_b, h3);
  // prim caps: K-split x6 (864 blocks = 3.375/CU, m97 rate-saturating occupancy)
  conv_mfma_kernel<20, 20, 256, 6, 6, 256, 2, false, false, 6, false>
      <<<864, 256, 0, stream>>>(h3, wtp, prim_b, nullptr, part);

  // fused routing (uhatps folds 6-way prim reduce; batches 8 b's/block)
  uhatps_kernel<<<288, 320, 0, stream>>>(w_route, part, prim_b, uhat, parts_a);
  wprepd_kernel<<<1344, 256, 0, stream>>>(d2_w, wd2, d3_w, wd3);  // wtp dead now
  ba_kernel<18, true, true><<<2304, 256, 0, stream>>>(uhat, parts_a, 0.1f, blog, parts_b);
  ba_kernel<9, false, false><<<2304, 256, 0, stream>>>(uhat, parts_b, 1.0f, blog, parts_a);

  // masked reconstruction
  maskd1v_kernel<<<256, 1024, 0, stream>>>(parts_a, y, d1_w, d1_b, vout, r1h);
  gemm_mfma_kernel<1024, 2048, 4><<<128, 256, 0, stream>>>(r1h, wd2, dpart2);
  d2red_kernel<<<512, 256, 0, stream>>>(dpart2, d2_b, r2h);
  gemm_mfma_kernel<2048, 1664, 8><<<208, 256, 0, stream>>>(r2h, wd3, dpart3);
  d3red_kernel<<<416, 256, 0, stream>>>(dpart3, d3_b, recon);
}